// Round 13
// baseline (1682.561 us; speedup 1.0000x reference)
//
#include <hip/hip_runtime.h>
#include <math.h>

// ---------------------------------------------------------------------------
#define D 768
#define NPARA 32
#define LPARA 512
#define LQ 32
#define NENT 10000
#define MMENT 30000
#define NPAIR 20000
#define NSTEP 3

using bf16x8 = __attribute__((ext_vector_type(8))) short;
using f32x4  = __attribute__((ext_vector_type(4))) float;

__device__ __forceinline__ float geluf(float x) {
    return 0.5f * x * (1.0f + erff(x * 0.70710678118654752f));
}
__device__ __forceinline__ float bf2f(ushort h) {
    union { unsigned u; float f; } v; v.u = ((unsigned)h) << 16; return v.f;
}
// round-to-nearest-even fp32 -> bf16
__device__ __forceinline__ ushort bfrne(float x) {
    union { float f; unsigned u; } v; v.f = x;
    unsigned r = (v.u + 0x7FFF + ((v.u >> 16) & 1)) >> 16;
    return (ushort)r;
}

// ---------------------------------------------------------------------------
// Single-plane bf16 MFMA GEMM. Tile (MI*32) x 128, A+B LDS (XOR-swizzled),
// register prefetch of next A and B tiles, band-major XCD swizzle.
// MI=2: 64x128 (wave 32x64)  -- for small-M / N=256 GEMMs (grid >= 314)
// MI=4: 128x128 (wave 64x64) -- for M=20000 GEMMs (1.5x FLOP per LDS byte)
// MODE 0: A = bf16 plane [M][K]
// MODE 1: A row r = concat(para[p,t1,:], para[p,t2,:]) fp32 gather, K=1536
// MODE 2: A sections {S, O, SO} selected per k-tile (SO precomputed), K=2304
//         (Ah carries the SO plane)
// B: pre-transposed bf16 weights WT[N][K]. OUTP 0: fp32 C; 1: bf16 C.
// NOTE: launch_bounds (256,4): (256,5) caused scratch spill (R11).
// ---------------------------------------------------------------------------
#define BN 128

__device__ __forceinline__ int ldso(int row, int kb) {   // kb = byte offset
    return row * 64 + (((kb) ^ ((row & 7) << 4)) >> 1);
}

template <int MODE, int ACT, int OUTP, int MI>
__global__ __launch_bounds__(256, 4) void gemm_m(
    const ushort* __restrict__ Ah,
    const float* __restrict__ para, const int* __restrict__ ppos, int c1, int c2,
    const ushort* __restrict__ Sh, const ushort* __restrict__ Oh,
    const ushort* __restrict__ Bh, const float* __restrict__ bias,
    float* __restrict__ Cf, ushort* __restrict__ Ch,
    int M, int N, int K, int nby)
{
    constexpr int BM = MI * 32;
    constexpr int TPR = 256 / BM;    // threads per A-row (4 or 2)
    constexpr int SPAN = 64 / TPR;   // ushorts per thread per A-row (16 or 32)
    constexpr int NV = SPAN / 8;     // bf16x8 vectors per thread (2 or 4)

    __shared__ ushort sA[BM * 64];   //  8 or 16 KB
    __shared__ ushort sB[BN * 64];   // 16 KB

    const int nwg = gridDim.x;
    const int q = nwg >> 3, r = nwg & 7;
    const int xcd = blockIdx.x & 7, idx = blockIdx.x >> 3;
    const int wgid = (xcd < r) ? xcd * (q + 1) + idx
                               : r * (q + 1) + (xcd - r) * q + idx;
    const int m0 = (wgid / nby) * BM;
    const int n0 = (wgid % nby) * BN;

    const int tid = threadIdx.x;
    const int lane = tid & 63;
    const int wv = tid >> 6;
    const int wr = (wv >> 1) * (MI * 16);
    const int wc = (wv & 1) * 64;
    const int ln = lane & 15;
    const int kg = lane >> 4;

    f32x4 acc[MI][4];
#pragma unroll
    for (int i = 0; i < MI; ++i)
#pragma unroll
        for (int j = 0; j < 4; ++j)
#pragma unroll
            for (int e = 0; e < 4; ++e) acc[i][j][e] = 0.0f;

    const int arow = tid / TPR, aq = tid % TPR;
    const int brow = tid >> 1, bq = tid & 1;
    const int gm = m0 + arow;
    const bool ok = gm < M;

    int baseL = 0, baseR = 0;
    if (MODE == 1 && ok) {
        int p = ppos[gm * 5];
        baseL = (p * LPARA + ppos[gm * 5 + c1]) * D;
        baseR = (p * LPARA + ppos[gm * 5 + c2]) * D;
    }

    bf16x8 pa[NV];           // MODE 0/2 prefetch
    float4 pf[2 * NV];       // MODE 1 prefetch
    bf16x8 pb[4];            // B prefetch (64B/thread)

    auto prefA = [&](int kt) {
        if (MODE == 0 || MODE == 2) {
            const ushort* pl;
            int koff;
            if (MODE == 0) { pl = Ah; koff = kt; }
            else {
                const int sec = kt / D;
                pl = (sec == 0) ? Sh : (sec == 1) ? Oh : Ah;   // Ah = SO plane
                koff = kt - sec * D;
            }
            if (ok) {
                const ushort* g = pl + (size_t)gm * ((MODE == 0) ? K : D)
                                + koff + aq * SPAN;
#pragma unroll
                for (int i = 0; i < NV; ++i) pa[i] = *(const bf16x8*)(g + i * 8);
            } else {
#pragma unroll
                for (int i = 0; i < NV; ++i)
#pragma unroll
                    for (int z = 0; z < 8; ++z) pa[i][z] = 0;
            }
        } else {   // MODE 1
            const int kb = kt + aq * SPAN;         // tile never crosses D bound
            const int gb = (kb < D) ? (baseL + kb) : (baseR + kb - D);
#pragma unroll
            for (int j = 0; j < 2 * NV; ++j)
                pf[j] = ok ? *(const float4*)(para + gb + j * 4)
                           : make_float4(0.f, 0.f, 0.f, 0.f);
        }
    };

    auto prefB = [&](int kt) {
        const ushort* g = Bh + (size_t)(n0 + brow) * K + kt + bq * 32;
#pragma unroll
        for (int i = 0; i < 4; ++i)
            pb[i] = *(const bf16x8*)(g + i * 8);
    };

    auto storeAB = [&]() {
        if (MODE == 0 || MODE == 2) {
#pragma unroll
            for (int i = 0; i < NV; ++i)
                *(bf16x8*)&sA[ldso(arow, aq * SPAN * 2 + i * 16)] = pa[i];
        } else {
#pragma unroll
            for (int j = 0; j < 2 * NV; ++j) {
                ushort4 h;
                h.x = bfrne(pf[j].x); h.y = bfrne(pf[j].y);
                h.z = bfrne(pf[j].z); h.w = bfrne(pf[j].w);
                *(ushort4*)&sA[ldso(arow, aq * SPAN * 2 + j * 8)] = h;
            }
        }
#pragma unroll
        for (int i = 0; i < 4; ++i)
            *(bf16x8*)&sB[ldso(brow, bq * 64 + i * 16)] = pb[i];
    };

    prefA(0);
    prefB(0);

    for (int kt = 0; kt < K; kt += 64) {
        if (kt > 0) __syncthreads();
        storeAB();
        __syncthreads();

        const int ktn = kt + 64;
        if (ktn < K) { prefA(ktn); prefB(ktn); }

#pragma unroll
        for (int ks = 0; ks < 2; ++ks) {
            bf16x8 fb[4];
#pragma unroll
            for (int ni = 0; ni < 4; ++ni)
                fb[ni] = *(const bf16x8*)&sB[ldso(wc + ni * 16 + ln, ks * 64 + kg * 16)];
#pragma unroll
            for (int mi = 0; mi < MI; ++mi) {
                bf16x8 fa = *(const bf16x8*)&sA[ldso(wr + mi * 16 + ln, ks * 64 + kg * 16)];
#pragma unroll
                for (int ni = 0; ni < 4; ++ni)
                    acc[mi][ni] = __builtin_amdgcn_mfma_f32_16x16x32_bf16(
                        fa, fb[ni], acc[mi][ni], 0, 0, 0);
            }
        }
    }

    // epilogue: row = (lane>>4)*4+reg, col = lane&15
#pragma unroll
    for (int mi = 0; mi < MI; ++mi)
#pragma unroll
        for (int ni = 0; ni < 4; ++ni) {
            int col = n0 + wc + ni * 16 + ln;
            f32x4 a = acc[mi][ni];
#pragma unroll
            for (int j = 0; j < 4; ++j) {
                int row = m0 + wr + mi * 16 + kg * 4 + j;
                if (row < M) {
                    float v = a[j] + bias[col];
                    if (ACT == 1) v = geluf(v);
                    if (OUTP == 0) Cf[(size_t)row * N + col] = v;
                    else           Ch[(size_t)row * N + col] = bfrne(v);
                }
            }
        }
}

// ---------------------------------------------------------------------------
// SO[i] = bf16(S[i] * O[i])  (vector ushort4)
__global__ void k_so(const ushort* __restrict__ S, const ushort* __restrict__ O,
                     ushort* __restrict__ SO, int n4)
{
    int i = blockIdx.x * blockDim.x + threadIdx.x;
    if (i >= n4) return;
    ushort4 s = ((const ushort4*)S)[i];
    ushort4 o = ((const ushort4*)O)[i];
    ushort4 r;
    r.x = bfrne(bf2f(s.x) * bf2f(o.x));
    r.y = bfrne(bf2f(s.y) * bf2f(o.y));
    r.z = bfrne(bf2f(s.z) * bf2f(o.z));
    r.w = bfrne(bf2f(s.w) * bf2f(o.w));
    ((ushort4*)SO)[i] = r;
}

// ---------------------------------------------------------------------------
// Weight transpose: W[K][N] fp32 -> WT[N][K] bf16 (RNE)
__global__ __launch_bounds__(256) void k_wt(const float* __restrict__ W,
                                            ushort* __restrict__ WTh, int K, int N)
{
    __shared__ float t[32][33];
    const int k0 = blockIdx.x * 32, n0 = blockIdx.y * 32;
    const int c = threadIdx.x & 31, r8 = threadIdx.x >> 5;
#pragma unroll
    for (int i = 0; i < 4; ++i) {
        int r = r8 + i * 8;
        t[r][c] = W[(size_t)(k0 + r) * N + n0 + c];
    }
    __syncthreads();
#pragma unroll
    for (int i = 0; i < 4; ++i) {
        int r = r8 + i * 8;
        WTh[(size_t)(n0 + r) * K + k0 + c] = bfrne(t[c][r]);
    }
}

// folded pair W1: Wf[2304][768] from pW1[3072][768]
__global__ void k_fold(const float* __restrict__ pW1, float* __restrict__ Wf, int n)
{
    int i = blockIdx.x * blockDim.x + threadIdx.x;
    if (i >= n) return;
    int row = i / D;
    float v;
    if (row < D)            v = pW1[i] - pW1[i + 1536 * D];
    else if (row < 2 * D)   v = pW1[i] + pW1[i + 768 * D];
    else                    v = pW1[i + 768 * D];
    Wf[i] = v;
}

__global__ __launch_bounds__(256) void k_entmean(
    const float* __restrict__ para, const int* __restrict__ mpos,
    const int* __restrict__ mid, int M, ushort* __restrict__ oh)
{
    __shared__ int sb[2];
    const int e = blockIdx.x;
    if (threadIdx.x < 2) {
        int target = e + threadIdx.x;
        int lo = 0, hi = M;
        while (lo < hi) {
            int md = (lo + hi) >> 1;
            if (mid[md] < target) lo = md + 1; else hi = md;
        }
        sb[threadIdx.x] = lo;
    }
    __syncthreads();
    const int lo = sb[0], hi = sb[1];
    const int tid = threadIdx.x;
    float a0 = 0, a1 = 0, a2 = 0, b0 = 0, b1 = 0, b2 = 0;
    for (int m = lo; m < hi; ++m) {
        int p = mpos[m * 3], t1 = mpos[m * 3 + 1], t2 = mpos[m * 3 + 2];
        const float* L = para + (size_t)(p * LPARA + t1) * D;
        const float* R = para + (size_t)(p * LPARA + t2) * D;
        a0 += L[tid]; a1 += L[tid + 256]; a2 += L[tid + 512];
        b0 += R[tid]; b1 += R[tid + 256]; b2 += R[tid + 512];
    }
    const float inv = (hi > lo) ? 1.0f / (float)(hi - lo) : 0.0f;
    size_t base = (size_t)e * (2 * D);
    float vals[6] = { a0 * inv, a1 * inv, a2 * inv, b0 * inv, b1 * inv, b2 * inv };
    int offs[6] = { tid, tid + 256, tid + 512, D + tid, D + tid + 256, D + tid + 512 };
#pragma unroll
    for (int i = 0; i < 6; ++i) oh[base + offs[i]] = bfrne(vals[i]);
}

// ---------------------------------------------------------------------------
// Batched split-K matvec (deterministic). grid (N/64, nks, T).
__global__ __launch_bounds__(256) void k_mvpart(
    const float* __restrict__ x, int xstride,
    const float* __restrict__ W, float* __restrict__ acc, int K, int N, int nks)
{
    const int t = blockIdx.z;
    const float* xt = x + (size_t)t * xstride;
    const float* Wt = W + (size_t)t * K * N;
    const int jj = threadIdx.x & 63;
    const int kq = threadIdx.x >> 6;
    const int j = blockIdx.x * 64 + jj;
    const int kchunk = K / (nks * 4);
    const int kbeg = (blockIdx.y * 4 + kq) * kchunk;
    float s = 0.0f;
    for (int k = kbeg; k < kbeg + kchunk; ++k)
        s = fmaf(xt[k], Wt[(size_t)k * N + j], s);
    __shared__ float red[256];
    red[threadIdx.x] = s;
    __syncthreads();
    if (kq == 0) {
        float v = red[jj] + red[64 + jj] + red[128 + jj] + red[192 + jj];
        acc[((size_t)(t * nks) + blockIdx.y) * N + j] = v;
    }
}

__global__ void k_biasact(const float* __restrict__ acc, const float* __restrict__ b,
                          float* __restrict__ out, int N, int nks, int act)
{
    const int t = blockIdx.y;
    const int j = blockIdx.x * 256 + threadIdx.x;
    if (j >= N) return;
    float s = 0.0f;
    for (int i = 0; i < nks; ++i) s += acc[((size_t)(t * nks) + i) * N + j];
    s += b[(size_t)t * N + j];
    if (act) s = geluf(s);
    out[(size_t)t * N + j] = s;
}

__global__ void k_dot3(const float* __restrict__ x, const float* __restrict__ W,
                       const float* __restrict__ b, float* __restrict__ out)
{
    int j = threadIdx.x >> 6, lane = threadIdx.x & 63;
    if (j >= 3) return;
    float s = 0.0f;
#pragma unroll
    for (int i = 0; i < 4; ++i) {
        int k = lane + i * 64;
        s += x[k] * W[k * 3 + j];
    }
    for (int off = 32; off > 0; off >>= 1) s += __shfl_down(s, off, 64);
    if (lane == 0) out[j] = s + b[j];
}

__global__ void k_ctx3(const float* __restrict__ cq3, const float* __restrict__ qwh,
                       float* __restrict__ ctx3)
{
    const float* cq = cq3 + (size_t)blockIdx.x * D;
    float* ctx = ctx3 + (size_t)blockIdx.x * D;
    __shared__ float red[256];
    __shared__ float dist[LQ];
    const int tid = threadIdx.x;
    const int l = tid >> 3, part = tid & 7;
    float s = 0.0f;
    for (int d = part; d < D; d += 8) s += cq[d] * qwh[l * D + d];
    red[tid] = s;
    __syncthreads();
    if (part == 0) {
        float v = 0;
        for (int i = 0; i < 8; ++i) v += red[l * 8 + i];
        dist[l] = v;
    }
    __syncthreads();
    if (tid == 0) {
        float mx = -1e30f;
        for (int i = 0; i < LQ; ++i) mx = fmaxf(mx, dist[i]);
        float sm = 0;
        for (int i = 0; i < LQ; ++i) { float e = expf(dist[i] - mx); dist[i] = e; sm += e; }
        float inv = 1.0f / sm;
        for (int i = 0; i < LQ; ++i) dist[i] *= inv;
    }
    __syncthreads();
    for (int d = tid; d < D; d += 256) {
        float v = 0;
#pragma unroll
        for (int l2 = 0; l2 < LQ; ++l2) v += dist[l2] * qwh[l2 * D + d];
        ctx[d] = v + cq[d];
    }
}

__global__ void k_scalew(const float* __restrict__ ctx, const float* __restrict__ w1,
                         float* __restrict__ o, int n)
{
    int i = blockIdx.x * 256 + threadIdx.x;
    if (i < n) o[i] = ctx[i >> 8] * w1[i];
}

template <int PAIRMODE>
__global__ void k_rowdot(const float* __restrict__ H, const float* __restrict__ w2,
                         const float* __restrict__ sb2, int Nr,
                         float* __restrict__ simout,
                         const float* __restrict__ laste, const int* __restrict__ so,
                         float* __restrict__ newe)
{
    int r = blockIdx.x * 4 + (threadIdx.x >> 6);
    int lane = threadIdx.x & 63;
    if (r >= Nr) return;
    float s = 0.0f;
#pragma unroll
    for (int i = 0; i < 4; ++i)
        s += H[(size_t)r * 256 + lane + i * 64] * w2[lane + i * 64];
    for (int off = 32; off > 0; off >>= 1) s += __shfl_down(s, off, 64);
    if (lane == 0) {
        s += sb2[0];
        if (PAIRMODE == 0) {
            simout[r] = s;
        } else {
            float p = 1.0f / (1.0f + expf(-s));
            float v = laste[so[r * 2]] * p;
            atomicAdd(&newe[so[r * 2 + 1]], v);
        }
    }
}

__global__ void k_softmax(const float* __restrict__ sim, float* __restrict__ outp, int n)
{
    __shared__ float red[256];
    __shared__ float s_mx, s_sum;
    const int tid = threadIdx.x;
    float mx = -1e30f;
    for (int i = tid; i < n; i += 256) mx = fmaxf(mx, sim[i]);
    red[tid] = mx; __syncthreads();
    for (int off = 128; off > 0; off >>= 1) {
        if (tid < off) red[tid] = fmaxf(red[tid], red[tid + off]);
        __syncthreads();
    }
    if (tid == 0) s_mx = red[0];
    __syncthreads();
    const float mxv = s_mx;
    float sum = 0;
    for (int i = tid; i < n; i += 256) sum += expf(sim[i] - mxv);
    red[tid] = sum; __syncthreads();
    for (int off = 128; off > 0; off >>= 1) {
        if (tid < off) red[tid] += red[tid + off];
        __syncthreads();
    }
    if (tid == 0) s_sum = red[0];
    __syncthreads();
    const float inv = 1.0f / s_sum;
    for (int i = tid; i < n; i += 256) {
        float v = expf(sim[i] - mxv) * inv;
        outp[i] = v / fmaxf(v, 1.0f);
    }
}

__global__ void k_zero(float* p, int n)
{
    int i = blockIdx.x * blockDim.x + threadIdx.x;
    if (i < n) p[i] = 0.0f;
}

__global__ void k_clampstore(const float* __restrict__ ne, float* __restrict__ outp, int n)
{
    int i = blockIdx.x * blockDim.x + threadIdx.x;
    if (i < n) { float v = ne[i]; outp[i] = v / fmaxf(v, 1.0f); }
}

__global__ void k_final(const float* __restrict__ probs, const float* __restrict__ hlog,
                        float* __restrict__ out, int n)
{
    int i = blockIdx.x * blockDim.x + threadIdx.x;
    if (i >= n) return;
    float l0 = hlog[0], l1 = hlog[1], l2 = hlog[2];
    float m = fmaxf(l0, fmaxf(l1, l2));
    float e0 = expf(l0 - m), e1 = expf(l1 - m), e2 = expf(l2 - m);
    float inv = 1.0f / (e0 + e1 + e2);
    out[i] = (e0 * probs[i] + e1 * probs[n + i] + e2 * probs[2 * n + i]) * inv;
}

// ---------------------------------------------------------------------------
extern "C" void kernel_launch(void* const* d_in, const int* in_sizes, int n_in,
                              void* d_out, int out_size, void* d_ws, size_t ws_size,
                              hipStream_t stream)
{
    const size_t WS_NEED = 148793744;  // 141.9 MiB
    if (ws_size < WS_NEED) return;

    const float* para  = (const float*)d_in[0];
    const float* q     = (const float*)d_in[1];
    const float* qwh   = (const float*)d_in[2];
    const float* stW1  = (const float*)d_in[3];
    const float* stb1  = (const float*)d_in[4];
    const float* stW2  = (const float*)d_in[5];
    const float* stb2  = (const float*)d_in[6];
    const float* mW1   = (const float*)d_in[7];
    const float* mb1   = (const float*)d_in[8];
    const float* mW2   = (const float*)d_in[9];
    const float* mb2   = (const float*)d_in[10];
    const float* pW1   = (const float*)d_in[11];
    const float* pb1   = (const float*)d_in[12];
    const float* pW2   = (const float*)d_in[13];
    const float* pb2   = (const float*)d_in[14];
    const float* simW1 = (const float*)d_in[15];
    const float* simb1 = (const float*)d_in[16];
    const float* simW2 = (const float*)d_in[17];
    const float* simb2 = (const float*)d_in[18];
    const float* hW1   = (const float*)d_in[19];
    const float* hb1   = (const float*)d_in[20];
    const float* hW2   = (const float*)d_in[21];
    const float* hb2   = (const float*)d_in[22];
    const int*   mpos  = (const int*)d_in[23];
    const int*   mid   = (const int*)d_in[24];
    const int*   ppos  = (const int*)d_in[25];
    const int*   pso   = (const int*)d_in[26];

    // ---- workspace layout (single bf16 planes) ----
    ushort* P1   = (ushort*)d_ws;          // 15,360,000 (EM -> sub_feat -> pair_emb)
    ushort* HID  = P1  + 15360000;         // 15,360,000 (hidden; H256 fp32 overlay)
    ushort* OBJ  = HID + 15360000;         // 15,360,000 (Wfold tmp -> obj_feat)
    ushort* SOp  = OBJ + 15360000;         // 15,360,000 (sub*obj plane)
    ushort* E    = SOp + 15360000;         //  7,680,000 (ent_emb)
    ushort* mW1T = E    + 7680000;         //  1,179,648
    ushort* mW2T = mW1T + 1179648;         //    589,824
    ushort* WfT  = mW2T + 589824;          //  1,769,472 ([768][2304] folded)
    ushort* pW2T = WfT  + 1769472;         //    589,824
    ushort* W1sT0 = pW2T + 589824;         //    589,824 (3 x 196,608)
    float*  W1s   = (float*)(W1sT0 + 589824);  // 196,608
    float*  simb  = W1s  + 196608;         // 20,000
    float*  probs = simb + 20000;          // 30,000
    float*  newe  = probs + 30000;         // 10,000
    float*  acc3  = newe + 10000;          // 13,824
    float*  h3    = acc3 + 13824;          // 2,304
    float*  cq3   = h3   + 2304;           // 2,304
    float*  ctx3  = cq3  + 2304;           // 2,304
    float*  hacc  = ctx3 + 2304;           // 1,536
    float*  hh    = hacc + 1536;           // 256
    float*  hlog  = hh   + 256;            // 4
    float*  H256  = (float*)HID;           // 20000x256 fp32 overlay (HID dead then)
    float*  Wfold = (float*)OBJ;           // fp32 tmp (dead before OBJ written)

    dim3 B256(256);
    const ushort* np = nullptr;

    // 0) weight prep
    k_fold<<<(2304 * D + 255) / 256, B256, 0, stream>>>(pW1, Wfold, 2304 * D);
    k_wt<<<dim3(48, 24), B256, 0, stream>>>(mW1, mW1T, 2 * D, D);
    k_wt<<<dim3(24, 24), B256, 0, stream>>>(mW2, mW2T, D, D);
    k_wt<<<dim3(72, 24), B256, 0, stream>>>(Wfold, WfT, 3 * D, D);
    k_wt<<<dim3(24, 24), B256, 0, stream>>>(pW2, pW2T, D, D);

    // 1) batched step MLPs + ctx + scaled sim weights
    k_mvpart<<<dim3(12, 6, 3), B256, 0, stream>>>(q, 0, stW1, acc3, D, D, 6);
    k_biasact<<<dim3(3, 3), B256, 0, stream>>>(acc3, stb1, h3, D, 6, 1);
    k_mvpart<<<dim3(12, 6, 3), B256, 0, stream>>>(h3, D, stW2, acc3, D, D, 6);
    k_biasact<<<dim3(3, 3), B256, 0, stream>>>(acc3, stb2, cq3, D, 6, 0);
    k_ctx3<<<3, B256, 0, stream>>>(cq3, qwh, ctx3);
    for (int t = 0; t < NSTEP; ++t) {
        k_scalew<<<768, 256, 0, stream>>>(ctx3 + (size_t)t * D, simW1, W1s, D * 256);
        k_wt<<<dim3(24, 8), B256, 0, stream>>>(W1s, W1sT0 + t * 196608, D, 256);
    }

    // 2) entity mention means -> P1 (10000 x 1536 bf16)
    k_entmean<<<NENT, 256, 0, stream>>>(para, mpos, mid, MMENT, P1);

    // 3) ent_emb (M=10000: MI=2, grid 942)
    gemm_m<0, 1, 1, 2><<<942, B256, 0, stream>>>(P1, nullptr, nullptr, 0, 0, np, np,
        mW1T, mb1, nullptr, HID, NENT, D, 2 * D, 6);
    gemm_m<0, 0, 1, 2><<<942, B256, 0, stream>>>(HID, nullptr, nullptr, 0, 0, np, np,
        mW2T, mb2, nullptr, E, NENT, D, D, 6);

    // 4) step 0: sim on entities -> probs[0]
    gemm_m<0, 1, 0, 2><<<314, B256, 0, stream>>>(E, nullptr, nullptr, 0, 0, np, np,
        W1sT0, simb1, H256, nullptr, NENT, 256, D, 2);
    k_rowdot<0><<<NENT / 4, 256, 0, stream>>>(H256, simW2, simb2, NENT, simb,
                                              nullptr, nullptr, nullptr);
    k_softmax<<<1, 256, 0, stream>>>(simb, probs, NENT);

    // 5) pair pipeline (M=20000: MI=4, grid 157x6=942)
    gemm_m<1, 1, 1, 4><<<942, B256, 0, stream>>>(np, para, ppos, 1, 2, np, np,
        mW1T, mb1, nullptr, HID, NPAIR, D, 2 * D, 6);
    gemm_m<0, 0, 1, 4><<<942, B256, 0, stream>>>(HID, nullptr, nullptr, 0, 0, np, np,
        mW2T, mb2, nullptr, P1, NPAIR, D, D, 6);
    gemm_m<1, 1, 1, 4><<<942, B256, 0, stream>>>(np, para, ppos, 3, 4, np, np,
        mW1T, mb1, nullptr, HID, NPAIR, D, 2 * D, 6);
    gemm_m<0, 0, 1, 4><<<942, B256, 0, stream>>>(HID, nullptr, nullptr, 0, 0, np, np,
        mW2T, mb2, nullptr, OBJ, NPAIR, D, D, 6);
    k_so<<<15000, B256, 0, stream>>>(P1, OBJ, SOp, NPAIR * D / 4);
    gemm_m<2, 1, 1, 4><<<942, B256, 0, stream>>>(SOp, nullptr, nullptr, 0, 0, P1, OBJ,
        WfT, pb1, nullptr, HID, NPAIR, D, 3 * D, 6);
    gemm_m<0, 0, 1, 4><<<942, B256, 0, stream>>>(HID, nullptr, nullptr, 0, 0, np, np,
        pW2T, pb2, nullptr, P1, NPAIR, D, D, 6);

    // 6) steps 1,2: sim on pairs + scatter-propagate (MI=2, grid 626)
    for (int t = 1; t < NSTEP; ++t) {
        gemm_m<0, 1, 0, 2><<<626, B256, 0, stream>>>(P1, nullptr, nullptr, 0, 0, np, np,
            W1sT0 + t * 196608, simb1, H256, nullptr, NPAIR, 256, D, 2);
        k_zero<<<40, 256, 0, stream>>>(newe, NENT);
        k_rowdot<1><<<NPAIR / 4, 256, 0, stream>>>(H256, simW2, simb2, NPAIR, nullptr,
                                                   probs + (t - 1) * NENT, pso, newe);
        k_clampstore<<<40, 256, 0, stream>>>(newe, probs + t * NENT, NENT);
    }

    // 7) hop attention + final mix
    k_mvpart<<<dim3(4, 6, 1), B256, 0, stream>>>(q, 0, hW1, hacc, D, 256, 6);
    k_biasact<<<dim3(1, 1), B256, 0, stream>>>(hacc, hb1, hh, 256, 6, 1);
    k_dot3<<<1, B256, 0, stream>>>(hh, hW2, hb2, hlog);
    k_final<<<40, 256, 0, stream>>>(probs, hlog, (float*)d_out, NENT);
}

// Round 14
// 1199.089 us; speedup vs baseline: 1.4032x; 1.4032x over previous
//
#include <hip/hip_runtime.h>
#include <math.h>

// ---------------------------------------------------------------------------
#define D 768
#define NPARA 32
#define LPARA 512
#define LQ 32
#define NENT 10000
#define MMENT 30000
#define NPAIR 20000
#define NSTEP 3

using bf16x8 = __attribute__((ext_vector_type(8))) short;
using f32x4  = __attribute__((ext_vector_type(4))) float;

__device__ __forceinline__ float geluf(float x) {
    return 0.5f * x * (1.0f + erff(x * 0.70710678118654752f));
}
__device__ __forceinline__ float bf2f(ushort h) {
    union { unsigned u; float f; } v; v.u = ((unsigned)h) << 16; return v.f;
}
// round-to-nearest-even fp32 -> bf16
__device__ __forceinline__ ushort bfrne(float x) {
    union { float f; unsigned u; } v; v.f = x;
    unsigned r = (v.u + 0x7FFF + ((v.u >> 16) & 1)) >> 16;
    return (ushort)r;
}

// ---------------------------------------------------------------------------
// Single-plane bf16 MFMA GEMM. Tile (MI*32) x 128, A+B LDS (XOR-swizzled),
// register prefetch of next A and B tiles, band-major XCD swizzle.
// MI=2: 64x128 (wave 32x64)  -- small-M / N=256 GEMMs (~60 VGPR)
// MI=4: 128x128 (wave 64x64) -- M=20000 GEMMs (~140 VGPR: acc 64 + prefetch)
// launch_bounds(256,3): 170-reg budget. (256,4)=128 spilled MI=4 (R13:
// VGPR 64, WRITE 772MB scratch traffic); (256,5)=102 spilled MI=2 (R11).
// MODE 0: A = bf16 plane [M][K]
// MODE 1: A row r = concat(para[p,t1,:], para[p,t2,:]) fp32 gather, K=1536
// MODE 2: A sections {S, O, SO} per k-tile (SO precomputed; Ah = SO plane)
// B: pre-transposed bf16 weights WT[N][K]. OUTP 0: fp32 C; 1: bf16 C.
// ---------------------------------------------------------------------------
#define BN 128

__device__ __forceinline__ int ldso(int row, int kb) {   // kb = byte offset
    return row * 64 + (((kb) ^ ((row & 7) << 4)) >> 1);
}

template <int MODE, int ACT, int OUTP, int MI>
__global__ __launch_bounds__(256, 3) void gemm_m(
    const ushort* __restrict__ Ah,
    const float* __restrict__ para, const int* __restrict__ ppos, int c1, int c2,
    const ushort* __restrict__ Sh, const ushort* __restrict__ Oh,
    const ushort* __restrict__ Bh, const float* __restrict__ bias,
    float* __restrict__ Cf, ushort* __restrict__ Ch,
    int M, int N, int K, int nby)
{
    constexpr int BM = MI * 32;
    constexpr int TPR = 256 / BM;    // threads per A-row (4 or 2)
    constexpr int SPAN = 64 / TPR;   // ushorts per thread per A-row (16 or 32)
    constexpr int NV = SPAN / 8;     // bf16x8 vectors per thread (2 or 4)

    __shared__ ushort sA[BM * 64];   //  8 or 16 KB
    __shared__ ushort sB[BN * 64];   // 16 KB

    const int nwg = gridDim.x;
    const int q = nwg >> 3, r = nwg & 7;
    const int xcd = blockIdx.x & 7, idx = blockIdx.x >> 3;
    const int wgid = (xcd < r) ? xcd * (q + 1) + idx
                               : r * (q + 1) + (xcd - r) * q + idx;
    const int m0 = (wgid / nby) * BM;
    const int n0 = (wgid % nby) * BN;

    const int tid = threadIdx.x;
    const int lane = tid & 63;
    const int wv = tid >> 6;
    const int wr = (wv >> 1) * (MI * 16);
    const int wc = (wv & 1) * 64;
    const int ln = lane & 15;
    const int kg = lane >> 4;

    f32x4 acc[MI][4];
#pragma unroll
    for (int i = 0; i < MI; ++i)
#pragma unroll
        for (int j = 0; j < 4; ++j)
#pragma unroll
            for (int e = 0; e < 4; ++e) acc[i][j][e] = 0.0f;

    const int arow = tid / TPR, aq = tid % TPR;
    const int brow = tid >> 1, bq = tid & 1;
    const int gm = m0 + arow;
    const bool ok = gm < M;

    int baseL = 0, baseR = 0;
    if (MODE == 1 && ok) {
        int p = ppos[gm * 5];
        baseL = (p * LPARA + ppos[gm * 5 + c1]) * D;
        baseR = (p * LPARA + ppos[gm * 5 + c2]) * D;
    }

    bf16x8 pa[NV];           // MODE 0/2 prefetch
    float4 pf[2 * NV];       // MODE 1 prefetch
    bf16x8 pb[4];            // B prefetch (64B/thread)

    auto prefA = [&](int kt) {
        if (MODE == 0 || MODE == 2) {
            const ushort* pl;
            int koff;
            if (MODE == 0) { pl = Ah; koff = kt; }
            else {
                const int sec = kt / D;
                pl = (sec == 0) ? Sh : (sec == 1) ? Oh : Ah;   // Ah = SO plane
                koff = kt - sec * D;
            }
            if (ok) {
                const ushort* g = pl + (size_t)gm * ((MODE == 0) ? K : D)
                                + koff + aq * SPAN;
#pragma unroll
                for (int i = 0; i < NV; ++i) pa[i] = *(const bf16x8*)(g + i * 8);
            } else {
#pragma unroll
                for (int i = 0; i < NV; ++i)
#pragma unroll
                    for (int z = 0; z < 8; ++z) pa[i][z] = 0;
            }
        } else {   // MODE 1
            const int kb = kt + aq * SPAN;         // tile never crosses D bound
            const int gb = (kb < D) ? (baseL + kb) : (baseR + kb - D);
#pragma unroll
            for (int j = 0; j < 2 * NV; ++j)
                pf[j] = ok ? *(const float4*)(para + gb + j * 4)
                           : make_float4(0.f, 0.f, 0.f, 0.f);
        }
    };

    auto prefB = [&](int kt) {
        const ushort* g = Bh + (size_t)(n0 + brow) * K + kt + bq * 32;
#pragma unroll
        for (int i = 0; i < 4; ++i)
            pb[i] = *(const bf16x8*)(g + i * 8);
    };

    auto storeAB = [&]() {
        if (MODE == 0 || MODE == 2) {
#pragma unroll
            for (int i = 0; i < NV; ++i)
                *(bf16x8*)&sA[ldso(arow, aq * SPAN * 2 + i * 16)] = pa[i];
        } else {
#pragma unroll
            for (int j = 0; j < 2 * NV; ++j) {
                ushort4 h;
                h.x = bfrne(pf[j].x); h.y = bfrne(pf[j].y);
                h.z = bfrne(pf[j].z); h.w = bfrne(pf[j].w);
                *(ushort4*)&sA[ldso(arow, aq * SPAN * 2 + j * 8)] = h;
            }
        }
#pragma unroll
        for (int i = 0; i < 4; ++i)
            *(bf16x8*)&sB[ldso(brow, bq * 64 + i * 16)] = pb[i];
    };

    prefA(0);
    prefB(0);

    for (int kt = 0; kt < K; kt += 64) {
        if (kt > 0) __syncthreads();
        storeAB();
        __syncthreads();

        const int ktn = kt + 64;
        if (ktn < K) { prefA(ktn); prefB(ktn); }

#pragma unroll
        for (int ks = 0; ks < 2; ++ks) {
            bf16x8 fb[4];
#pragma unroll
            for (int ni = 0; ni < 4; ++ni)
                fb[ni] = *(const bf16x8*)&sB[ldso(wc + ni * 16 + ln, ks * 64 + kg * 16)];
#pragma unroll
            for (int mi = 0; mi < MI; ++mi) {
                bf16x8 fa = *(const bf16x8*)&sA[ldso(wr + mi * 16 + ln, ks * 64 + kg * 16)];
#pragma unroll
                for (int ni = 0; ni < 4; ++ni)
                    acc[mi][ni] = __builtin_amdgcn_mfma_f32_16x16x32_bf16(
                        fa, fb[ni], acc[mi][ni], 0, 0, 0);
            }
        }
    }

    // epilogue: row = (lane>>4)*4+reg, col = lane&15
#pragma unroll
    for (int mi = 0; mi < MI; ++mi)
#pragma unroll
        for (int ni = 0; ni < 4; ++ni) {
            int col = n0 + wc + ni * 16 + ln;
            f32x4 a = acc[mi][ni];
#pragma unroll
            for (int j = 0; j < 4; ++j) {
                int row = m0 + wr + mi * 16 + kg * 4 + j;
                if (row < M) {
                    float v = a[j] + bias[col];
                    if (ACT == 1) v = geluf(v);
                    if (OUTP == 0) Cf[(size_t)row * N + col] = v;
                    else           Ch[(size_t)row * N + col] = bfrne(v);
                }
            }
        }
}

// ---------------------------------------------------------------------------
// SO[i] = bf16(S[i] * O[i])  (vector ushort4)
__global__ void k_so(const ushort* __restrict__ S, const ushort* __restrict__ O,
                     ushort* __restrict__ SO, int n4)
{
    int i = blockIdx.x * blockDim.x + threadIdx.x;
    if (i >= n4) return;
    ushort4 s = ((const ushort4*)S)[i];
    ushort4 o = ((const ushort4*)O)[i];
    ushort4 r;
    r.x = bfrne(bf2f(s.x) * bf2f(o.x));
    r.y = bfrne(bf2f(s.y) * bf2f(o.y));
    r.z = bfrne(bf2f(s.z) * bf2f(o.z));
    r.w = bfrne(bf2f(s.w) * bf2f(o.w));
    ((ushort4*)SO)[i] = r;
}

// ---------------------------------------------------------------------------
// Weight transpose: W[K][N] fp32 -> WT[N][K] bf16 (RNE)
__global__ __launch_bounds__(256) void k_wt(const float* __restrict__ W,
                                            ushort* __restrict__ WTh, int K, int N)
{
    __shared__ float t[32][33];
    const int k0 = blockIdx.x * 32, n0 = blockIdx.y * 32;
    const int c = threadIdx.x & 31, r8 = threadIdx.x >> 5;
#pragma unroll
    for (int i = 0; i < 4; ++i) {
        int r = r8 + i * 8;
        t[r][c] = W[(size_t)(k0 + r) * N + n0 + c];
    }
    __syncthreads();
#pragma unroll
    for (int i = 0; i < 4; ++i) {
        int r = r8 + i * 8;
        WTh[(size_t)(n0 + r) * K + k0 + c] = bfrne(t[c][r]);
    }
}

// folded pair W1: Wf[2304][768] from pW1[3072][768]
__global__ void k_fold(const float* __restrict__ pW1, float* __restrict__ Wf, int n)
{
    int i = blockIdx.x * blockDim.x + threadIdx.x;
    if (i >= n) return;
    int row = i / D;
    float v;
    if (row < D)            v = pW1[i] - pW1[i + 1536 * D];
    else if (row < 2 * D)   v = pW1[i] + pW1[i + 768 * D];
    else                    v = pW1[i + 768 * D];
    Wf[i] = v;
}

__global__ __launch_bounds__(256) void k_entmean(
    const float* __restrict__ para, const int* __restrict__ mpos,
    const int* __restrict__ mid, int M, ushort* __restrict__ oh)
{
    __shared__ int sb[2];
    const int e = blockIdx.x;
    if (threadIdx.x < 2) {
        int target = e + threadIdx.x;
        int lo = 0, hi = M;
        while (lo < hi) {
            int md = (lo + hi) >> 1;
            if (mid[md] < target) lo = md + 1; else hi = md;
        }
        sb[threadIdx.x] = lo;
    }
    __syncthreads();
    const int lo = sb[0], hi = sb[1];
    const int tid = threadIdx.x;
    float a0 = 0, a1 = 0, a2 = 0, b0 = 0, b1 = 0, b2 = 0;
    for (int m = lo; m < hi; ++m) {
        int p = mpos[m * 3], t1 = mpos[m * 3 + 1], t2 = mpos[m * 3 + 2];
        const float* L = para + (size_t)(p * LPARA + t1) * D;
        const float* R = para + (size_t)(p * LPARA + t2) * D;
        a0 += L[tid]; a1 += L[tid + 256]; a2 += L[tid + 512];
        b0 += R[tid]; b1 += R[tid + 256]; b2 += R[tid + 512];
    }
    const float inv = (hi > lo) ? 1.0f / (float)(hi - lo) : 0.0f;
    size_t base = (size_t)e * (2 * D);
    float vals[6] = { a0 * inv, a1 * inv, a2 * inv, b0 * inv, b1 * inv, b2 * inv };
    int offs[6] = { tid, tid + 256, tid + 512, D + tid, D + tid + 256, D + tid + 512 };
#pragma unroll
    for (int i = 0; i < 6; ++i) oh[base + offs[i]] = bfrne(vals[i]);
}

// ---------------------------------------------------------------------------
// Batched split-K matvec (deterministic). grid (N/64, nks, T).
__global__ __launch_bounds__(256) void k_mvpart(
    const float* __restrict__ x, int xstride,
    const float* __restrict__ W, float* __restrict__ acc, int K, int N, int nks)
{
    const int t = blockIdx.z;
    const float* xt = x + (size_t)t * xstride;
    const float* Wt = W + (size_t)t * K * N;
    const int jj = threadIdx.x & 63;
    const int kq = threadIdx.x >> 6;
    const int j = blockIdx.x * 64 + jj;
    const int kchunk = K / (nks * 4);
    const int kbeg = (blockIdx.y * 4 + kq) * kchunk;
    float s = 0.0f;
    for (int k = kbeg; k < kbeg + kchunk; ++k)
        s = fmaf(xt[k], Wt[(size_t)k * N + j], s);
    __shared__ float red[256];
    red[threadIdx.x] = s;
    __syncthreads();
    if (kq == 0) {
        float v = red[jj] + red[64 + jj] + red[128 + jj] + red[192 + jj];
        acc[((size_t)(t * nks) + blockIdx.y) * N + j] = v;
    }
}

__global__ void k_biasact(const float* __restrict__ acc, const float* __restrict__ b,
                          float* __restrict__ out, int N, int nks, int act)
{
    const int t = blockIdx.y;
    const int j = blockIdx.x * 256 + threadIdx.x;
    if (j >= N) return;
    float s = 0.0f;
    for (int i = 0; i < nks; ++i) s += acc[((size_t)(t * nks) + i) * N + j];
    s += b[(size_t)t * N + j];
    if (act) s = geluf(s);
    out[(size_t)t * N + j] = s;
}

__global__ void k_dot3(const float* __restrict__ x, const float* __restrict__ W,
                       const float* __restrict__ b, float* __restrict__ out)
{
    int j = threadIdx.x >> 6, lane = threadIdx.x & 63;
    if (j >= 3) return;
    float s = 0.0f;
#pragma unroll
    for (int i = 0; i < 4; ++i) {
        int k = lane + i * 64;
        s += x[k] * W[k * 3 + j];
    }
    for (int off = 32; off > 0; off >>= 1) s += __shfl_down(s, off, 64);
    if (lane == 0) out[j] = s + b[j];
}

__global__ void k_ctx3(const float* __restrict__ cq3, const float* __restrict__ qwh,
                       float* __restrict__ ctx3)
{
    const float* cq = cq3 + (size_t)blockIdx.x * D;
    float* ctx = ctx3 + (size_t)blockIdx.x * D;
    __shared__ float red[256];
    __shared__ float dist[LQ];
    const int tid = threadIdx.x;
    const int l = tid >> 3, part = tid & 7;
    float s = 0.0f;
    for (int d = part; d < D; d += 8) s += cq[d] * qwh[l * D + d];
    red[tid] = s;
    __syncthreads();
    if (part == 0) {
        float v = 0;
        for (int i = 0; i < 8; ++i) v += red[l * 8 + i];
        dist[l] = v;
    }
    __syncthreads();
    if (tid == 0) {
        float mx = -1e30f;
        for (int i = 0; i < LQ; ++i) mx = fmaxf(mx, dist[i]);
        float sm = 0;
        for (int i = 0; i < LQ; ++i) { float e = expf(dist[i] - mx); dist[i] = e; sm += e; }
        float inv = 1.0f / sm;
        for (int i = 0; i < LQ; ++i) dist[i] *= inv;
    }
    __syncthreads();
    for (int d = tid; d < D; d += 256) {
        float v = 0;
#pragma unroll
        for (int l2 = 0; l2 < LQ; ++l2) v += dist[l2] * qwh[l2 * D + d];
        ctx[d] = v + cq[d];
    }
}

__global__ void k_scalew(const float* __restrict__ ctx, const float* __restrict__ w1,
                         float* __restrict__ o, int n)
{
    int i = blockIdx.x * 256 + threadIdx.x;
    if (i < n) o[i] = ctx[i >> 8] * w1[i];
}

template <int PAIRMODE>
__global__ void k_rowdot(const float* __restrict__ H, const float* __restrict__ w2,
                         const float* __restrict__ sb2, int Nr,
                         float* __restrict__ simout,
                         const float* __restrict__ laste, const int* __restrict__ so,
                         float* __restrict__ newe)
{
    int r = blockIdx.x * 4 + (threadIdx.x >> 6);
    int lane = threadIdx.x & 63;
    if (r >= Nr) return;
    float s = 0.0f;
#pragma unroll
    for (int i = 0; i < 4; ++i)
        s += H[(size_t)r * 256 + lane + i * 64] * w2[lane + i * 64];
    for (int off = 32; off > 0; off >>= 1) s += __shfl_down(s, off, 64);
    if (lane == 0) {
        s += sb2[0];
        if (PAIRMODE == 0) {
            simout[r] = s;
        } else {
            float p = 1.0f / (1.0f + expf(-s));
            float v = laste[so[r * 2]] * p;
            atomicAdd(&newe[so[r * 2 + 1]], v);
        }
    }
}

__global__ void k_softmax(const float* __restrict__ sim, float* __restrict__ outp, int n)
{
    __shared__ float red[256];
    __shared__ float s_mx, s_sum;
    const int tid = threadIdx.x;
    float mx = -1e30f;
    for (int i = tid; i < n; i += 256) mx = fmaxf(mx, sim[i]);
    red[tid] = mx; __syncthreads();
    for (int off = 128; off > 0; off >>= 1) {
        if (tid < off) red[tid] = fmaxf(red[tid], red[tid + off]);
        __syncthreads();
    }
    if (tid == 0) s_mx = red[0];
    __syncthreads();
    const float mxv = s_mx;
    float sum = 0;
    for (int i = tid; i < n; i += 256) sum += expf(sim[i] - mxv);
    red[tid] = sum; __syncthreads();
    for (int off = 128; off > 0; off >>= 1) {
        if (tid < off) red[tid] += red[tid + off];
        __syncthreads();
    }
    if (tid == 0) s_sum = red[0];
    __syncthreads();
    const float inv = 1.0f / s_sum;
    for (int i = tid; i < n; i += 256) {
        float v = expf(sim[i] - mxv) * inv;
        outp[i] = v / fmaxf(v, 1.0f);
    }
}

__global__ void k_zero(float* p, int n)
{
    int i = blockIdx.x * blockDim.x + threadIdx.x;
    if (i < n) p[i] = 0.0f;
}

__global__ void k_clampstore(const float* __restrict__ ne, float* __restrict__ outp, int n)
{
    int i = blockIdx.x * blockDim.x + threadIdx.x;
    if (i < n) { float v = ne[i]; outp[i] = v / fmaxf(v, 1.0f); }
}

__global__ void k_final(const float* __restrict__ probs, const float* __restrict__ hlog,
                        float* __restrict__ out, int n)
{
    int i = blockIdx.x * blockDim.x + threadIdx.x;
    if (i >= n) return;
    float l0 = hlog[0], l1 = hlog[1], l2 = hlog[2];
    float m = fmaxf(l0, fmaxf(l1, l2));
    float e0 = expf(l0 - m), e1 = expf(l1 - m), e2 = expf(l2 - m);
    float inv = 1.0f / (e0 + e1 + e2);
    out[i] = (e0 * probs[i] + e1 * probs[n + i] + e2 * probs[2 * n + i]) * inv;
}

// ---------------------------------------------------------------------------
extern "C" void kernel_launch(void* const* d_in, const int* in_sizes, int n_in,
                              void* d_out, int out_size, void* d_ws, size_t ws_size,
                              hipStream_t stream)
{
    const size_t WS_NEED = 148793744;  // 141.9 MiB
    if (ws_size < WS_NEED) return;

    const float* para  = (const float*)d_in[0];
    const float* q     = (const float*)d_in[1];
    const float* qwh   = (const float*)d_in[2];
    const float* stW1  = (const float*)d_in[3];
    const float* stb1  = (const float*)d_in[4];
    const float* stW2  = (const float*)d_in[5];
    const float* stb2  = (const float*)d_in[6];
    const float* mW1   = (const float*)d_in[7];
    const float* mb1   = (const float*)d_in[8];
    const float* mW2   = (const float*)d_in[9];
    const float* mb2   = (const float*)d_in[10];
    const float* pW1   = (const float*)d_in[11];
    const float* pb1   = (const float*)d_in[12];
    const float* pW2   = (const float*)d_in[13];
    const float* pb2   = (const float*)d_in[14];
    const float* simW1 = (const float*)d_in[15];
    const float* simb1 = (const float*)d_in[16];
    const float* simW2 = (const float*)d_in[17];
    const float* simb2 = (const float*)d_in[18];
    const float* hW1   = (const float*)d_in[19];
    const float* hb1   = (const float*)d_in[20];
    const float* hW2   = (const float*)d_in[21];
    const float* hb2   = (const float*)d_in[22];
    const int*   mpos  = (const int*)d_in[23];
    const int*   mid   = (const int*)d_in[24];
    const int*   ppos  = (const int*)d_in[25];
    const int*   pso   = (const int*)d_in[26];

    // ---- workspace layout (single bf16 planes) ----
    ushort* P1   = (ushort*)d_ws;          // 15,360,000 (EM -> sub_feat -> pair_emb)
    ushort* HID  = P1  + 15360000;         // 15,360,000 (hidden; H256 fp32 overlay)
    ushort* OBJ  = HID + 15360000;         // 15,360,000 (Wfold tmp -> obj_feat)
    ushort* SOp  = OBJ + 15360000;         // 15,360,000 (sub*obj plane)
    ushort* E    = SOp + 15360000;         //  7,680,000 (ent_emb)
    ushort* mW1T = E    + 7680000;         //  1,179,648
    ushort* mW2T = mW1T + 1179648;         //    589,824
    ushort* WfT  = mW2T + 589824;          //  1,769,472 ([768][2304] folded)
    ushort* pW2T = WfT  + 1769472;         //    589,824
    ushort* W1sT0 = pW2T + 589824;         //    589,824 (3 x 196,608)
    float*  W1s   = (float*)(W1sT0 + 589824);  // 196,608
    float*  simb  = W1s  + 196608;         // 20,000
    float*  probs = simb + 20000;          // 30,000
    float*  newe  = probs + 30000;         // 10,000
    float*  acc3  = newe + 10000;          // 13,824
    float*  h3    = acc3 + 13824;          // 2,304
    float*  cq3   = h3   + 2304;           // 2,304
    float*  ctx3  = cq3  + 2304;           // 2,304
    float*  hacc  = ctx3 + 2304;           // 1,536
    float*  hh    = hacc + 1536;           // 256
    float*  hlog  = hh   + 256;            // 4
    float*  H256  = (float*)HID;           // 20000x256 fp32 overlay (HID dead then)
    float*  Wfold = (float*)OBJ;           // fp32 tmp (dead before OBJ written)

    dim3 B256(256);
    const ushort* np = nullptr;

    // 0) weight prep
    k_fold<<<(2304 * D + 255) / 256, B256, 0, stream>>>(pW1, Wfold, 2304 * D);
    k_wt<<<dim3(48, 24), B256, 0, stream>>>(mW1, mW1T, 2 * D, D);
    k_wt<<<dim3(24, 24), B256, 0, stream>>>(mW2, mW2T, D, D);
    k_wt<<<dim3(72, 24), B256, 0, stream>>>(Wfold, WfT, 3 * D, D);
    k_wt<<<dim3(24, 24), B256, 0, stream>>>(pW2, pW2T, D, D);

    // 1) batched step MLPs + ctx + scaled sim weights
    k_mvpart<<<dim3(12, 6, 3), B256, 0, stream>>>(q, 0, stW1, acc3, D, D, 6);
    k_biasact<<<dim3(3, 3), B256, 0, stream>>>(acc3, stb1, h3, D, 6, 1);
    k_mvpart<<<dim3(12, 6, 3), B256, 0, stream>>>(h3, D, stW2, acc3, D, D, 6);
    k_biasact<<<dim3(3, 3), B256, 0, stream>>>(acc3, stb2, cq3, D, 6, 0);
    k_ctx3<<<3, B256, 0, stream>>>(cq3, qwh, ctx3);
    for (int t = 0; t < NSTEP; ++t) {
        k_scalew<<<768, 256, 0, stream>>>(ctx3 + (size_t)t * D, simW1, W1s, D * 256);
        k_wt<<<dim3(24, 8), B256, 0, stream>>>(W1s, W1sT0 + t * 196608, D, 256);
    }

    // 2) entity mention means -> P1 (10000 x 1536 bf16)
    k_entmean<<<NENT, 256, 0, stream>>>(para, mpos, mid, MMENT, P1);

    // 3) ent_emb (M=10000: MI=2, grid 942)
    gemm_m<0, 1, 1, 2><<<942, B256, 0, stream>>>(P1, nullptr, nullptr, 0, 0, np, np,
        mW1T, mb1, nullptr, HID, NENT, D, 2 * D, 6);
    gemm_m<0, 0, 1, 2><<<942, B256, 0, stream>>>(HID, nullptr, nullptr, 0, 0, np, np,
        mW2T, mb2, nullptr, E, NENT, D, D, 6);

    // 4) step 0: sim on entities -> probs[0]
    gemm_m<0, 1, 0, 2><<<314, B256, 0, stream>>>(E, nullptr, nullptr, 0, 0, np, np,
        W1sT0, simb1, H256, nullptr, NENT, 256, D, 2);
    k_rowdot<0><<<NENT / 4, 256, 0, stream>>>(H256, simW2, simb2, NENT, simb,
                                              nullptr, nullptr, nullptr);
    k_softmax<<<1, 256, 0, stream>>>(simb, probs, NENT);

    // 5) pair pipeline (M=20000: MI=4, grid 157x6=942)
    gemm_m<1, 1, 1, 4><<<942, B256, 0, stream>>>(np, para, ppos, 1, 2, np, np,
        mW1T, mb1, nullptr, HID, NPAIR, D, 2 * D, 6);
    gemm_m<0, 0, 1, 4><<<942, B256, 0, stream>>>(HID, nullptr, nullptr, 0, 0, np, np,
        mW2T, mb2, nullptr, P1, NPAIR, D, D, 6);
    gemm_m<1, 1, 1, 4><<<942, B256, 0, stream>>>(np, para, ppos, 3, 4, np, np,
        mW1T, mb1, nullptr, HID, NPAIR, D, 2 * D, 6);
    gemm_m<0, 0, 1, 4><<<942, B256, 0, stream>>>(HID, nullptr, nullptr, 0, 0, np, np,
        mW2T, mb2, nullptr, OBJ, NPAIR, D, D, 6);
    k_so<<<15000, B256, 0, stream>>>(P1, OBJ, SOp, NPAIR * D / 4);
    gemm_m<2, 1, 1, 4><<<942, B256, 0, stream>>>(SOp, nullptr, nullptr, 0, 0, P1, OBJ,
        WfT, pb1, nullptr, HID, NPAIR, D, 3 * D, 6);
    gemm_m<0, 0, 1, 4><<<942, B256, 0, stream>>>(HID, nullptr, nullptr, 0, 0, np, np,
        pW2T, pb2, nullptr, P1, NPAIR, D, D, 6);

    // 6) steps 1,2: sim on pairs + scatter-propagate (MI=2, grid 626)
    for (int t = 1; t < NSTEP; ++t) {
        gemm_m<0, 1, 0, 2><<<626, B256, 0, stream>>>(P1, nullptr, nullptr, 0, 0, np, np,
            W1sT0 + t * 196608, simb1, H256, nullptr, NPAIR, 256, D, 2);
        k_zero<<<40, 256, 0, stream>>>(newe, NENT);
        k_rowdot<1><<<NPAIR / 4, 256, 0, stream>>>(H256, simW2, simb2, NPAIR, nullptr,
                                                   probs + (t - 1) * NENT, pso, newe);
        k_clampstore<<<40, 256, 0, stream>>>(newe, probs + t * NENT, NENT);
    }

    // 7) hop attention + final mix
    k_mvpart<<<dim3(4, 6, 1), B256, 0, stream>>>(q, 0, hW1, hacc, D, 256, 6);
    k_biasact<<<dim3(1, 1), B256, 0, stream>>>(hacc, hb1, hh, 256, 6, 1);
    k_dot3<<<1, B256, 0, stream>>>(hh, hW2, hb2, hlog);
    k_final<<<40, 256, 0, stream>>>(probs, hlog, (float*)d_out, NENT);
}

// Round 16
// 1026.377 us; speedup vs baseline: 1.6393x; 1.1683x over previous
//
#include <hip/hip_runtime.h>
#include <math.h>

// ---------------------------------------------------------------------------
#define D 768
#define NPARA 32
#define LPARA 512
#define LQ 32
#define NENT 10000
#define MMENT 30000
#define NPAIR 20000
#define NSTEP 3

using bf16x8 = __attribute__((ext_vector_type(8))) short;
using f32x4  = __attribute__((ext_vector_type(4))) float;

__device__ __forceinline__ float geluf(float x) {
    return 0.5f * x * (1.0f + erff(x * 0.70710678118654752f));
}
__device__ __forceinline__ float bf2f(ushort h) {
    union { unsigned u; float f; } v; v.u = ((unsigned)h) << 16; return v.f;
}
// round-to-nearest-even fp32 -> bf16
__device__ __forceinline__ ushort bfrne(float x) {
    union { float f; unsigned u; } v; v.f = x;
    unsigned r = (v.u + 0x7FFF + ((v.u >> 16) & 1)) >> 16;
    return (ushort)r;
}

// ---------------------------------------------------------------------------
// Single-plane bf16 MFMA GEMM. 64x128 tile (MI=2 ONLY — the R12 known-good
// config: VGPR 60, no spill). MI=4 at launch_bounds (256,4) and (256,3)
// both scratch-spilled (R13: VGPR 64 / WRITE 772MB; R14: VGPR 72 / 455MB)
// — do not revisit without -Rpass-analysis visibility.
// A+B LDS (XOR-swizzled), register prefetch of next A+B tiles, band-major
// XCD swizzle.
// MODE 0: A = bf16 plane [M][K]
// MODE 1: A row r = concat(para[p,t1,:], para[p,t2,:]) fp32 gather, K=1536
// MODE 2: A sections {S, O, SO} per k-tile, plane-select only (SO
//         precomputed by k_so; Ah = SO plane), K=2304
// B: pre-transposed bf16 weights WT[N][K]. OUTP 0: fp32 C; 1: bf16 C.
// ---------------------------------------------------------------------------
#define BN 128

__device__ __forceinline__ int ldso(int row, int kb) {   // kb = byte offset
    return row * 64 + (((kb) ^ ((row & 7) << 4)) >> 1);
}

template <int MODE, int ACT, int OUTP>
__global__ __launch_bounds__(256, 4) void gemm_m(
    const ushort* __restrict__ Ah,
    const float* __restrict__ para, const int* __restrict__ ppos, int c1, int c2,
    const ushort* __restrict__ Sh, const ushort* __restrict__ Oh,
    const ushort* __restrict__ Bh, const float* __restrict__ bias,
    float* __restrict__ Cf, ushort* __restrict__ Ch,
    int M, int N, int K, int nby)
{
    constexpr int BM = 64;
    constexpr int TPR = 4;           // threads per A-row
    constexpr int SPAN = 16;         // ushorts per thread per A-row
    constexpr int NV = 2;            // bf16x8 vectors per thread

    __shared__ ushort sA[BM * 64];   //  8 KB
    __shared__ ushort sB[BN * 64];   // 16 KB

    const int nwg = gridDim.x;
    const int q = nwg >> 3, r = nwg & 7;
    const int xcd = blockIdx.x & 7, idx = blockIdx.x >> 3;
    const int wgid = (xcd < r) ? xcd * (q + 1) + idx
                               : r * (q + 1) + (xcd - r) * q + idx;
    const int m0 = (wgid / nby) * BM;
    const int n0 = (wgid % nby) * BN;

    const int tid = threadIdx.x;
    const int lane = tid & 63;
    const int wv = tid >> 6;
    const int wr = (wv >> 1) * 32;
    const int wc = (wv & 1) * 64;
    const int ln = lane & 15;
    const int kg = lane >> 4;

    f32x4 acc[2][4];
#pragma unroll
    for (int i = 0; i < 2; ++i)
#pragma unroll
        for (int j = 0; j < 4; ++j)
#pragma unroll
            for (int e = 0; e < 4; ++e) acc[i][j][e] = 0.0f;

    const int arow = tid / TPR, aq = tid % TPR;
    const int brow = tid >> 1, bq = tid & 1;
    const int gm = m0 + arow;
    const bool ok = gm < M;

    int baseL = 0, baseR = 0;
    if (MODE == 1 && ok) {
        int p = ppos[gm * 5];
        baseL = (p * LPARA + ppos[gm * 5 + c1]) * D;
        baseR = (p * LPARA + ppos[gm * 5 + c2]) * D;
    }

    bf16x8 pa[NV];           // MODE 0/2 prefetch
    float4 pf[2 * NV];       // MODE 1 prefetch
    bf16x8 pb[4];            // B prefetch (64B/thread)

    auto prefA = [&](int kt) {
        if (MODE == 0 || MODE == 2) {
            const ushort* pl;
            int koff;
            if (MODE == 0) { pl = Ah; koff = kt; }
            else {
                const int sec = kt / D;
                pl = (sec == 0) ? Sh : (sec == 1) ? Oh : Ah;   // Ah = SO plane
                koff = kt - sec * D;
            }
            if (ok) {
                const ushort* g = pl + (size_t)gm * ((MODE == 0) ? K : D)
                                + koff + aq * SPAN;
#pragma unroll
                for (int i = 0; i < NV; ++i) pa[i] = *(const bf16x8*)(g + i * 8);
            } else {
#pragma unroll
                for (int i = 0; i < NV; ++i)
#pragma unroll
                    for (int z = 0; z < 8; ++z) pa[i][z] = 0;
            }
        } else {   // MODE 1
            const int kb = kt + aq * SPAN;         // tile never crosses D bound
            const int gb = (kb < D) ? (baseL + kb) : (baseR + kb - D);
#pragma unroll
            for (int j = 0; j < 2 * NV; ++j)
                pf[j] = ok ? *(const float4*)(para + gb + j * 4)
                           : make_float4(0.f, 0.f, 0.f, 0.f);
        }
    };

    auto prefB = [&](int kt) {
        const ushort* g = Bh + (size_t)(n0 + brow) * K + kt + bq * 32;
#pragma unroll
        for (int i = 0; i < 4; ++i)
            pb[i] = *(const bf16x8*)(g + i * 8);
    };

    auto storeAB = [&]() {
        if (MODE == 0 || MODE == 2) {
#pragma unroll
            for (int i = 0; i < NV; ++i)
                *(bf16x8*)&sA[ldso(arow, aq * SPAN * 2 + i * 16)] = pa[i];
        } else {
#pragma unroll
            for (int j = 0; j < 2 * NV; ++j) {
                ushort4 h;
                h.x = bfrne(pf[j].x); h.y = bfrne(pf[j].y);
                h.z = bfrne(pf[j].z); h.w = bfrne(pf[j].w);
                *(ushort4*)&sA[ldso(arow, aq * SPAN * 2 + j * 8)] = h;
            }
        }
#pragma unroll
        for (int i = 0; i < 4; ++i)
            *(bf16x8*)&sB[ldso(brow, bq * 64 + i * 16)] = pb[i];
    };

    prefA(0);
    prefB(0);

    for (int kt = 0; kt < K; kt += 64) {
        if (kt > 0) __syncthreads();
        storeAB();
        __syncthreads();

        const int ktn = kt + 64;
        if (ktn < K) { prefA(ktn); prefB(ktn); }

#pragma unroll
        for (int ks = 0; ks < 2; ++ks) {
            bf16x8 fb[4];
#pragma unroll
            for (int ni = 0; ni < 4; ++ni)
                fb[ni] = *(const bf16x8*)&sB[ldso(wc + ni * 16 + ln, ks * 64 + kg * 16)];
#pragma unroll
            for (int mi = 0; mi < 2; ++mi) {
                bf16x8 fa = *(const bf16x8*)&sA[ldso(wr + mi * 16 + ln, ks * 64 + kg * 16)];
#pragma unroll
                for (int ni = 0; ni < 4; ++ni)
                    acc[mi][ni] = __builtin_amdgcn_mfma_f32_16x16x32_bf16(
                        fa, fb[ni], acc[mi][ni], 0, 0, 0);
            }
        }
    }

    // epilogue: row = (lane>>4)*4+reg, col = lane&15
#pragma unroll
    for (int mi = 0; mi < 2; ++mi)
#pragma unroll
        for (int ni = 0; ni < 4; ++ni) {
            int col = n0 + wc + ni * 16 + ln;
            f32x4 a = acc[mi][ni];
#pragma unroll
            for (int j = 0; j < 4; ++j) {
                int row = m0 + wr + mi * 16 + kg * 4 + j;
                if (row < M) {
                    float v = a[j] + bias[col];
                    if (ACT == 1) v = geluf(v);
                    if (OUTP == 0) Cf[(size_t)row * N + col] = v;
                    else           Ch[(size_t)row * N + col] = bfrne(v);
                }
            }
        }
}

// ---------------------------------------------------------------------------
// SO[i] = bf16(S[i] * O[i])  (vector ushort4)
__global__ void k_so(const ushort* __restrict__ S, const ushort* __restrict__ O,
                     ushort* __restrict__ SO, int n4)
{
    int i = blockIdx.x * blockDim.x + threadIdx.x;
    if (i >= n4) return;
    ushort4 s = ((const ushort4*)S)[i];
    ushort4 o = ((const ushort4*)O)[i];
    ushort4 r;
    r.x = bfrne(bf2f(s.x) * bf2f(o.x));
    r.y = bfrne(bf2f(s.y) * bf2f(o.y));
    r.z = bfrne(bf2f(s.z) * bf2f(o.z));
    r.w = bfrne(bf2f(s.w) * bf2f(o.w));
    ((ushort4*)SO)[i] = r;
}

// ---------------------------------------------------------------------------
// Weight transpose: W[K][N] fp32 -> WT[N][K] bf16 (RNE)
__global__ __launch_bounds__(256) void k_wt(const float* __restrict__ W,
                                            ushort* __restrict__ WTh, int K, int N)
{
    __shared__ float t[32][33];
    const int k0 = blockIdx.x * 32, n0 = blockIdx.y * 32;
    const int c = threadIdx.x & 31, r8 = threadIdx.x >> 5;
#pragma unroll
    for (int i = 0; i < 4; ++i) {
        int r = r8 + i * 8;
        t[r][c] = W[(size_t)(k0 + r) * N + n0 + c];
    }
    __syncthreads();
#pragma unroll
    for (int i = 0; i < 4; ++i) {
        int r = r8 + i * 8;
        WTh[(size_t)(n0 + r) * K + k0 + c] = bfrne(t[c][r]);
    }
}

// folded pair W1: Wf[2304][768] from pW1[3072][768]
__global__ void k_fold(const float* __restrict__ pW1, float* __restrict__ Wf, int n)
{
    int i = blockIdx.x * blockDim.x + threadIdx.x;
    if (i >= n) return;
    int row = i / D;
    float v;
    if (row < D)            v = pW1[i] - pW1[i + 1536 * D];
    else if (row < 2 * D)   v = pW1[i] + pW1[i + 768 * D];
    else                    v = pW1[i + 768 * D];
    Wf[i] = v;
}

__global__ __launch_bounds__(256) void k_entmean(
    const float* __restrict__ para, const int* __restrict__ mpos,
    const int* __restrict__ mid, int M, ushort* __restrict__ oh)
{
    __shared__ int sb[2];
    const int e = blockIdx.x;
    if (threadIdx.x < 2) {
        int target = e + threadIdx.x;
        int lo = 0, hi = M;
        while (lo < hi) {
            int md = (lo + hi) >> 1;
            if (mid[md] < target) lo = md + 1; else hi = md;
        }
        sb[threadIdx.x] = lo;
    }
    __syncthreads();
    const int lo = sb[0], hi = sb[1];
    const int tid = threadIdx.x;
    float a0 = 0, a1 = 0, a2 = 0, b0 = 0, b1 = 0, b2 = 0;
    for (int m = lo; m < hi; ++m) {
        int p = mpos[m * 3], t1 = mpos[m * 3 + 1], t2 = mpos[m * 3 + 2];
        const float* L = para + (size_t)(p * LPARA + t1) * D;
        const float* R = para + (size_t)(p * LPARA + t2) * D;
        a0 += L[tid]; a1 += L[tid + 256]; a2 += L[tid + 512];
        b0 += R[tid]; b1 += R[tid + 256]; b2 += R[tid + 512];
    }
    const float inv = (hi > lo) ? 1.0f / (float)(hi - lo) : 0.0f;
    size_t base = (size_t)e * (2 * D);
    float vals[6] = { a0 * inv, a1 * inv, a2 * inv, b0 * inv, b1 * inv, b2 * inv };
    int offs[6] = { tid, tid + 256, tid + 512, D + tid, D + tid + 256, D + tid + 512 };
#pragma unroll
    for (int i = 0; i < 6; ++i) oh[base + offs[i]] = bfrne(vals[i]);
}

// ---------------------------------------------------------------------------
// Batched split-K matvec (deterministic). grid (N/64, nks, T).
__global__ __launch_bounds__(256) void k_mvpart(
    const float* __restrict__ x, int xstride,
    const float* __restrict__ W, float* __restrict__ acc, int K, int N, int nks)
{
    const int t = blockIdx.z;
    const float* xt = x + (size_t)t * xstride;
    const float* Wt = W + (size_t)t * K * N;
    const int jj = threadIdx.x & 63;
    const int kq = threadIdx.x >> 6;
    const int j = blockIdx.x * 64 + jj;
    const int kchunk = K / (nks * 4);
    const int kbeg = (blockIdx.y * 4 + kq) * kchunk;
    float s = 0.0f;
    for (int k = kbeg; k < kbeg + kchunk; ++k)
        s = fmaf(xt[k], Wt[(size_t)k * N + j], s);
    __shared__ float red[256];
    red[threadIdx.x] = s;
    __syncthreads();
    if (kq == 0) {
        float v = red[jj] + red[64 + jj] + red[128 + jj] + red[192 + jj];
        acc[((size_t)(t * nks) + blockIdx.y) * N + j] = v;
    }
}

__global__ void k_biasact(const float* __restrict__ acc, const float* __restrict__ b,
                          float* __restrict__ out, int N, int nks, int act)
{
    const int t = blockIdx.y;
    const int j = blockIdx.x * 256 + threadIdx.x;
    if (j >= N) return;
    float s = 0.0f;
    for (int i = 0; i < nks; ++i) s += acc[((size_t)(t * nks) + i) * N + j];
    s += b[(size_t)t * N + j];
    if (act) s = geluf(s);
    out[(size_t)t * N + j] = s;
}

__global__ void k_dot3(const float* __restrict__ x, const float* __restrict__ W,
                       const float* __restrict__ b, float* __restrict__ out)
{
    int j = threadIdx.x >> 6, lane = threadIdx.x & 63;
    if (j >= 3) return;
    float s = 0.0f;
#pragma unroll
    for (int i = 0; i < 4; ++i) {
        int k = lane + i * 64;
        s += x[k] * W[k * 3 + j];
    }
    for (int off = 32; off > 0; off >>= 1) s += __shfl_down(s, off, 64);
    if (lane == 0) out[j] = s + b[j];
}

__global__ void k_ctx3(const float* __restrict__ cq3, const float* __restrict__ qwh,
                       float* __restrict__ ctx3)
{
    const float* cq = cq3 + (size_t)blockIdx.x * D;
    float* ctx = ctx3 + (size_t)blockIdx.x * D;
    __shared__ float red[256];
    __shared__ float dist[LQ];
    const int tid = threadIdx.x;
    const int l = tid >> 3, part = tid & 7;
    float s = 0.0f;
    for (int d = part; d < D; d += 8) s += cq[d] * qwh[l * D + d];
    red[tid] = s;
    __syncthreads();
    if (part == 0) {
        float v = 0;
        for (int i = 0; i < 8; ++i) v += red[l * 8 + i];
        dist[l] = v;
    }
    __syncthreads();
    if (tid == 0) {
        float mx = -1e30f;
        for (int i = 0; i < LQ; ++i) mx = fmaxf(mx, dist[i]);
        float sm = 0;
        for (int i = 0; i < LQ; ++i) { float e = expf(dist[i] - mx); dist[i] = e; sm += e; }
        float inv = 1.0f / sm;
        for (int i = 0; i < LQ; ++i) dist[i] *= inv;
    }
    __syncthreads();
    for (int d = tid; d < D; d += 256) {
        float v = 0;
#pragma unroll
        for (int l2 = 0; l2 < LQ; ++l2) v += dist[l2] * qwh[l2 * D + d];
        ctx[d] = v + cq[d];
    }
}

__global__ void k_scalew(const float* __restrict__ ctx, const float* __restrict__ w1,
                         float* __restrict__ o, int n)
{
    int i = blockIdx.x * 256 + threadIdx.x;
    if (i < n) o[i] = ctx[i >> 8] * w1[i];
}

template <int PAIRMODE>
__global__ void k_rowdot(const float* __restrict__ H, const float* __restrict__ w2,
                         const float* __restrict__ sb2, int Nr,
                         float* __restrict__ simout,
                         const float* __restrict__ laste, const int* __restrict__ so,
                         float* __restrict__ newe)
{
    int r = blockIdx.x * 4 + (threadIdx.x >> 6);
    int lane = threadIdx.x & 63;
    if (r >= Nr) return;
    float s = 0.0f;
#pragma unroll
    for (int i = 0; i < 4; ++i)
        s += H[(size_t)r * 256 + lane + i * 64] * w2[lane + i * 64];
    for (int off = 32; off > 0; off >>= 1) s += __shfl_down(s, off, 64);
    if (lane == 0) {
        s += sb2[0];
        if (PAIRMODE == 0) {
            simout[r] = s;
        } else {
            float p = 1.0f / (1.0f + expf(-s));
            float v = laste[so[r * 2]] * p;
            atomicAdd(&newe[so[r * 2 + 1]], v);
        }
    }
}

__global__ void k_softmax(const float* __restrict__ sim, float* __restrict__ outp, int n)
{
    __shared__ float red[256];
    __shared__ float s_mx, s_sum;
    const int tid = threadIdx.x;
    float mx = -1e30f;
    for (int i = tid; i < n; i += 256) mx = fmaxf(mx, sim[i]);
    red[tid] = mx; __syncthreads();
    for (int off = 128; off > 0; off >>= 1) {
        if (tid < off) red[tid] = fmaxf(red[tid], red[tid + off]);
        __syncthreads();
    }
    if (tid == 0) s_mx = red[0];
    __syncthreads();
    const float mxv = s_mx;
    float sum = 0;
    for (int i = tid; i < n; i += 256) sum += expf(sim[i] - mxv);
    red[tid] = sum; __syncthreads();
    for (int off = 128; off > 0; off >>= 1) {
        if (tid < off) red[tid] += red[tid + off];
        __syncthreads();
    }
    if (tid == 0) s_sum = red[0];
    __syncthreads();
    const float inv = 1.0f / s_sum;
    for (int i = tid; i < n; i += 256) {
        float v = expf(sim[i] - mxv) * inv;
        outp[i] = v / fmaxf(v, 1.0f);
    }
}

__global__ void k_zero(float* p, int n)
{
    int i = blockIdx.x * blockDim.x + threadIdx.x;
    if (i < n) p[i] = 0.0f;
}

__global__ void k_clampstore(const float* __restrict__ ne, float* __restrict__ outp, int n)
{
    int i = blockIdx.x * blockDim.x + threadIdx.x;
    if (i < n) { float v = ne[i]; outp[i] = v / fmaxf(v, 1.0f); }
}

__global__ void k_final(const float* __restrict__ probs, const float* __restrict__ hlog,
                        float* __restrict__ out, int n)
{
    int i = blockIdx.x * blockDim.x + threadIdx.x;
    if (i >= n) return;
    float l0 = hlog[0], l1 = hlog[1], l2 = hlog[2];
    float m = fmaxf(l0, fmaxf(l1, l2));
    float e0 = expf(l0 - m), e1 = expf(l1 - m), e2 = expf(l2 - m);
    float inv = 1.0f / (e0 + e1 + e2);
    out[i] = (e0 * probs[i] + e1 * probs[n + i] + e2 * probs[2 * n + i]) * inv;
}

// ---------------------------------------------------------------------------
extern "C" void kernel_launch(void* const* d_in, const int* in_sizes, int n_in,
                              void* d_out, int out_size, void* d_ws, size_t ws_size,
                              hipStream_t stream)
{
    const size_t WS_NEED = 148793744;  // 141.9 MiB
    if (ws_size < WS_NEED) return;

    const float* para  = (const float*)d_in[0];
    const float* q     = (const float*)d_in[1];
    const float* qwh   = (const float*)d_in[2];
    const float* stW1  = (const float*)d_in[3];
    const float* stb1  = (const float*)d_in[4];
    const float* stW2  = (const float*)d_in[5];
    const float* stb2  = (const float*)d_in[6];
    const float* mW1   = (const float*)d_in[7];
    const float* mb1   = (const float*)d_in[8];
    const float* mW2   = (const float*)d_in[9];
    const float* mb2   = (const float*)d_in[10];
    const float* pW1   = (const float*)d_in[11];
    const float* pb1   = (const float*)d_in[12];
    const float* pW2   = (const float*)d_in[13];
    const float* pb2   = (const float*)d_in[14];
    const float* simW1 = (const float*)d_in[15];
    const float* simb1 = (const float*)d_in[16];
    const float* simW2 = (const float*)d_in[17];
    const float* simb2 = (const float*)d_in[18];
    const float* hW1   = (const float*)d_in[19];
    const float* hb1   = (const float*)d_in[20];
    const float* hW2   = (const float*)d_in[21];
    const float* hb2   = (const float*)d_in[22];
    const int*   mpos  = (const int*)d_in[23];
    const int*   mid   = (const int*)d_in[24];
    const int*   ppos  = (const int*)d_in[25];
    const int*   pso   = (const int*)d_in[26];

    // ---- workspace layout (single bf16 planes) ----
    ushort* P1   = (ushort*)d_ws;          // 15,360,000 (EM -> sub_feat -> pair_emb)
    ushort* HID  = P1  + 15360000;         // 15,360,000 (hidden; H256 fp32 overlay)
    ushort* OBJ  = HID + 15360000;         // 15,360,000 (Wfold tmp -> obj_feat)
    ushort* SOp  = OBJ + 15360000;         // 15,360,000 (sub*obj plane)
    ushort* E    = SOp + 15360000;         //  7,680,000 (ent_emb)
    ushort* mW1T = E    + 7680000;         //  1,179,648
    ushort* mW2T = mW1T + 1179648;         //    589,824
    ushort* WfT  = mW2T + 589824;          //  1,769,472 ([768][2304] folded)
    ushort* pW2T = WfT  + 1769472;         //    589,824
    ushort* W1sT0 = pW2T + 589824;         //    589,824 (3 x 196,608)
    float*  W1s   = (float*)(W1sT0 + 589824);  // 196,608
    float*  simb  = W1s  + 196608;         // 20,000
    float*  probs = simb + 20000;          // 30,000
    float*  newe  = probs + 30000;         // 10,000
    float*  acc3  = newe + 10000;          // 13,824
    float*  h3    = acc3 + 13824;          // 2,304
    float*  cq3   = h3   + 2304;           // 2,304
    float*  ctx3  = cq3  + 2304;           // 2,304
    float*  hacc  = ctx3 + 2304;           // 1,536
    float*  hh    = hacc + 1536;           // 256
    float*  hlog  = hh   + 256;            // 4
    float*  H256  = (float*)HID;           // 20000x256 fp32 overlay (HID dead then)
    float*  Wfold = (float*)OBJ;           // fp32 tmp (dead before OBJ written)

    dim3 B256(256);
    const ushort* np = nullptr;

    // 0) weight prep
    k_fold<<<(2304 * D + 255) / 256, B256, 0, stream>>>(pW1, Wfold, 2304 * D);
    k_wt<<<dim3(48, 24), B256, 0, stream>>>(mW1, mW1T, 2 * D, D);
    k_wt<<<dim3(24, 24), B256, 0, stream>>>(mW2, mW2T, D, D);
    k_wt<<<dim3(72, 24), B256, 0, stream>>>(Wfold, WfT, 3 * D, D);
    k_wt<<<dim3(24, 24), B256, 0, stream>>>(pW2, pW2T, D, D);

    // 1) batched step MLPs + ctx + scaled sim weights
    k_mvpart<<<dim3(12, 6, 3), B256, 0, stream>>>(q, 0, stW1, acc3, D, D, 6);
    k_biasact<<<dim3(3, 3), B256, 0, stream>>>(acc3, stb1, h3, D, 6, 1);
    k_mvpart<<<dim3(12, 6, 3), B256, 0, stream>>>(h3, D, stW2, acc3, D, D, 6);
    k_biasact<<<dim3(3, 3), B256, 0, stream>>>(acc3, stb2, cq3, D, 6, 0);
    k_ctx3<<<3, B256, 0, stream>>>(cq3, qwh, ctx3);
    for (int t = 0; t < NSTEP; ++t) {
        k_scalew<<<768, 256, 0, stream>>>(ctx3 + (size_t)t * D, simW1, W1s, D * 256);
        k_wt<<<dim3(24, 8), B256, 0, stream>>>(W1s, W1sT0 + t * 196608, D, 256);
    }

    // 2) entity mention means -> P1 (10000 x 1536 bf16)
    k_entmean<<<NENT, 256, 0, stream>>>(para, mpos, mid, MMENT, P1);

    // 3) ent_emb (M=10000, grid 157x6=942)
    gemm_m<0, 1, 1><<<942, B256, 0, stream>>>(P1, nullptr, nullptr, 0, 0, np, np,
        mW1T, mb1, nullptr, HID, NENT, D, 2 * D, 6);
    gemm_m<0, 0, 1><<<942, B256, 0, stream>>>(HID, nullptr, nullptr, 0, 0, np, np,
        mW2T, mb2, nullptr, E, NENT, D, D, 6);

    // 4) step 0: sim on entities -> probs[0]
    gemm_m<0, 1, 0><<<314, B256, 0, stream>>>(E, nullptr, nullptr, 0, 0, np, np,
        W1sT0, simb1, H256, nullptr, NENT, 256, D, 2);
    k_rowdot<0><<<NENT / 4, 256, 0, stream>>>(H256, simW2, simb2, NENT, simb,
                                              nullptr, nullptr, nullptr);
    k_softmax<<<1, 256, 0, stream>>>(simb, probs, NENT);

    // 5) pair pipeline, full 20000 rows per launch (grid 313x6=1878)
    gemm_m<1, 1, 1><<<1878, B256, 0, stream>>>(np, para, ppos, 1, 2, np, np,
        mW1T, mb1, nullptr, HID, NPAIR, D, 2 * D, 6);
    gemm_m<0, 0, 1><<<1878, B256, 0, stream>>>(HID, nullptr, nullptr, 0, 0, np, np,
        mW2T, mb2, nullptr, P1, NPAIR, D, D, 6);
    gemm_m<1, 1, 1><<<1878, B256, 0, stream>>>(np, para, ppos, 3, 4, np, np,
        mW1T, mb1, nullptr, HID, NPAIR, D, 2 * D, 6);
    gemm_m<0, 0, 1><<<1878, B256, 0, stream>>>(HID, nullptr, nullptr, 0, 0, np, np,
        mW2T, mb2, nullptr, OBJ, NPAIR, D, D, 6);
    k_so<<<15000, B256, 0, stream>>>(P1, OBJ, SOp, NPAIR * D / 4);
    gemm_m<2, 1, 1><<<1878, B256, 0, stream>>>(SOp, nullptr, nullptr, 0, 0, P1, OBJ,
        WfT, pb1, nullptr, HID, NPAIR, D, 3 * D, 6);
    gemm_m<0, 0, 1><<<1878, B256, 0, stream>>>(HID, nullptr, nullptr, 0, 0, np, np,
        pW2T, pb2, nullptr, P1, NPAIR, D, D, 6);

    // 6) steps 1,2: sim on pairs + scatter-propagate (grid 313x2=626)
    for (int t = 1; t < NSTEP; ++t) {
        gemm_m<0, 1, 0><<<626, B256, 0, stream>>>(P1, nullptr, nullptr, 0, 0, np, np,
            W1sT0 + t * 196608, simb1, H256, nullptr, NPAIR, 256, D, 2);
        k_zero<<<40, 256, 0, stream>>>(newe, NENT);
        k_rowdot<1><<<NPAIR / 4, 256, 0, stream>>>(H256, simW2, simb2, NPAIR, nullptr,
                                                   probs + (t - 1) * NENT, pso, newe);
        k_clampstore<<<40, 256, 0, stream>>>(newe, probs + t * NENT, NENT);
    }

    // 7) hop attention + final mix
    k_mvpart<<<dim3(4, 6, 1), B256, 0, stream>>>(q, 0, hW1, hacc, D, 256, 6);
    k_biasact<<<dim3(1, 1), B256, 0, stream>>>(hacc, hb1, hh, 256, 6, 1);
    k_dot3<<<1, B256, 0, stream>>>(hh, hW2, hb2, hlog);
    k_final<<<40, 256, 0, stream>>>(probs, hlog, (float*)d_out, NENT);
}

// Round 17
// 818.460 us; speedup vs baseline: 2.0558x; 1.2540x over previous
//
#include <hip/hip_runtime.h>
#include <math.h>

// ---------------------------------------------------------------------------
#define D 768
#define NPARA 32
#define LPARA 512
#define LQ 32
#define NENT 10000
#define MMENT 30000
#define NPAIR 20000
#define NSTEP 3

using bf16x8 = __attribute__((ext_vector_type(8))) short;
using f32x4  = __attribute__((ext_vector_type(4))) float;

__device__ __forceinline__ float geluf(float x) {
    return 0.5f * x * (1.0f + erff(x * 0.70710678118654752f));
}
__device__ __forceinline__ float bf2f(ushort h) {
    union { unsigned u; float f; } v; v.u = ((unsigned)h) << 16; return v.f;
}
// round-to-nearest-even fp32 -> bf16
__device__ __forceinline__ ushort bfrne(float x) {
    union { float f; unsigned u; } v; v.f = x;
    unsigned r = (v.u + 0x7FFF + ((v.u >> 16) & 1)) >> 16;
    return (ushort)r;
}

// ---------------------------------------------------------------------------
// Single-plane bf16 MFMA GEMM. 64x128 tile, A+B LDS (XOR-swizzled), register
// prefetch of next A and B tiles, band-major XCD swizzle.
// THIS IS THE R12 KNOWN-GOOD TEMPLATE (VGPR 60, no spill, 815us total).
// Do NOT edit this template: R13/R14 (MI=4 @ lb 4/3) and R16 (merged MODE0/2
// prefetch path) all perturbed regalloc -> scratch spill (WRITE 455-772MB).
// MODE 0: A = bf16 plane [M][K]
// MODE 1: A row r = concat(para[p,t1,:], para[p,t2,:]) fp32 gather, K=1536
// MODE 2: A row r, sections {S, O, S*O} from bf16 feats, K=2304 (folded W1)
// B: pre-transposed bf16 weights WT[N][K]. OUTP 0: fp32 C; 1: bf16 C.
// launch_bounds (256,4): (256,5) capped regs ~102 -> spill (R11).
// ---------------------------------------------------------------------------
#define BM 64
#define BN 128

__device__ __forceinline__ int ldso(int row, int kb) {   // ushort index
    return row * 64 + (((kb) ^ ((row & 7) << 4)) >> 1);
}

template <int MODE, int ACT, int OUTP>
__global__ __launch_bounds__(256, 4) void gemm_m(
    const ushort* __restrict__ Ah,
    const float* __restrict__ para, const int* __restrict__ ppos, int c1, int c2,
    const ushort* __restrict__ Sh, const ushort* __restrict__ Oh,
    const ushort* __restrict__ Bh, const float* __restrict__ bias,
    float* __restrict__ Cf, ushort* __restrict__ Ch,
    int M, int N, int K, int nby)
{
    __shared__ ushort sA[BM * 64];   //  8 KB
    __shared__ ushort sB[BN * 64];   // 16 KB

    const int nwg = gridDim.x;
    const int q = nwg >> 3, r = nwg & 7;
    const int xcd = blockIdx.x & 7, idx = blockIdx.x >> 3;
    const int wgid = (xcd < r) ? xcd * (q + 1) + idx
                               : r * (q + 1) + (xcd - r) * q + idx;
    const int m0 = (wgid / nby) * BM;
    const int n0 = (wgid % nby) * BN;

    const int tid = threadIdx.x;
    const int lane = tid & 63;
    const int wv = tid >> 6;
    const int wr = (wv >> 1) * 32;
    const int wc = (wv & 1) * 64;
    const int ln = lane & 15;
    const int kg = lane >> 4;

    f32x4 acc[2][4];
#pragma unroll
    for (int i = 0; i < 2; ++i)
#pragma unroll
        for (int j = 0; j < 4; ++j)
#pragma unroll
            for (int e = 0; e < 4; ++e) acc[i][j][e] = 0.0f;

    const int arow = tid >> 2, aq = tid & 3;   // A: 4 thr/row, 16 ushort each
    const int brow = tid >> 1, bq = tid & 1;   // B: 2 thr/row, 32 ushort each
    const int gm = m0 + arow;
    const bool ok = gm < M;

    int baseL = 0, baseR = 0;
    if (MODE == 1 && ok) {
        int p = ppos[gm * 5];
        baseL = (p * LPARA + ppos[gm * 5 + c1]) * D;
        baseR = (p * LPARA + ppos[gm * 5 + c2]) * D;
    }

    bf16x8 pa[2];     // MODE 0 prefetch
    float4 pf[4];     // MODE 1 prefetch (16 fp32)
    ushort4 ps[8];    // MODE 2 prefetch (S and/or O quads)
    bf16x8 pb[4];     // B prefetch (32 ushorts)

    auto prefA = [&](int kt) {
        if (MODE == 0) {
            if (ok) {
                const ushort* g = Ah + (size_t)gm * K + kt + aq * 16;
                pa[0] = *(const bf16x8*)g;
                pa[1] = *(const bf16x8*)(g + 8);
            } else {
#pragma unroll
                for (int i = 0; i < 2; ++i)
#pragma unroll
                    for (int z = 0; z < 8; ++z) pa[i][z] = 0;
            }
        } else if (MODE == 1) {
            const int kb = kt + aq * 16;            // never crosses D boundary
            const int gb = (kb < D) ? (baseL + kb) : (baseR + kb - D);
#pragma unroll
            for (int j = 0; j < 4; ++j)
                pf[j] = ok ? *(const float4*)(para + gb + j * 4)
                           : make_float4(0.f, 0.f, 0.f, 0.f);
        } else {
            const int sec = kt / D;
            const size_t rb = (size_t)gm * D + (kt - sec * D) + aq * 16;
            if (ok) {
                if (sec == 0) {
#pragma unroll
                    for (int j = 0; j < 4; ++j)
                        ps[j] = *(const ushort4*)(Sh + rb + j * 4);
                } else if (sec == 1) {
#pragma unroll
                    for (int j = 0; j < 4; ++j)
                        ps[j] = *(const ushort4*)(Oh + rb + j * 4);
                } else {
#pragma unroll
                    for (int j = 0; j < 4; ++j) {
                        ps[j]     = *(const ushort4*)(Sh + rb + j * 4);
                        ps[4 + j] = *(const ushort4*)(Oh + rb + j * 4);
                    }
                }
            }
        }
    };

    auto prefB = [&](int kt) {
        const ushort* g = Bh + (size_t)(n0 + brow) * K + kt + bq * 32;
#pragma unroll
        for (int i = 0; i < 4; ++i)
            pb[i] = *(const bf16x8*)(g + i * 8);
    };

    auto storeAB = [&](int kt) {
        if (MODE == 0) {
            int o0 = ldso(arow, aq * 32), o1 = ldso(arow, aq * 32 + 16);
            *(bf16x8*)&sA[o0] = pa[0];
            *(bf16x8*)&sA[o1] = pa[1];
        } else if (MODE == 1) {
#pragma unroll
            for (int j = 0; j < 4; ++j) {
                ushort4 h;
                h.x = bfrne(pf[j].x); h.y = bfrne(pf[j].y);
                h.z = bfrne(pf[j].z); h.w = bfrne(pf[j].w);
                *(ushort4*)&sA[ldso(arow, aq * 32 + j * 8)] = h;
            }
        } else {
            const int sec = kt / D;
#pragma unroll
            for (int j = 0; j < 4; ++j) {
                ushort4 h;
                if (ok) {
                    if (sec < 2) {
                        h = ps[j];
                    } else {
                        h.x = bfrne(bf2f(ps[j].x) * bf2f(ps[4 + j].x));
                        h.y = bfrne(bf2f(ps[j].y) * bf2f(ps[4 + j].y));
                        h.z = bfrne(bf2f(ps[j].z) * bf2f(ps[4 + j].z));
                        h.w = bfrne(bf2f(ps[j].w) * bf2f(ps[4 + j].w));
                    }
                } else {
                    h.x = h.y = h.z = h.w = 0;
                }
                *(ushort4*)&sA[ldso(arow, aq * 32 + j * 8)] = h;
            }
        }
#pragma unroll
        for (int i = 0; i < 4; ++i)
            *(bf16x8*)&sB[ldso(brow, bq * 64 + i * 16)] = pb[i];
    };

    prefA(0);
    prefB(0);

    for (int kt = 0; kt < K; kt += 64) {
        if (kt > 0) __syncthreads();
        storeAB(kt);
        __syncthreads();

        const int ktn = kt + 64;
        if (ktn < K) { prefA(ktn); prefB(ktn); }

#pragma unroll
        for (int ks = 0; ks < 2; ++ks) {
            bf16x8 fb[4];
#pragma unroll
            for (int ni = 0; ni < 4; ++ni)
                fb[ni] = *(const bf16x8*)&sB[ldso(wc + ni * 16 + ln, ks * 64 + kg * 16)];
#pragma unroll
            for (int mi = 0; mi < 2; ++mi) {
                bf16x8 fa = *(const bf16x8*)&sA[ldso(wr + mi * 16 + ln, ks * 64 + kg * 16)];
#pragma unroll
                for (int ni = 0; ni < 4; ++ni)
                    acc[mi][ni] = __builtin_amdgcn_mfma_f32_16x16x32_bf16(
                        fa, fb[ni], acc[mi][ni], 0, 0, 0);
            }
        }
    }

    // epilogue: row = (lane>>4)*4+reg, col = lane&15
#pragma unroll
    for (int mi = 0; mi < 2; ++mi)
#pragma unroll
        for (int ni = 0; ni < 4; ++ni) {
            int col = n0 + wc + ni * 16 + ln;
            f32x4 a = acc[mi][ni];
#pragma unroll
            for (int j = 0; j < 4; ++j) {
                int row = m0 + wr + mi * 16 + kg * 4 + j;
                if (row < M) {
                    float v = a[j] + bias[col];
                    if (ACT == 1) v = geluf(v);
                    if (OUTP == 0) Cf[(size_t)row * N + col] = v;
                    else           Ch[(size_t)row * N + col] = bfrne(v);
                }
            }
        }
}

// ---------------------------------------------------------------------------
// Weight transpose: W[K][N] fp32 -> WT[N][K] bf16 (RNE)
__global__ __launch_bounds__(256) void k_wt(const float* __restrict__ W,
                                            ushort* __restrict__ WTh, int K, int N)
{
    __shared__ float t[32][33];
    const int k0 = blockIdx.x * 32, n0 = blockIdx.y * 32;
    const int c = threadIdx.x & 31, r8 = threadIdx.x >> 5;
#pragma unroll
    for (int i = 0; i < 4; ++i) {
        int r = r8 + i * 8;
        t[r][c] = W[(size_t)(k0 + r) * N + n0 + c];
    }
    __syncthreads();
#pragma unroll
    for (int i = 0; i < 4; ++i) {
        int r = r8 + i * 8;
        WTh[(size_t)(n0 + r) * K + k0 + c] = bfrne(t[c][r]);
    }
}

// folded pair W1: Wf[2304][768] from pW1[3072][768]
__global__ void k_fold(const float* __restrict__ pW1, float* __restrict__ Wf, int n)
{
    int i = blockIdx.x * blockDim.x + threadIdx.x;
    if (i >= n) return;
    int row = i / D;
    float v;
    if (row < D)            v = pW1[i] - pW1[i + 1536 * D];
    else if (row < 2 * D)   v = pW1[i] + pW1[i + 768 * D];
    else                    v = pW1[i + 768 * D];
    Wf[i] = v;
}

__global__ __launch_bounds__(256) void k_entmean(
    const float* __restrict__ para, const int* __restrict__ mpos,
    const int* __restrict__ mid, int M, ushort* __restrict__ oh)
{
    __shared__ int sb[2];
    const int e = blockIdx.x;
    if (threadIdx.x < 2) {
        int target = e + threadIdx.x;
        int lo = 0, hi = M;
        while (lo < hi) {
            int md = (lo + hi) >> 1;
            if (mid[md] < target) lo = md + 1; else hi = md;
        }
        sb[threadIdx.x] = lo;
    }
    __syncthreads();
    const int lo = sb[0], hi = sb[1];
    const int tid = threadIdx.x;
    float a0 = 0, a1 = 0, a2 = 0, b0 = 0, b1 = 0, b2 = 0;
    for (int m = lo; m < hi; ++m) {
        int p = mpos[m * 3], t1 = mpos[m * 3 + 1], t2 = mpos[m * 3 + 2];
        const float* L = para + (size_t)(p * LPARA + t1) * D;
        const float* R = para + (size_t)(p * LPARA + t2) * D;
        a0 += L[tid]; a1 += L[tid + 256]; a2 += L[tid + 512];
        b0 += R[tid]; b1 += R[tid + 256]; b2 += R[tid + 512];
    }
    const float inv = (hi > lo) ? 1.0f / (float)(hi - lo) : 0.0f;
    size_t base = (size_t)e * (2 * D);
    float vals[6] = { a0 * inv, a1 * inv, a2 * inv, b0 * inv, b1 * inv, b2 * inv };
    int offs[6] = { tid, tid + 256, tid + 512, D + tid, D + tid + 256, D + tid + 512 };
#pragma unroll
    for (int i = 0; i < 6; ++i) oh[base + offs[i]] = bfrne(vals[i]);
}

// ---------------------------------------------------------------------------
// Batched split-K matvec (deterministic). grid (N/64, nks, T).
__global__ __launch_bounds__(256) void k_mvpart(
    const float* __restrict__ x, int xstride,
    const float* __restrict__ W, float* __restrict__ acc, int K, int N, int nks)
{
    const int t = blockIdx.z;
    const float* xt = x + (size_t)t * xstride;
    const float* Wt = W + (size_t)t * K * N;
    const int jj = threadIdx.x & 63;
    const int kq = threadIdx.x >> 6;
    const int j = blockIdx.x * 64 + jj;
    const int kchunk = K / (nks * 4);
    const int kbeg = (blockIdx.y * 4 + kq) * kchunk;
    float s = 0.0f;
    for (int k = kbeg; k < kbeg + kchunk; ++k)
        s = fmaf(xt[k], Wt[(size_t)k * N + j], s);
    __shared__ float red[256];
    red[threadIdx.x] = s;
    __syncthreads();
    if (kq == 0) {
        float v = red[jj] + red[64 + jj] + red[128 + jj] + red[192 + jj];
        acc[((size_t)(t * nks) + blockIdx.y) * N + j] = v;
    }
}

__global__ void k_biasact(const float* __restrict__ acc, const float* __restrict__ b,
                          float* __restrict__ out, int N, int nks, int act)
{
    const int t = blockIdx.y;
    const int j = blockIdx.x * 256 + threadIdx.x;
    if (j >= N) return;
    float s = 0.0f;
    for (int i = 0; i < nks; ++i) s += acc[((size_t)(t * nks) + i) * N + j];
    s += b[(size_t)t * N + j];
    if (act) s = geluf(s);
    out[(size_t)t * N + j] = s;
}

__global__ void k_dot3(const float* __restrict__ x, const float* __restrict__ W,
                       const float* __restrict__ b, float* __restrict__ out)
{
    int j = threadIdx.x >> 6, lane = threadIdx.x & 63;
    if (j >= 3) return;
    float s = 0.0f;
#pragma unroll
    for (int i = 0; i < 4; ++i) {
        int k = lane + i * 64;
        s += x[k] * W[k * 3 + j];
    }
    for (int off = 32; off > 0; off >>= 1) s += __shfl_down(s, off, 64);
    if (lane == 0) out[j] = s + b[j];
}

__global__ void k_ctx3(const float* __restrict__ cq3, const float* __restrict__ qwh,
                       float* __restrict__ ctx3)
{
    const float* cq = cq3 + (size_t)blockIdx.x * D;
    float* ctx = ctx3 + (size_t)blockIdx.x * D;
    __shared__ float red[256];
    __shared__ float dist[LQ];
    const int tid = threadIdx.x;
    const int l = tid >> 3, part = tid & 7;
    float s = 0.0f;
    for (int d = part; d < D; d += 8) s += cq[d] * qwh[l * D + d];
    red[tid] = s;
    __syncthreads();
    if (part == 0) {
        float v = 0;
        for (int i = 0; i < 8; ++i) v += red[l * 8 + i];
        dist[l] = v;
    }
    __syncthreads();
    if (tid == 0) {
        float mx = -1e30f;
        for (int i = 0; i < LQ; ++i) mx = fmaxf(mx, dist[i]);
        float sm = 0;
        for (int i = 0; i < LQ; ++i) { float e = expf(dist[i] - mx); dist[i] = e; sm += e; }
        float inv = 1.0f / sm;
        for (int i = 0; i < LQ; ++i) dist[i] *= inv;
    }
    __syncthreads();
    for (int d = tid; d < D; d += 256) {
        float v = 0;
#pragma unroll
        for (int l2 = 0; l2 < LQ; ++l2) v += dist[l2] * qwh[l2 * D + d];
        ctx[d] = v + cq[d];
    }
}

__global__ void k_scalew(const float* __restrict__ ctx, const float* __restrict__ w1,
                         float* __restrict__ o, int n)
{
    int i = blockIdx.x * 256 + threadIdx.x;
    if (i < n) o[i] = ctx[i >> 8] * w1[i];
}

template <int PAIRMODE>
__global__ void k_rowdot(const float* __restrict__ H, const float* __restrict__ w2,
                         const float* __restrict__ sb2, int Nr,
                         float* __restrict__ simout,
                         const float* __restrict__ laste, const int* __restrict__ so,
                         float* __restrict__ newe)
{
    int r = blockIdx.x * 4 + (threadIdx.x >> 6);
    int lane = threadIdx.x & 63;
    if (r >= Nr) return;
    float s = 0.0f;
#pragma unroll
    for (int i = 0; i < 4; ++i)
        s += H[(size_t)r * 256 + lane + i * 64] * w2[lane + i * 64];
    for (int off = 32; off > 0; off >>= 1) s += __shfl_down(s, off, 64);
    if (lane == 0) {
        s += sb2[0];
        if (PAIRMODE == 0) {
            simout[r] = s;
        } else {
            float p = 1.0f / (1.0f + expf(-s));
            float v = laste[so[r * 2]] * p;
            atomicAdd(&newe[so[r * 2 + 1]], v);
        }
    }
}

__global__ void k_softmax(const float* __restrict__ sim, float* __restrict__ outp, int n)
{
    __shared__ float red[256];
    __shared__ float s_mx, s_sum;
    const int tid = threadIdx.x;
    float mx = -1e30f;
    for (int i = tid; i < n; i += 256) mx = fmaxf(mx, sim[i]);
    red[tid] = mx; __syncthreads();
    for (int off = 128; off > 0; off >>= 1) {
        if (tid < off) red[tid] = fmaxf(red[tid], red[tid + off]);
        __syncthreads();
    }
    if (tid == 0) s_mx = red[0];
    __syncthreads();
    const float mxv = s_mx;
    float sum = 0;
    for (int i = tid; i < n; i += 256) sum += expf(sim[i] - mxv);
    red[tid] = sum; __syncthreads();
    for (int off = 128; off > 0; off >>= 1) {
        if (tid < off) red[tid] += red[tid + off];
        __syncthreads();
    }
    if (tid == 0) s_sum = red[0];
    __syncthreads();
    const float inv = 1.0f / s_sum;
    for (int i = tid; i < n; i += 256) {
        float v = expf(sim[i] - mxv) * inv;
        outp[i] = v / fmaxf(v, 1.0f);
    }
}

__global__ void k_zero(float* p, int n)
{
    int i = blockIdx.x * blockDim.x + threadIdx.x;
    if (i < n) p[i] = 0.0f;
}

__global__ void k_clampstore(const float* __restrict__ ne, float* __restrict__ outp, int n)
{
    int i = blockIdx.x * blockDim.x + threadIdx.x;
    if (i < n) { float v = ne[i]; outp[i] = v / fmaxf(v, 1.0f); }
}

__global__ void k_final(const float* __restrict__ probs, const float* __restrict__ hlog,
                        float* __restrict__ out, int n)
{
    int i = blockIdx.x * blockDim.x + threadIdx.x;
    if (i >= n) return;
    float l0 = hlog[0], l1 = hlog[1], l2 = hlog[2];
    float m = fmaxf(l0, fmaxf(l1, l2));
    float e0 = expf(l0 - m), e1 = expf(l1 - m), e2 = expf(l2 - m);
    float inv = 1.0f / (e0 + e1 + e2);
    out[i] = (e0 * probs[i] + e1 * probs[n + i] + e2 * probs[2 * n + i]) * inv;
}

// ---------------------------------------------------------------------------
extern "C" void kernel_launch(void* const* d_in, const int* in_sizes, int n_in,
                              void* d_out, int out_size, void* d_ws, size_t ws_size,
                              hipStream_t stream)
{
    const size_t WS_NEED = 118073744;  // 112.6 MiB
    if (ws_size < WS_NEED) return;

    const float* para  = (const float*)d_in[0];
    const float* q     = (const float*)d_in[1];
    const float* qwh   = (const float*)d_in[2];
    const float* stW1  = (const float*)d_in[3];
    const float* stb1  = (const float*)d_in[4];
    const float* stW2  = (const float*)d_in[5];
    const float* stb2  = (const float*)d_in[6];
    const float* mW1   = (const float*)d_in[7];
    const float* mb1   = (const float*)d_in[8];
    const float* mW2   = (const float*)d_in[9];
    const float* mb2   = (const float*)d_in[10];
    const float* pW1   = (const float*)d_in[11];
    const float* pb1   = (const float*)d_in[12];
    const float* pW2   = (const float*)d_in[13];
    const float* pb2   = (const float*)d_in[14];
    const float* simW1 = (const float*)d_in[15];
    const float* simb1 = (const float*)d_in[16];
    const float* simW2 = (const float*)d_in[17];
    const float* simb2 = (const float*)d_in[18];
    const float* hW1   = (const float*)d_in[19];
    const float* hb1   = (const float*)d_in[20];
    const float* hW2   = (const float*)d_in[21];
    const float* hb2   = (const float*)d_in[22];
    const int*   mpos  = (const int*)d_in[23];
    const int*   mid   = (const int*)d_in[24];
    const int*   ppos  = (const int*)d_in[25];
    const int*   pso   = (const int*)d_in[26];

    // ---- workspace layout (single bf16 planes) ----
    ushort* P1   = (ushort*)d_ws;          // 15,360,000 (EM -> sub_feat -> pair_emb)
    ushort* HID  = P1  + 15360000;         // 15,360,000 (hidden 20000x768; H256 overlay)
    ushort* OBJ  = HID + 15360000;         // 15,360,000 (Wfold tmp -> obj_feat)
    ushort* E    = OBJ + 15360000;         //  7,680,000 (ent_emb)
    ushort* mW1T = E    + 7680000;         //  1,179,648
    ushort* mW2T = mW1T + 1179648;         //    589,824
    ushort* WfT  = mW2T + 589824;          //  1,769,472 ([768][2304] folded)
    ushort* pW2T = WfT  + 1769472;         //    589,824
    ushort* W1sT0 = pW2T + 589824;         //    589,824 (3 x 196,608)
    float*  W1s   = (float*)(W1sT0 + 589824);  // 196,608
    float*  simb  = W1s  + 196608;         // 20,000
    float*  probs = simb + 20000;          // 30,000
    float*  newe  = probs + 30000;         // 10,000
    float*  acc3  = newe + 10000;          // 13,824
    float*  h3    = acc3 + 13824;          // 2,304
    float*  cq3   = h3   + 2304;           // 2,304
    float*  ctx3  = cq3  + 2304;           // 2,304
    float*  hacc  = ctx3 + 2304;           // 1,536
    float*  hh    = hacc + 1536;           // 256
    float*  hlog  = hh   + 256;            // 4
    float*  H256  = (float*)HID;           // 20000x256 fp32 overlay (HID dead then)
    float*  Wfold = (float*)OBJ;           // fp32 tmp (dead before OBJ written)

    dim3 B256(256);
    const ushort* np = nullptr;

    // 0) weight prep
    k_fold<<<(2304 * D + 255) / 256, B256, 0, stream>>>(pW1, Wfold, 2304 * D);
    k_wt<<<dim3(48, 24), B256, 0, stream>>>(mW1, mW1T, 2 * D, D);
    k_wt<<<dim3(24, 24), B256, 0, stream>>>(mW2, mW2T, D, D);
    k_wt<<<dim3(72, 24), B256, 0, stream>>>(Wfold, WfT, 3 * D, D);
    k_wt<<<dim3(24, 24), B256, 0, stream>>>(pW2, pW2T, D, D);

    // 1) batched step MLPs + ctx + scaled sim weights
    k_mvpart<<<dim3(12, 6, 3), B256, 0, stream>>>(q, 0, stW1, acc3, D, D, 6);
    k_biasact<<<dim3(3, 3), B256, 0, stream>>>(acc3, stb1, h3, D, 6, 1);
    k_mvpart<<<dim3(12, 6, 3), B256, 0, stream>>>(h3, D, stW2, acc3, D, D, 6);
    k_biasact<<<dim3(3, 3), B256, 0, stream>>>(acc3, stb2, cq3, D, 6, 0);
    k_ctx3<<<3, B256, 0, stream>>>(cq3, qwh, ctx3);
    for (int t = 0; t < NSTEP; ++t) {
        k_scalew<<<768, 256, 0, stream>>>(ctx3 + (size_t)t * D, simW1, W1s, D * 256);
        k_wt<<<dim3(24, 8), B256, 0, stream>>>(W1s, W1sT0 + t * 196608, D, 256);
    }

    // 2) entity mention means -> P1 (10000 x 1536 bf16)
    k_entmean<<<NENT, 256, 0, stream>>>(para, mpos, mid, MMENT, P1);

    // 3) ent_emb: gelu(EM@mW1) -> HID; HID@mW2 -> E
    gemm_m<0, 1, 1><<<942, B256, 0, stream>>>(P1, nullptr, nullptr, 0, 0, np, np,
        mW1T, mb1, nullptr, HID, NENT, D, 2 * D, 6);
    gemm_m<0, 0, 1><<<942, B256, 0, stream>>>(HID, nullptr, nullptr, 0, 0, np, np,
        mW2T, mb2, nullptr, E, NENT, D, D, 6);

    // 4) step 0: sim on entities -> probs[0]  (H256 overlays HID, ent hidden dead)
    gemm_m<0, 1, 0><<<314, B256, 0, stream>>>(E, nullptr, nullptr, 0, 0, np, np,
        W1sT0, simb1, H256, nullptr, NENT, 256, D, 2);
    k_rowdot<0><<<NENT / 4, 256, 0, stream>>>(H256, simW2, simb2, NENT, simb,
                                              nullptr, nullptr, nullptr);
    k_softmax<<<1, 256, 0, stream>>>(simb, probs, NENT);

    // 5) pair pipeline, full 20000 rows per launch (no chunking)
    gemm_m<1, 1, 1><<<1878, B256, 0, stream>>>(np, para, ppos, 1, 2, np, np,
        mW1T, mb1, nullptr, HID, NPAIR, D, 2 * D, 6);
    gemm_m<0, 0, 1><<<1878, B256, 0, stream>>>(HID, nullptr, nullptr, 0, 0, np, np,
        mW2T, mb2, nullptr, P1, NPAIR, D, D, 6);
    gemm_m<1, 1, 1><<<1878, B256, 0, stream>>>(np, para, ppos, 3, 4, np, np,
        mW1T, mb1, nullptr, HID, NPAIR, D, 2 * D, 6);
    gemm_m<0, 0, 1><<<1878, B256, 0, stream>>>(HID, nullptr, nullptr, 0, 0, np, np,
        mW2T, mb2, nullptr, OBJ, NPAIR, D, D, 6);
    gemm_m<2, 1, 1><<<1878, B256, 0, stream>>>(np, nullptr, nullptr, 0, 0, P1, OBJ,
        WfT, pb1, nullptr, HID, NPAIR, D, 3 * D, 6);
    gemm_m<0, 0, 1><<<1878, B256, 0, stream>>>(HID, nullptr, nullptr, 0, 0, np, np,
        pW2T, pb2, nullptr, P1, NPAIR, D, D, 6);

    // 6) steps 1,2: sim on pairs + scatter-propagate (H256 overlays HID)
    for (int t = 1; t < NSTEP; ++t) {
        gemm_m<0, 1, 0><<<626, B256, 0, stream>>>(P1, nullptr, nullptr, 0, 0, np, np,
            W1sT0 + t * 196608, simb1, H256, nullptr, NPAIR, 256, D, 2);
        k_zero<<<40, 256, 0, stream>>>(newe, NENT);
        k_rowdot<1><<<NPAIR / 4, 256, 0, stream>>>(H256, simW2, simb2, NPAIR, nullptr,
                                                   probs + (t - 1) * NENT, pso, newe);
        k_clampstore<<<40, 256, 0, stream>>>(newe, probs + t * NENT, NENT);
    }

    // 7) hop attention + final mix
    k_mvpart<<<dim3(4, 6, 1), B256, 0, stream>>>(q, 0, hW1, hacc, D, 256, 6);
    k_biasact<<<dim3(1, 1), B256, 0, stream>>>(hacc, hb1, hh, 256, 6, 1);
    k_dot3<<<1, B256, 0, stream>>>(hh, hW2, hb2, hlog);
    k_final<<<40, 256, 0, stream>>>(probs, hlog, (float*)d_out, NENT);
}

// Round 18
// 673.342 us; speedup vs baseline: 2.4988x; 1.2155x over previous
//
#include <hip/hip_runtime.h>
#include <math.h>

// ---------------------------------------------------------------------------
#define D 768
#define NPARA 32
#define LPARA 512
#define LQ 32
#define NENT 10000
#define MMENT 30000
#define NPAIR 20000
#define NSTEP 3
#define NTOK (NPARA * LPARA)   // 16384 unique tokens

using bf16x8 = __attribute__((ext_vector_type(8))) short;
using f32x4  = __attribute__((ext_vector_type(4))) float;

__device__ __forceinline__ float geluf(float x) {
    return 0.5f * x * (1.0f + erff(x * 0.70710678118654752f));
}
__device__ __forceinline__ float bf2f(ushort h) {
    union { unsigned u; float f; } v; v.u = ((unsigned)h) << 16; return v.f;
}
// round-to-nearest-even fp32 -> bf16
__device__ __forceinline__ ushort bfrne(float x) {
    union { float f; unsigned u; } v; v.f = x;
    unsigned r = (v.u + 0x7FFF + ((v.u >> 16) & 1)) >> 16;
    return (ushort)r;
}

// ---------------------------------------------------------------------------
// Single-plane bf16 MFMA GEMM. 64x128 tile, A+B LDS (XOR-swizzled), register
// prefetch of next A and B tiles, band-major XCD swizzle.
// R12 KNOWN-GOOD TEMPLATE (VGPR 60, no spill) — body must stay byte-identical.
// R13/R14 (MI=4) and R16 (merged prefetch) all perturbed regalloc -> spill.
// MODE 0: A = bf16 plane [M][K]
// MODE 1: A row r = concat(para[p,t1,:], para[p,t2,:]) fp32 gather (UNUSED now)
// MODE 2: A row r, sections {S, O, S*O} from bf16 feats, K=2304 (folded W1)
// B: pre-transposed bf16 weights WT[N][K]. OUTP 0: fp32 C; 1: bf16 C.
// ---------------------------------------------------------------------------
#define BM 64
#define BN 128

__device__ __forceinline__ int ldso(int row, int kb) {   // ushort index
    return row * 64 + (((kb) ^ ((row & 7) << 4)) >> 1);
}

template <int MODE, int ACT, int OUTP>
__global__ __launch_bounds__(256, 4) void gemm_m(
    const ushort* __restrict__ Ah,
    const float* __restrict__ para, const int* __restrict__ ppos, int c1, int c2,
    const ushort* __restrict__ Sh, const ushort* __restrict__ Oh,
    const ushort* __restrict__ Bh, const float* __restrict__ bias,
    float* __restrict__ Cf, ushort* __restrict__ Ch,
    int M, int N, int K, int nby)
{
    __shared__ ushort sA[BM * 64];   //  8 KB
    __shared__ ushort sB[BN * 64];   // 16 KB

    const int nwg = gridDim.x;
    const int q = nwg >> 3, r = nwg & 7;
    const int xcd = blockIdx.x & 7, idx = blockIdx.x >> 3;
    const int wgid = (xcd < r) ? xcd * (q + 1) + idx
                               : r * (q + 1) + (xcd - r) * q + idx;
    const int m0 = (wgid / nby) * BM;
    const int n0 = (wgid % nby) * BN;

    const int tid = threadIdx.x;
    const int lane = tid & 63;
    const int wv = tid >> 6;
    const int wr = (wv >> 1) * 32;
    const int wc = (wv & 1) * 64;
    const int ln = lane & 15;
    const int kg = lane >> 4;

    f32x4 acc[2][4];
#pragma unroll
    for (int i = 0; i < 2; ++i)
#pragma unroll
        for (int j = 0; j < 4; ++j)
#pragma unroll
            for (int e = 0; e < 4; ++e) acc[i][j][e] = 0.0f;

    const int arow = tid >> 2, aq = tid & 3;   // A: 4 thr/row, 16 ushort each
    const int brow = tid >> 1, bq = tid & 1;   // B: 2 thr/row, 32 ushort each
    const int gm = m0 + arow;
    const bool ok = gm < M;

    int baseL = 0, baseR = 0;
    if (MODE == 1 && ok) {
        int p = ppos[gm * 5];
        baseL = (p * LPARA + ppos[gm * 5 + c1]) * D;
        baseR = (p * LPARA + ppos[gm * 5 + c2]) * D;
    }

    bf16x8 pa[2];     // MODE 0 prefetch
    float4 pf[4];     // MODE 1 prefetch (16 fp32)
    ushort4 ps[8];    // MODE 2 prefetch (S and/or O quads)
    bf16x8 pb[4];     // B prefetch (32 ushorts)

    auto prefA = [&](int kt) {
        if (MODE == 0) {
            if (ok) {
                const ushort* g = Ah + (size_t)gm * K + kt + aq * 16;
                pa[0] = *(const bf16x8*)g;
                pa[1] = *(const bf16x8*)(g + 8);
            } else {
#pragma unroll
                for (int i = 0; i < 2; ++i)
#pragma unroll
                    for (int z = 0; z < 8; ++z) pa[i][z] = 0;
            }
        } else if (MODE == 1) {
            const int kb = kt + aq * 16;            // never crosses D boundary
            const int gb = (kb < D) ? (baseL + kb) : (baseR + kb - D);
#pragma unroll
            for (int j = 0; j < 4; ++j)
                pf[j] = ok ? *(const float4*)(para + gb + j * 4)
                           : make_float4(0.f, 0.f, 0.f, 0.f);
        } else {
            const int sec = kt / D;
            const size_t rb = (size_t)gm * D + (kt - sec * D) + aq * 16;
            if (ok) {
                if (sec == 0) {
#pragma unroll
                    for (int j = 0; j < 4; ++j)
                        ps[j] = *(const ushort4*)(Sh + rb + j * 4);
                } else if (sec == 1) {
#pragma unroll
                    for (int j = 0; j < 4; ++j)
                        ps[j] = *(const ushort4*)(Oh + rb + j * 4);
                } else {
#pragma unroll
                    for (int j = 0; j < 4; ++j) {
                        ps[j]     = *(const ushort4*)(Sh + rb + j * 4);
                        ps[4 + j] = *(const ushort4*)(Oh + rb + j * 4);
                    }
                }
            }
        }
    };

    auto prefB = [&](int kt) {
        const ushort* g = Bh + (size_t)(n0 + brow) * K + kt + bq * 32;
#pragma unroll
        for (int i = 0; i < 4; ++i)
            pb[i] = *(const bf16x8*)(g + i * 8);
    };

    auto storeAB = [&](int kt) {
        if (MODE == 0) {
            int o0 = ldso(arow, aq * 32), o1 = ldso(arow, aq * 32 + 16);
            *(bf16x8*)&sA[o0] = pa[0];
            *(bf16x8*)&sA[o1] = pa[1];
        } else if (MODE == 1) {
#pragma unroll
            for (int j = 0; j < 4; ++j) {
                ushort4 h;
                h.x = bfrne(pf[j].x); h.y = bfrne(pf[j].y);
                h.z = bfrne(pf[j].z); h.w = bfrne(pf[j].w);
                *(ushort4*)&sA[ldso(arow, aq * 32 + j * 8)] = h;
            }
        } else {
            const int sec = kt / D;
#pragma unroll
            for (int j = 0; j < 4; ++j) {
                ushort4 h;
                if (ok) {
                    if (sec < 2) {
                        h = ps[j];
                    } else {
                        h.x = bfrne(bf2f(ps[j].x) * bf2f(ps[4 + j].x));
                        h.y = bfrne(bf2f(ps[j].y) * bf2f(ps[4 + j].y));
                        h.z = bfrne(bf2f(ps[j].z) * bf2f(ps[4 + j].z));
                        h.w = bfrne(bf2f(ps[j].w) * bf2f(ps[4 + j].w));
                    }
                } else {
                    h.x = h.y = h.z = h.w = 0;
                }
                *(ushort4*)&sA[ldso(arow, aq * 32 + j * 8)] = h;
            }
        }
#pragma unroll
        for (int i = 0; i < 4; ++i)
            *(bf16x8*)&sB[ldso(brow, bq * 64 + i * 16)] = pb[i];
    };

    prefA(0);
    prefB(0);

    for (int kt = 0; kt < K; kt += 64) {
        if (kt > 0) __syncthreads();
        storeAB(kt);
        __syncthreads();

        const int ktn = kt + 64;
        if (ktn < K) { prefA(ktn); prefB(ktn); }

#pragma unroll
        for (int ks = 0; ks < 2; ++ks) {
            bf16x8 fb[4];
#pragma unroll
            for (int ni = 0; ni < 4; ++ni)
                fb[ni] = *(const bf16x8*)&sB[ldso(wc + ni * 16 + ln, ks * 64 + kg * 16)];
#pragma unroll
            for (int mi = 0; mi < 2; ++mi) {
                bf16x8 fa = *(const bf16x8*)&sA[ldso(wr + mi * 16 + ln, ks * 64 + kg * 16)];
#pragma unroll
                for (int ni = 0; ni < 4; ++ni)
                    acc[mi][ni] = __builtin_amdgcn_mfma_f32_16x16x32_bf16(
                        fa, fb[ni], acc[mi][ni], 0, 0, 0);
            }
        }
    }

    // epilogue: row = (lane>>4)*4+reg, col = lane&15
#pragma unroll
    for (int mi = 0; mi < 2; ++mi)
#pragma unroll
        for (int ni = 0; ni < 4; ++ni) {
            int col = n0 + wc + ni * 16 + ln;
            f32x4 a = acc[mi][ni];
#pragma unroll
            for (int j = 0; j < 4; ++j) {
                int row = m0 + wr + mi * 16 + kg * 4 + j;
                if (row < M) {
                    float v = a[j] + bias[col];
                    if (ACT == 1) v = geluf(v);
                    if (OUTP == 0) Cf[(size_t)row * N + col] = v;
                    else           Ch[(size_t)row * N + col] = bfrne(v);
                }
            }
        }
}

// ---------------------------------------------------------------------------
// Weight transpose: W[K][N] fp32 -> WT[N][K] bf16 (RNE)
__global__ __launch_bounds__(256) void k_wt(const float* __restrict__ W,
                                            ushort* __restrict__ WTh, int K, int N)
{
    __shared__ float t[32][33];
    const int k0 = blockIdx.x * 32, n0 = blockIdx.y * 32;
    const int c = threadIdx.x & 31, r8 = threadIdx.x >> 5;
#pragma unroll
    for (int i = 0; i < 4; ++i) {
        int r = r8 + i * 8;
        t[r][c] = W[(size_t)(k0 + r) * N + n0 + c];
    }
    __syncthreads();
#pragma unroll
    for (int i = 0; i < 4; ++i) {
        int r = r8 + i * 8;
        WTh[(size_t)(n0 + r) * K + k0 + c] = bfrne(t[c][r]);
    }
}

// folded pair W1: Wf[2304][768] from pW1[3072][768]
__global__ void k_fold(const float* __restrict__ pW1, float* __restrict__ Wf, int n)
{
    int i = blockIdx.x * blockDim.x + threadIdx.x;
    if (i >= n) return;
    int row = i / D;
    float v;
    if (row < D)            v = pW1[i] - pW1[i + 1536 * D];
    else if (row < 2 * D)   v = pW1[i] + pW1[i + 768 * D];
    else                    v = pW1[i + 768 * D];
    Wf[i] = v;
}

// para fp32 -> bf16 plane (vectorized x4)
__global__ void k_cvt(const float* __restrict__ src, ushort* __restrict__ dst, int n4)
{
    int i = blockIdx.x * blockDim.x + threadIdx.x;
    if (i >= n4) return;
    float4 v = ((const float4*)src)[i];
    ushort4 h;
    h.x = bfrne(v.x); h.y = bfrne(v.y); h.z = bfrne(v.z); h.w = bfrne(v.w);
    ((ushort4*)dst)[i] = h;
}

// hid[r,:] = gelu(Tl[tok(c1)] + Tr[tok(c2)] + b)   one block per row, 768 cols
__global__ __launch_bounds__(256) void k_addgelu(
    const ushort* __restrict__ Tl, const ushort* __restrict__ Tr,
    const int* __restrict__ ppos, int c1, int c2,
    const float* __restrict__ b, ushort* __restrict__ out)
{
    const int rr = blockIdx.x;
    const int p = ppos[rr * 5];
    const size_t bl = (size_t)(p * LPARA + ppos[rr * 5 + c1]) * D;
    const size_t br = (size_t)(p * LPARA + ppos[rr * 5 + c2]) * D;
    const int tid = threadIdx.x;
#pragma unroll
    for (int i = 0; i < 3; ++i) {
        int d = tid + i * 256;
        float v = bf2f(Tl[bl + d]) + bf2f(Tr[br + d]) + b[d];
        out[(size_t)rr * D + d] = bfrne(geluf(v));
    }
}

// entity hidden via token embeddings: gelu(mean(Tl[tokL]+Tr[tokR]) + b)
__global__ __launch_bounds__(256) void k_entmean_t(
    const ushort* __restrict__ Tl, const ushort* __restrict__ Tr,
    const int* __restrict__ mpos, const int* __restrict__ mid, int M,
    const float* __restrict__ b, ushort* __restrict__ oh)
{
    __shared__ int sb[2];
    const int e = blockIdx.x;
    if (threadIdx.x < 2) {
        int target = e + threadIdx.x;
        int lo = 0, hi = M;
        while (lo < hi) {
            int md = (lo + hi) >> 1;
            if (mid[md] < target) lo = md + 1; else hi = md;
        }
        sb[threadIdx.x] = lo;
    }
    __syncthreads();
    const int lo = sb[0], hi = sb[1];
    const int tid = threadIdx.x;
    float s0 = 0, s1 = 0, s2 = 0;
    for (int m = lo; m < hi; ++m) {
        int p = mpos[m * 3], t1 = mpos[m * 3 + 1], t2 = mpos[m * 3 + 2];
        const ushort* L = Tl + (size_t)(p * LPARA + t1) * D;
        const ushort* R = Tr + (size_t)(p * LPARA + t2) * D;
        s0 += bf2f(L[tid])       + bf2f(R[tid]);
        s1 += bf2f(L[tid + 256]) + bf2f(R[tid + 256]);
        s2 += bf2f(L[tid + 512]) + bf2f(R[tid + 512]);
    }
    const float inv = (hi > lo) ? 1.0f / (float)(hi - lo) : 0.0f;
    size_t base = (size_t)e * D;
    oh[base + tid]       = bfrne(geluf(s0 * inv + b[tid]));
    oh[base + tid + 256] = bfrne(geluf(s1 * inv + b[tid + 256]));
    oh[base + tid + 512] = bfrne(geluf(s2 * inv + b[tid + 512]));
}

// ---------------------------------------------------------------------------
// Batched split-K matvec (deterministic). grid (N/64, nks, T).
__global__ __launch_bounds__(256) void k_mvpart(
    const float* __restrict__ x, int xstride,
    const float* __restrict__ W, float* __restrict__ acc, int K, int N, int nks)
{
    const int t = blockIdx.z;
    const float* xt = x + (size_t)t * xstride;
    const float* Wt = W + (size_t)t * K * N;
    const int jj = threadIdx.x & 63;
    const int kq = threadIdx.x >> 6;
    const int j = blockIdx.x * 64 + jj;
    const int kchunk = K / (nks * 4);
    const int kbeg = (blockIdx.y * 4 + kq) * kchunk;
    float s = 0.0f;
    for (int k = kbeg; k < kbeg + kchunk; ++k)
        s = fmaf(xt[k], Wt[(size_t)k * N + j], s);
    __shared__ float red[256];
    red[threadIdx.x] = s;
    __syncthreads();
    if (kq == 0) {
        float v = red[jj] + red[64 + jj] + red[128 + jj] + red[192 + jj];
        acc[((size_t)(t * nks) + blockIdx.y) * N + j] = v;
    }
}

__global__ void k_biasact(const float* __restrict__ acc, const float* __restrict__ b,
                          float* __restrict__ out, int N, int nks, int act)
{
    const int t = blockIdx.y;
    const int j = blockIdx.x * 256 + threadIdx.x;
    if (j >= N) return;
    float s = 0.0f;
    for (int i = 0; i < nks; ++i) s += acc[((size_t)(t * nks) + i) * N + j];
    s += b[(size_t)t * N + j];
    if (act) s = geluf(s);
    out[(size_t)t * N + j] = s;
}

__global__ void k_dot3(const float* __restrict__ x, const float* __restrict__ W,
                       const float* __restrict__ b, float* __restrict__ out)
{
    int j = threadIdx.x >> 6, lane = threadIdx.x & 63;
    if (j >= 3) return;
    float s = 0.0f;
#pragma unroll
    for (int i = 0; i < 4; ++i) {
        int k = lane + i * 64;
        s += x[k] * W[k * 3 + j];
    }
    for (int off = 32; off > 0; off >>= 1) s += __shfl_down(s, off, 64);
    if (lane == 0) out[j] = s + b[j];
}

__global__ void k_ctx3(const float* __restrict__ cq3, const float* __restrict__ qwh,
                       float* __restrict__ ctx3)
{
    const float* cq = cq3 + (size_t)blockIdx.x * D;
    float* ctx = ctx3 + (size_t)blockIdx.x * D;
    __shared__ float red[256];
    __shared__ float dist[LQ];
    const int tid = threadIdx.x;
    const int l = tid >> 3, part = tid & 7;
    float s = 0.0f;
    for (int d = part; d < D; d += 8) s += cq[d] * qwh[l * D + d];
    red[tid] = s;
    __syncthreads();
    if (part == 0) {
        float v = 0;
        for (int i = 0; i < 8; ++i) v += red[l * 8 + i];
        dist[l] = v;
    }
    __syncthreads();
    if (tid == 0) {
        float mx = -1e30f;
        for (int i = 0; i < LQ; ++i) mx = fmaxf(mx, dist[i]);
        float sm = 0;
        for (int i = 0; i < LQ; ++i) { float e = expf(dist[i] - mx); dist[i] = e; sm += e; }
        float inv = 1.0f / sm;
        for (int i = 0; i < LQ; ++i) dist[i] *= inv;
    }
    __syncthreads();
    for (int d = tid; d < D; d += 256) {
        float v = 0;
#pragma unroll
        for (int l2 = 0; l2 < LQ; ++l2) v += dist[l2] * qwh[l2 * D + d];
        ctx[d] = v + cq[d];
    }
}

__global__ void k_scalew(const float* __restrict__ ctx, const float* __restrict__ w1,
                         float* __restrict__ o, int n)
{
    int i = blockIdx.x * 256 + threadIdx.x;
    if (i < n) o[i] = ctx[i >> 8] * w1[i];
}

template <int PAIRMODE>
__global__ void k_rowdot(const float* __restrict__ H, const float* __restrict__ w2,
                         const float* __restrict__ sb2, int Nr,
                         float* __restrict__ simout,
                         const float* __restrict__ laste, const int* __restrict__ so,
                         float* __restrict__ newe)
{
    int r = blockIdx.x * 4 + (threadIdx.x >> 6);
    int lane = threadIdx.x & 63;
    if (r >= Nr) return;
    float s = 0.0f;
#pragma unroll
    for (int i = 0; i < 4; ++i)
        s += H[(size_t)r * 256 + lane + i * 64] * w2[lane + i * 64];
    for (int off = 32; off > 0; off >>= 1) s += __shfl_down(s, off, 64);
    if (lane == 0) {
        s += sb2[0];
        if (PAIRMODE == 0) {
            simout[r] = s;
        } else {
            float p = 1.0f / (1.0f + expf(-s));
            float v = laste[so[r * 2]] * p;
            atomicAdd(&newe[so[r * 2 + 1]], v);
        }
    }
}

__global__ void k_softmax(const float* __restrict__ sim, float* __restrict__ outp, int n)
{
    __shared__ float red[256];
    __shared__ float s_mx, s_sum;
    const int tid = threadIdx.x;
    float mx = -1e30f;
    for (int i = tid; i < n; i += 256) mx = fmaxf(mx, sim[i]);
    red[tid] = mx; __syncthreads();
    for (int off = 128; off > 0; off >>= 1) {
        if (tid < off) red[tid] = fmaxf(red[tid], red[tid + off]);
        __syncthreads();
    }
    if (tid == 0) s_mx = red[0];
    __syncthreads();
    const float mxv = s_mx;
    float sum = 0;
    for (int i = tid; i < n; i += 256) sum += expf(sim[i] - mxv);
    red[tid] = sum; __syncthreads();
    for (int off = 128; off > 0; off >>= 1) {
        if (tid < off) red[tid] += red[tid + off];
        __syncthreads();
    }
    if (tid == 0) s_sum = red[0];
    __syncthreads();
    const float inv = 1.0f / s_sum;
    for (int i = tid; i < n; i += 256) {
        float v = expf(sim[i] - mxv) * inv;
        outp[i] = v / fmaxf(v, 1.0f);
    }
}

__global__ void k_zero(float* p, int n)
{
    int i = blockIdx.x * blockDim.x + threadIdx.x;
    if (i < n) p[i] = 0.0f;
}

__global__ void k_clampstore(const float* __restrict__ ne, float* __restrict__ outp, int n)
{
    int i = blockIdx.x * blockDim.x + threadIdx.x;
    if (i < n) { float v = ne[i]; outp[i] = v / fmaxf(v, 1.0f); }
}

__global__ void k_final(const float* __restrict__ probs, const float* __restrict__ hlog,
                        float* __restrict__ out, int n)
{
    int i = blockIdx.x * blockDim.x + threadIdx.x;
    if (i >= n) return;
    float l0 = hlog[0], l1 = hlog[1], l2 = hlog[2];
    float m = fmaxf(l0, fmaxf(l1, l2));
    float e0 = expf(l0 - m), e1 = expf(l1 - m), e2 = expf(l2 - m);
    float inv = 1.0f / (e0 + e1 + e2);
    out[i] = (e0 * probs[i] + e1 * probs[n + i] + e2 * probs[2 * n + i]) * inv;
}

// ---------------------------------------------------------------------------
extern "C" void kernel_launch(void* const* d_in, const int* in_sizes, int n_in,
                              void* d_out, int out_size, void* d_ws, size_t ws_size,
                              hipStream_t stream)
{
    const size_t WS_NEED = 148010384;  // 141.2 MiB (<= 148,793,744 proven OK)
    if (ws_size < WS_NEED) return;

    const float* para  = (const float*)d_in[0];
    const float* q     = (const float*)d_in[1];
    const float* qwh   = (const float*)d_in[2];
    const float* stW1  = (const float*)d_in[3];
    const float* stb1  = (const float*)d_in[4];
    const float* stW2  = (const float*)d_in[5];
    const float* stb2  = (const float*)d_in[6];
    const float* mW1   = (const float*)d_in[7];
    const float* mb1   = (const float*)d_in[8];
    const float* mW2   = (const float*)d_in[9];
    const float* mb2   = (const float*)d_in[10];
    const float* pW1   = (const float*)d_in[11];
    const float* pb1   = (const float*)d_in[12];
    const float* pW2   = (const float*)d_in[13];
    const float* pb2   = (const float*)d_in[14];
    const float* simW1 = (const float*)d_in[15];
    const float* simb1 = (const float*)d_in[16];
    const float* simW2 = (const float*)d_in[17];
    const float* simb2 = (const float*)d_in[18];
    const float* hW1   = (const float*)d_in[19];
    const float* hb1   = (const float*)d_in[20];
    const float* hW2   = (const float*)d_in[21];
    const float* hb2   = (const float*)d_in[22];
    const int*   mpos  = (const int*)d_in[23];
    const int*   mid   = (const int*)d_in[24];
    const int*   ppos  = (const int*)d_in[25];
    const int*   pso   = (const int*)d_in[26];

    // ---- workspace: 5 big regions (phase-overlapped) + weights + fp32 tail ----
    ushort* ws16 = (ushort*)d_ws;
    ushort* R1 = ws16;                     // 15,360,000: Wfold -> PB16 -> objhid -> pairhid
    ushort* R2 = R1 + 15360000;            // 15,360,000: Tl -> E -> pair_emb
    ushort* R3 = R2 + 15360000;            // 15,360,000: Tr -> H256(step0) -> sub_feat
    ushort* R4 = R3 + 15360000;            // 15,360,000: W1s tmp -> subhid -> obj_feat -> H256(1,2)
    ushort* R5 = R4 + 15360000;            //  7,680,000: enthid
    ushort* WlT   = R5 + 7680000;          //    589,824
    ushort* WrT   = WlT + 589824;          //    589,824
    ushort* mW2T  = WrT + 589824;          //    589,824
    ushort* WfT   = mW2T + 589824;         //  1,769,472
    ushort* pW2T  = WfT + 1769472;         //    589,824
    ushort* W1sT0 = pW2T + 589824;         //    589,824 (3 x 196,608)
    float*  tail  = (float*)(W1sT0 + 589824);
    float*  simb  = tail;                  // 20,000
    float*  probs = simb + 20000;          // 30,000
    float*  newe  = probs + 30000;         // 10,000
    float*  acc3  = newe + 10000;          // 13,824
    float*  h3    = acc3 + 13824;          // 2,304
    float*  cq3   = h3   + 2304;           // 2,304
    float*  ctx3  = cq3  + 2304;           // 2,304
    float*  hacc  = ctx3 + 2304;           // 1,536
    float*  hh    = hacc + 1536;           // 256
    float*  hlog  = hh   + 256;            // 4
    float*  zb    = hlog + 4;              // 768 (zero bias)

    float*  Wfold = (float*)R1;            // fp32 tmp (consumed before PB16)
    float*  W1s   = (float*)R4;            // fp32 tmp (consumed before subhid)
    ushort* PB16  = R1;                    // para bf16 [16384][768]
    ushort* Tl    = R2;                    // token emb L [16384][768]
    ushort* Tr    = R3;                    // token emb R
    ushort* enthid = R5;
    ushort* subhid = R4;
    ushort* objhid = R1;
    ushort* E      = R2;                   // [10000][768]
    float*  H256a  = (float*)R3;           // [10000][256] fp32
    ushort* subf   = R3;                   // [20000][768]
    ushort* objf   = R4;
    ushort* pairh  = R1;
    ushort* pairE  = R2;
    float*  H256b  = (float*)R4;           // [20000][256] fp32

    dim3 B256(256);
    const ushort* np = nullptr;

    // 0) weight prep (Wfold in R1, consumed immediately)
    k_fold<<<(2304 * D + 255) / 256, B256, 0, stream>>>(pW1, Wfold, 2304 * D);
    k_wt<<<dim3(24, 24), B256, 0, stream>>>(mW1, WlT, D, D);                 // rows 0..767
    k_wt<<<dim3(24, 24), B256, 0, stream>>>(mW1 + (size_t)D * D, WrT, D, D); // rows 768..1535
    k_wt<<<dim3(24, 24), B256, 0, stream>>>(mW2, mW2T, D, D);
    k_wt<<<dim3(72, 24), B256, 0, stream>>>(Wfold, WfT, 3 * D, D);
    k_wt<<<dim3(24, 24), B256, 0, stream>>>(pW2, pW2T, D, D);
    k_zero<<<3, B256, 0, stream>>>(zb, D);

    // 1) batched step MLPs + ctx + scaled sim weights (W1s tmp in R4)
    k_mvpart<<<dim3(12, 6, 3), B256, 0, stream>>>(q, 0, stW1, acc3, D, D, 6);
    k_biasact<<<dim3(3, 3), B256, 0, stream>>>(acc3, stb1, h3, D, 6, 1);
    k_mvpart<<<dim3(12, 6, 3), B256, 0, stream>>>(h3, D, stW2, acc3, D, D, 6);
    k_biasact<<<dim3(3, 3), B256, 0, stream>>>(acc3, stb2, cq3, D, 6, 0);
    k_ctx3<<<3, B256, 0, stream>>>(cq3, qwh, ctx3);
    for (int t = 0; t < NSTEP; ++t) {
        k_scalew<<<768, 256, 0, stream>>>(ctx3 + (size_t)t * D, simW1, W1s, D * 256);
        k_wt<<<dim3(24, 8), B256, 0, stream>>>(W1s, W1sT0 + t * 196608, D, 256);
    }

    // 2) token embeddings: PB16 = bf16(para); Tl = PB16@Wl, Tr = PB16@Wr
    k_cvt<<<(NTOK * D / 4 + 255) / 256, B256, 0, stream>>>(para, PB16, NTOK * D / 4);
    gemm_m<0, 0, 1><<<1536, B256, 0, stream>>>(PB16, nullptr, nullptr, 0, 0, np, np,
        WlT, zb, nullptr, Tl, NTOK, D, D, 6);
    gemm_m<0, 0, 1><<<1536, B256, 0, stream>>>(PB16, nullptr, nullptr, 0, 0, np, np,
        WrT, zb, nullptr, Tr, NTOK, D, D, 6);

    // 3) hiddens via gather-add-gelu (replaces the three K=1536 W1 GEMMs)
    k_entmean_t<<<NENT, 256, 0, stream>>>(Tl, Tr, mpos, mid, MMENT, mb1, enthid);
    k_addgelu<<<NPAIR, 256, 0, stream>>>(Tl, Tr, ppos, 1, 2, mb1, subhid);
    k_addgelu<<<NPAIR, 256, 0, stream>>>(Tl, Tr, ppos, 3, 4, mb1, objhid);

    // 4) ent_emb + step 0 sim -> probs[0]
    gemm_m<0, 0, 1><<<942, B256, 0, stream>>>(enthid, nullptr, nullptr, 0, 0, np, np,
        mW2T, mb2, nullptr, E, NENT, D, D, 6);
    gemm_m<0, 1, 0><<<314, B256, 0, stream>>>(E, nullptr, nullptr, 0, 0, np, np,
        W1sT0, simb1, H256a, nullptr, NENT, 256, D, 2);
    k_rowdot<0><<<NENT / 4, 256, 0, stream>>>(H256a, simW2, simb2, NENT, simb,
                                              nullptr, nullptr, nullptr);
    k_softmax<<<1, 256, 0, stream>>>(simb, probs, NENT);

    // 5) pair features + pair_emb
    gemm_m<0, 0, 1><<<1878, B256, 0, stream>>>(subhid, nullptr, nullptr, 0, 0, np, np,
        mW2T, mb2, nullptr, subf, NPAIR, D, D, 6);
    gemm_m<0, 0, 1><<<1878, B256, 0, stream>>>(objhid, nullptr, nullptr, 0, 0, np, np,
        mW2T, mb2, nullptr, objf, NPAIR, D, D, 6);
    gemm_m<2, 1, 1><<<1878, B256, 0, stream>>>(np, nullptr, nullptr, 0, 0, subf, objf,
        WfT, pb1, nullptr, pairh, NPAIR, D, 3 * D, 6);
    gemm_m<0, 0, 1><<<1878, B256, 0, stream>>>(pairh, nullptr, nullptr, 0, 0, np, np,
        pW2T, pb2, nullptr, pairE, NPAIR, D, D, 6);

    // 6) steps 1,2: sim on pairs + scatter-propagate
    for (int t = 1; t < NSTEP; ++t) {
        gemm_m<0, 1, 0><<<626, B256, 0, stream>>>(pairE, nullptr, nullptr, 0, 0, np, np,
            W1sT0 + t * 196608, simb1, H256b, nullptr, NPAIR, 256, D, 2);
        k_zero<<<40, 256, 0, stream>>>(newe, NENT);
        k_rowdot<1><<<NPAIR / 4, 256, 0, stream>>>(H256b, simW2, simb2, NPAIR, nullptr,
                                                   probs + (t - 1) * NENT, pso, newe);
        k_clampstore<<<40, 256, 0, stream>>>(newe, probs + t * NENT, NENT);
    }

    // 7) hop attention + final mix
    k_mvpart<<<dim3(4, 6, 1), B256, 0, stream>>>(q, 0, hW1, hacc, D, 256, 6);
    k_biasact<<<dim3(1, 1), B256, 0, stream>>>(hacc, hb1, hh, 256, 6, 1);
    k_dot3<<<1, B256, 0, stream>>>(hh, hW2, hb2, hlog);
    k_final<<<40, 256, 0, stream>>>(probs, hlog, (float*)d_out, NENT);
}

// Round 20
// 667.208 us; speedup vs baseline: 2.5218x; 1.0092x over previous
//
#include <hip/hip_runtime.h>
#include <math.h>

// ---------------------------------------------------------------------------
#define D 768
#define NPARA 32
#define LPARA 512
#define LQ 32
#define NENT 10000
#define MMENT 30000
#define NPAIR 20000
#define NSTEP 3
#define NTOK (NPARA * LPARA)   // 16384 unique tokens
#define TSTR 1536              // TLR row stride (Tl cols 0..767, Tr 768..1535)

using bf16x8 = __attribute__((ext_vector_type(8))) short;
using f32x4  = __attribute__((ext_vector_type(4))) float;

__device__ __forceinline__ float geluf(float x) {
    return 0.5f * x * (1.0f + erff(x * 0.70710678118654752f));
}
__device__ __forceinline__ float bf2f(ushort h) {
    union { unsigned u; float f; } v; v.u = ((unsigned)h) << 16; return v.f;
}
// round-to-nearest-even fp32 -> bf16
__device__ __forceinline__ ushort bfrne(float x) {
    union { float f; unsigned u; } v; v.f = x;
    unsigned r = (v.u + 0x7FFF + ((v.u >> 16) & 1)) >> 16;
    return (ushort)r;
}

// ---------------------------------------------------------------------------
// Single-plane bf16 MFMA GEMM. 64x128 tile, A+B LDS (XOR-swizzled), register
// prefetch of next A and B tiles, band-major XCD swizzle.
// R12 KNOWN-GOOD TEMPLATE (VGPR 60, no spill) — body must stay byte-identical.
// R13/R14 (MI=4) and R16 (merged prefetch) all perturbed regalloc -> spill.
// MODE 0: A = bf16 plane [M][K]
// MODE 1: A row r = concat(para[p,t1,:], para[p,t2,:]) fp32 gather (UNUSED now)
// MODE 2: A row r, sections {S, O, S*O} from bf16 feats, K=2304 (folded W1)
// B: pre-transposed bf16 weights WT[N][K]. OUTP 0: fp32 C; 1: bf16 C.
// ---------------------------------------------------------------------------
#define BM 64
#define BN 128

__device__ __forceinline__ int ldso(int row, int kb) {   // ushort index
    return row * 64 + (((kb) ^ ((row & 7) << 4)) >> 1);
}

template <int MODE, int ACT, int OUTP>
__global__ __launch_bounds__(256, 4) void gemm_m(
    const ushort* __restrict__ Ah,
    const float* __restrict__ para, const int* __restrict__ ppos, int c1, int c2,
    const ushort* __restrict__ Sh, const ushort* __restrict__ Oh,
    const ushort* __restrict__ Bh, const float* __restrict__ bias,
    float* __restrict__ Cf, ushort* __restrict__ Ch,
    int M, int N, int K, int nby)
{
    __shared__ ushort sA[BM * 64];   //  8 KB
    __shared__ ushort sB[BN * 64];   // 16 KB

    const int nwg = gridDim.x;
    const int q = nwg >> 3, r = nwg & 7;
    const int xcd = blockIdx.x & 7, idx = blockIdx.x >> 3;
    const int wgid = (xcd < r) ? xcd * (q + 1) + idx
                               : r * (q + 1) + (xcd - r) * q + idx;
    const int m0 = (wgid / nby) * BM;
    const int n0 = (wgid % nby) * BN;

    const int tid = threadIdx.x;
    const int lane = tid & 63;
    const int wv = tid >> 6;
    const int wr = (wv >> 1) * 32;
    const int wc = (wv & 1) * 64;
    const int ln = lane & 15;
    const int kg = lane >> 4;

    f32x4 acc[2][4];
#pragma unroll
    for (int i = 0; i < 2; ++i)
#pragma unroll
        for (int j = 0; j < 4; ++j)
#pragma unroll
            for (int e = 0; e < 4; ++e) acc[i][j][e] = 0.0f;

    const int arow = tid >> 2, aq = tid & 3;   // A: 4 thr/row, 16 ushort each
    const int brow = tid >> 1, bq = tid & 1;   // B: 2 thr/row, 32 ushort each
    const int gm = m0 + arow;
    const bool ok = gm < M;

    int baseL = 0, baseR = 0;
    if (MODE == 1 && ok) {
        int p = ppos[gm * 5];
        baseL = (p * LPARA + ppos[gm * 5 + c1]) * D;
        baseR = (p * LPARA + ppos[gm * 5 + c2]) * D;
    }

    bf16x8 pa[2];     // MODE 0 prefetch
    float4 pf[4];     // MODE 1 prefetch (16 fp32)
    ushort4 ps[8];    // MODE 2 prefetch (S and/or O quads)
    bf16x8 pb[4];     // B prefetch (32 ushorts)

    auto prefA = [&](int kt) {
        if (MODE == 0) {
            if (ok) {
                const ushort* g = Ah + (size_t)gm * K + kt + aq * 16;
                pa[0] = *(const bf16x8*)g;
                pa[1] = *(const bf16x8*)(g + 8);
            } else {
#pragma unroll
                for (int i = 0; i < 2; ++i)
#pragma unroll
                    for (int z = 0; z < 8; ++z) pa[i][z] = 0;
            }
        } else if (MODE == 1) {
            const int kb = kt + aq * 16;            // never crosses D boundary
            const int gb = (kb < D) ? (baseL + kb) : (baseR + kb - D);
#pragma unroll
            for (int j = 0; j < 4; ++j)
                pf[j] = ok ? *(const float4*)(para + gb + j * 4)
                           : make_float4(0.f, 0.f, 0.f, 0.f);
        } else {
            const int sec = kt / D;
            const size_t rb = (size_t)gm * D + (kt - sec * D) + aq * 16;
            if (ok) {
                if (sec == 0) {
#pragma unroll
                    for (int j = 0; j < 4; ++j)
                        ps[j] = *(const ushort4*)(Sh + rb + j * 4);
                } else if (sec == 1) {
#pragma unroll
                    for (int j = 0; j < 4; ++j)
                        ps[j] = *(const ushort4*)(Oh + rb + j * 4);
                } else {
#pragma unroll
                    for (int j = 0; j < 4; ++j) {
                        ps[j]     = *(const ushort4*)(Sh + rb + j * 4);
                        ps[4 + j] = *(const ushort4*)(Oh + rb + j * 4);
                    }
                }
            }
        }
    };

    auto prefB = [&](int kt) {
        const ushort* g = Bh + (size_t)(n0 + brow) * K + kt + bq * 32;
#pragma unroll
        for (int i = 0; i < 4; ++i)
            pb[i] = *(const bf16x8*)(g + i * 8);
    };

    auto storeAB = [&](int kt) {
        if (MODE == 0) {
            int o0 = ldso(arow, aq * 32), o1 = ldso(arow, aq * 32 + 16);
            *(bf16x8*)&sA[o0] = pa[0];
            *(bf16x8*)&sA[o1] = pa[1];
        } else if (MODE == 1) {
#pragma unroll
            for (int j = 0; j < 4; ++j) {
                ushort4 h;
                h.x = bfrne(pf[j].x); h.y = bfrne(pf[j].y);
                h.z = bfrne(pf[j].z); h.w = bfrne(pf[j].w);
                *(ushort4*)&sA[ldso(arow, aq * 32 + j * 8)] = h;
            }
        } else {
            const int sec = kt / D;
#pragma unroll
            for (int j = 0; j < 4; ++j) {
                ushort4 h;
                if (ok) {
                    if (sec < 2) {
                        h = ps[j];
                    } else {
                        h.x = bfrne(bf2f(ps[j].x) * bf2f(ps[4 + j].x));
                        h.y = bfrne(bf2f(ps[j].y) * bf2f(ps[4 + j].y));
                        h.z = bfrne(bf2f(ps[j].z) * bf2f(ps[4 + j].z));
                        h.w = bfrne(bf2f(ps[j].w) * bf2f(ps[4 + j].w));
                    }
                } else {
                    h.x = h.y = h.z = h.w = 0;
                }
                *(ushort4*)&sA[ldso(arow, aq * 32 + j * 8)] = h;
            }
        }
#pragma unroll
        for (int i = 0; i < 4; ++i)
            *(bf16x8*)&sB[ldso(brow, bq * 64 + i * 16)] = pb[i];
    };

    prefA(0);
    prefB(0);

    for (int kt = 0; kt < K; kt += 64) {
        if (kt > 0) __syncthreads();
        storeAB(kt);
        __syncthreads();

        const int ktn = kt + 64;
        if (ktn < K) { prefA(ktn); prefB(ktn); }

#pragma unroll
        for (int ks = 0; ks < 2; ++ks) {
            bf16x8 fb[4];
#pragma unroll
            for (int ni = 0; ni < 4; ++ni)
                fb[ni] = *(const bf16x8*)&sB[ldso(wc + ni * 16 + ln, ks * 64 + kg * 16)];
#pragma unroll
            for (int mi = 0; mi < 2; ++mi) {
                bf16x8 fa = *(const bf16x8*)&sA[ldso(wr + mi * 16 + ln, ks * 64 + kg * 16)];
#pragma unroll
                for (int ni = 0; ni < 4; ++ni)
                    acc[mi][ni] = __builtin_amdgcn_mfma_f32_16x16x32_bf16(
                        fa, fb[ni], acc[mi][ni], 0, 0, 0);
            }
        }
    }

    // epilogue: row = (lane>>4)*4+reg, col = lane&15
#pragma unroll
    for (int mi = 0; mi < 2; ++mi)
#pragma unroll
        for (int ni = 0; ni < 4; ++ni) {
            int col = n0 + wc + ni * 16 + ln;
            f32x4 a = acc[mi][ni];
#pragma unroll
            for (int j = 0; j < 4; ++j) {
                int row = m0 + wr + mi * 16 + kg * 4 + j;
                if (row < M) {
                    float v = a[j] + bias[col];
                    if (ACT == 1) v = geluf(v);
                    if (OUTP == 0) Cf[(size_t)row * N + col] = v;
                    else           Ch[(size_t)row * N + col] = bfrne(v);
                }
            }
        }
}

// ---------------------------------------------------------------------------
// Weight transpose: W[K][N] fp32 -> WT[N][K] bf16 (RNE)
__global__ __launch_bounds__(256) void k_wt(const float* __restrict__ W,
                                            ushort* __restrict__ WTh, int K, int N)
{
    __shared__ float t[32][33];
    const int k0 = blockIdx.x * 32, n0 = blockIdx.y * 32;
    const int c = threadIdx.x & 31, r8 = threadIdx.x >> 5;
#pragma unroll
    for (int i = 0; i < 4; ++i) {
        int r = r8 + i * 8;
        t[r][c] = W[(size_t)(k0 + r) * N + n0 + c];
    }
    __syncthreads();
#pragma unroll
    for (int i = 0; i < 4; ++i) {
        int r = r8 + i * 8;
        WTh[(size_t)(n0 + r) * K + k0 + c] = bfrne(t[c][r]);
    }
}

// folded pair W1: Wf[2304][768] from pW1[3072][768]
__global__ void k_fold(const float* __restrict__ pW1, float* __restrict__ Wf, int n)
{
    int i = blockIdx.x * blockDim.x + threadIdx.x;
    if (i >= n) return;
    int row = i / D;
    float v;
    if (row < D)            v = pW1[i] - pW1[i + 1536 * D];
    else if (row < 2 * D)   v = pW1[i] + pW1[i + 768 * D];
    else                    v = pW1[i + 768 * D];
    Wf[i] = v;
}

// para fp32 -> bf16 plane (vectorized x4)
__global__ void k_cvt(const float* __restrict__ src, ushort* __restrict__ dst, int n4)
{
    int i = blockIdx.x * blockDim.x + threadIdx.x;
    if (i >= n4) return;
    float4 v = ((const float4*)src)[i];
    ushort4 h;
    h.x = bfrne(v.x); h.y = bfrne(v.y); h.z = bfrne(v.z); h.w = bfrne(v.w);
    ((ushort4*)dst)[i] = h;
}

// hid[r,:] = gelu(TLR[tok(c1)][0:768] + TLR[tok(c2)][768:1536] + b)
__global__ __launch_bounds__(256) void k_addgelu(
    const ushort* __restrict__ T,
    const int* __restrict__ ppos, int c1, int c2,
    const float* __restrict__ b, ushort* __restrict__ out)
{
    const int rr = blockIdx.x;
    const int p = ppos[rr * 5];
    const size_t bl = (size_t)(p * LPARA + ppos[rr * 5 + c1]) * TSTR;
    const size_t br = (size_t)(p * LPARA + ppos[rr * 5 + c2]) * TSTR + D;
    const int tid = threadIdx.x;
#pragma unroll
    for (int i = 0; i < 3; ++i) {
        int d = tid + i * 256;
        float v = bf2f(T[bl + d]) + bf2f(T[br + d]) + b[d];
        out[(size_t)rr * D + d] = bfrne(geluf(v));
    }
}

// entity hidden via token embeddings: gelu(mean(Tl[tokL]+Tr[tokR]) + b)
__global__ __launch_bounds__(256) void k_entmean_t(
    const ushort* __restrict__ T,
    const int* __restrict__ mpos, const int* __restrict__ mid, int M,
    const float* __restrict__ b, ushort* __restrict__ oh)
{
    __shared__ int sb[2];
    const int e = blockIdx.x;
    if (threadIdx.x < 2) {
        int target = e + threadIdx.x;
        int lo = 0, hi = M;
        while (lo < hi) {
            int md = (lo + hi) >> 1;
            if (mid[md] < target) lo = md + 1; else hi = md;
        }
        sb[threadIdx.x] = lo;
    }
    __syncthreads();
    const int lo = sb[0], hi = sb[1];
    const int tid = threadIdx.x;
    float s0 = 0, s1 = 0, s2 = 0;
    for (int m = lo; m < hi; ++m) {
        int p = mpos[m * 3], t1 = mpos[m * 3 + 1], t2 = mpos[m * 3 + 2];
        const ushort* L = T + (size_t)(p * LPARA + t1) * TSTR;
        const ushort* R = T + (size_t)(p * LPARA + t2) * TSTR + D;
        s0 += bf2f(L[tid])       + bf2f(R[tid]);
        s1 += bf2f(L[tid + 256]) + bf2f(R[tid + 256]);
        s2 += bf2f(L[tid + 512]) + bf2f(R[tid + 512]);
    }
    const float inv = (hi > lo) ? 1.0f / (float)(hi - lo) : 0.0f;
    size_t base = (size_t)e * D;
    oh[base + tid]       = bfrne(geluf(s0 * inv + b[tid]));
    oh[base + tid + 256] = bfrne(geluf(s1 * inv + b[tid + 256]));
    oh[base + tid + 512] = bfrne(geluf(s2 * inv + b[tid + 512]));
}

// ---------------------------------------------------------------------------
// Batched split-K matvec (deterministic). grid (N/64, nks, T).
__global__ __launch_bounds__(256) void k_mvpart(
    const float* __restrict__ x, int xstride,
    const float* __restrict__ W, float* __restrict__ acc, int K, int N, int nks)
{
    const int t = blockIdx.z;
    const float* xt = x + (size_t)t * xstride;
    const float* Wt = W + (size_t)t * K * N;
    const int jj = threadIdx.x & 63;
    const int kq = threadIdx.x >> 6;
    const int j = blockIdx.x * 64 + jj;
    const int kchunk = K / (nks * 4);
    const int kbeg = (blockIdx.y * 4 + kq) * kchunk;
    float s = 0.0f;
    for (int k = kbeg; k < kbeg + kchunk; ++k)
        s = fmaf(xt[k], Wt[(size_t)k * N + j], s);
    __shared__ float red[256];
    red[threadIdx.x] = s;
    __syncthreads();
    if (kq == 0) {
        float v = red[jj] + red[64 + jj] + red[128 + jj] + red[192 + jj];
        acc[((size_t)(t * nks) + blockIdx.y) * N + j] = v;
    }
}

__global__ void k_biasact(const float* __restrict__ acc, const float* __restrict__ b,
                          float* __restrict__ out, int N, int nks, int act)
{
    const int t = blockIdx.y;
    const int j = blockIdx.x * 256 + threadIdx.x;
    if (j >= N) return;
    float s = 0.0f;
    for (int i = 0; i < nks; ++i) s += acc[((size_t)(t * nks) + i) * N + j];
    s += b[(size_t)t * N + j];
    if (act) s = geluf(s);
    out[(size_t)t * N + j] = s;
}

__global__ void k_dot3(const float* __restrict__ x, const float* __restrict__ W,
                       const float* __restrict__ b, float* __restrict__ out)
{
    int j = threadIdx.x >> 6, lane = threadIdx.x & 63;
    if (j >= 3) return;
    float s = 0.0f;
#pragma unroll
    for (int i = 0; i < 4; ++i) {
        int k = lane + i * 64;
        s += x[k] * W[k * 3 + j];
    }
    for (int off = 32; off > 0; off >>= 1) s += __shfl_down(s, off, 64);
    if (lane == 0) out[j] = s + b[j];
}

__global__ void k_ctx3(const float* __restrict__ cq3, const float* __restrict__ qwh,
                       float* __restrict__ ctx3)
{
    const float* cq = cq3 + (size_t)blockIdx.x * D;
    float* ctx = ctx3 + (size_t)blockIdx.x * D;
    __shared__ float red[256];
    __shared__ float dist[LQ];
    const int tid = threadIdx.x;
    const int l = tid >> 3, part = tid & 7;
    float s = 0.0f;
    for (int d = part; d < D; d += 8) s += cq[d] * qwh[l * D + d];
    red[tid] = s;
    __syncthreads();
    if (part == 0) {
        float v = 0;
        for (int i = 0; i < 8; ++i) v += red[l * 8 + i];
        dist[l] = v;
    }
    __syncthreads();
    if (tid == 0) {
        float mx = -1e30f;
        for (int i = 0; i < LQ; ++i) mx = fmaxf(mx, dist[i]);
        float sm = 0;
        for (int i = 0; i < LQ; ++i) { float e = expf(dist[i] - mx); dist[i] = e; sm += e; }
        float inv = 1.0f / sm;
        for (int i = 0; i < LQ; ++i) dist[i] *= inv;
    }
    __syncthreads();
    for (int d = tid; d < D; d += 256) {
        float v = 0;
#pragma unroll
        for (int l2 = 0; l2 < LQ; ++l2) v += dist[l2] * qwh[l2 * D + d];
        ctx[d] = v + cq[d];
    }
}

__global__ void k_scalew(const float* __restrict__ ctx, const float* __restrict__ w1,
                         float* __restrict__ o, int n)
{
    int i = blockIdx.x * 256 + threadIdx.x;
    if (i < n) o[i] = ctx[i >> 8] * w1[i];
}

template <int PAIRMODE>
__global__ void k_rowdot(const float* __restrict__ H, const float* __restrict__ w2,
                         const float* __restrict__ sb2, int Nr,
                         float* __restrict__ simout,
                         const float* __restrict__ laste, const int* __restrict__ so,
                         float* __restrict__ newe)
{
    int r = blockIdx.x * 4 + (threadIdx.x >> 6);
    int lane = threadIdx.x & 63;
    if (r >= Nr) return;
    float s = 0.0f;
#pragma unroll
    for (int i = 0; i < 4; ++i)
        s += H[(size_t)r * 256 + lane + i * 64] * w2[lane + i * 64];
    for (int off = 32; off > 0; off >>= 1) s += __shfl_down(s, off, 64);
    if (lane == 0) {
        s += sb2[0];
        if (PAIRMODE == 0) {
            simout[r] = s;
        } else {
            float p = 1.0f / (1.0f + expf(-s));
            float v = laste[so[r * 2]] * p;
            atomicAdd(&newe[so[r * 2 + 1]], v);
        }
    }
}

__global__ void k_softmax(const float* __restrict__ sim, float* __restrict__ outp, int n)
{
    __shared__ float red[256];
    __shared__ float s_mx, s_sum;
    const int tid = threadIdx.x;
    float mx = -1e30f;
    for (int i = tid; i < n; i += 256) mx = fmaxf(mx, sim[i]);
    red[tid] = mx; __syncthreads();
    for (int off = 128; off > 0; off >>= 1) {
        if (tid < off) red[tid] = fmaxf(red[tid], red[tid + off]);
        __syncthreads();
    }
    if (tid == 0) s_mx = red[0];
    __syncthreads();
    const float mxv = s_mx;
    float sum = 0;
    for (int i = tid; i < n; i += 256) sum += expf(sim[i] - mxv);
    red[tid] = sum; __syncthreads();
    for (int off = 128; off > 0; off >>= 1) {
        if (tid < off) red[tid] += red[tid + off];
        __syncthreads();
    }
    if (tid == 0) s_sum = red[0];
    __syncthreads();
    const float inv = 1.0f / s_sum;
    for (int i = tid; i < n; i += 256) {
        float v = expf(sim[i] - mxv) * inv;
        outp[i] = v / fmaxf(v, 1.0f);
    }
}

__global__ void k_zero(float* p, int n)
{
    int i = blockIdx.x * blockDim.x + threadIdx.x;
    if (i < n) p[i] = 0.0f;
}

__global__ void k_clampstore(const float* __restrict__ ne, float* __restrict__ outp, int n)
{
    int i = blockIdx.x * blockDim.x + threadIdx.x;
    if (i < n) { float v = ne[i]; outp[i] = v / fmaxf(v, 1.0f); }
}

__global__ void k_final(const float* __restrict__ probs, const float* __restrict__ hlog,
                        float* __restrict__ out, int n)
{
    int i = blockIdx.x * blockDim.x + threadIdx.x;
    if (i >= n) return;
    float l0 = hlog[0], l1 = hlog[1], l2 = hlog[2];
    float m = fmaxf(l0, fmaxf(l1, l2));
    float e0 = expf(l0 - m), e1 = expf(l1 - m), e2 = expf(l2 - m);
    float inv = 1.0f / (e0 + e1 + e2);
    out[i] = (e0 * probs[i] + e1 * probs[n + i] + e2 * probs[2 * n + i]) * inv;
}

// ---------------------------------------------------------------------------
extern "C" void kernel_launch(void* const* d_in, const int* in_sizes, int n_in,
                              void* d_out, int out_size, void* d_ws, size_t ws_size,
                              hipStream_t stream)
{
    const size_t WS_NEED = 148010384;  // 141.2 MiB (proven OK at 148.8 MB)
    if (ws_size < WS_NEED) return;

    const float* para  = (const float*)d_in[0];
    const float* q     = (const float*)d_in[1];
    const float* qwh   = (const float*)d_in[2];
    const float* stW1  = (const float*)d_in[3];
    const float* stb1  = (const float*)d_in[4];
    const float* stW2  = (const float*)d_in[5];
    const float* stb2  = (const float*)d_in[6];
    const float* mW1   = (const float*)d_in[7];
    const float* mb1   = (const float*)d_in[8];
    const float* mW2   = (const float*)d_in[9];
    const float* mb2   = (const float*)d_in[10];
    const float* pW1   = (const float*)d_in[11];
    const float* pb1   = (const float*)d_in[12];
    const float* pW2   = (const float*)d_in[13];
    const float* pb2   = (const float*)d_in[14];
    const float* simW1 = (const float*)d_in[15];
    const float* simb1 = (const float*)d_in[16];
    const float* simW2 = (const float*)d_in[17];
    const float* simb2 = (const float*)d_in[18];
    const float* hW1   = (const float*)d_in[19];
    const float* hb1   = (const float*)d_in[20];
    const float* hW2   = (const float*)d_in[21];
    const float* hb2   = (const float*)d_in[22];
    const int*   mpos  = (const int*)d_in[23];
    const int*   mid   = (const int*)d_in[24];
    const int*   ppos  = (const int*)d_in[25];
    const int*   pso   = (const int*)d_in[26];

    // ---- workspace: 5 regions (phase-overlapped) + weights + fp32 tail ----
    ushort* ws16 = (ushort*)d_ws;
    ushort* R1 = ws16;                     // 15,360,000: PB16 -> objhid -> pairh
    ushort* R2 = R1 + 15360000;            // 15,360,000: Wfold -> TLR[0:10.2M) -> E -> pairE
    ushort* R3 = R2 + 15360000;            // 15,360,000: TLR[tail 9.8M) + H256a -> subf
    ushort* R4 = R3 + 15360000;            // 15,360,000: W1s -> subhid -> objf -> H256b
    ushort* R5 = R4 + 15360000;            //  7,680,000: enthid
    ushort* WlrT  = R5 + 7680000;          //  1,179,648 ([1536][768]: Wl rows 0-767, Wr 768-1535)
    ushort* mW2T  = WlrT + 1179648;        //    589,824
    ushort* WfT   = mW2T + 589824;         //  1,769,472
    ushort* pW2T  = WfT + 1769472;         //    589,824
    ushort* W1sT0 = pW2T + 589824;         //    589,824 (3 x 196,608)
    float*  tail  = (float*)(W1sT0 + 589824);
    float*  simb  = tail;                  // 20,000
    float*  probs = simb + 20000;          // 30,000
    float*  newe  = probs + 30000;         // 10,000
    float*  acc3  = newe + 10000;          // 13,824
    float*  h3    = acc3 + 13824;          // 2,304
    float*  cq3   = h3   + 2304;           // 2,304
    float*  ctx3  = cq3  + 2304;           // 2,304
    float*  hacc  = ctx3 + 2304;           // 1,536
    float*  hh    = hacc + 1536;           // 256
    float*  hlog  = hh   + 256;            // 4
    float*  zb    = hlog + 4;              // 1536 (zero bias)

    // phase overlays
    float*  Wfold = (float*)R2;            // fp32 tmp (consumed before TLR)
    float*  W1s   = (float*)R4;            // fp32 tmp (consumed before subhid)
    ushort* PB16  = R1;                    // para bf16 [16384][768]
    ushort* TLR   = R2;                    // [16384][1536], spans R2 + 9.8M of R3
    float*  H256a = (float*)(R3 + 9830400);// [10000][256] fp32 (after TLR tail; 9.83M+5.12M<15.36M)
    ushort* enthid = R5;
    ushort* subhid = R4;                   // (after W1s consumed)
    ushort* objhid = R1;                   // (after PB16 dead)
    ushort* E      = R2;                   // [10000][768] (TLR dead by then)
    ushort* subf   = R3;                   // [20000][768] (TLR + H256a dead)
    ushort* objf   = R4;                   // (subhid dead)
    ushort* pairh  = R1;                   // (objhid dead)
    ushort* pairE  = R2;                   // (E dead)
    float*  H256b  = (float*)R4;           // [20000][256] fp32 (objf dead)

    dim3 B256(256);
    const ushort* np = nullptr;

    // 0) weight prep (Wfold in R2, consumed before TLR written)
    k_fold<<<(2304 * D + 255) / 256, B256, 0, stream>>>(pW1, Wfold, 2304 * D);
    k_wt<<<dim3(24, 24), B256, 0, stream>>>(mW1, WlrT, D, D);                       // Wl
    k_wt<<<dim3(24, 24), B256, 0, stream>>>(mW1 + (size_t)D * D, WlrT + (size_t)D * D, D, D); // Wr
    k_wt<<<dim3(24, 24), B256, 0, stream>>>(mW2, mW2T, D, D);
    k_wt<<<dim3(72, 24), B256, 0, stream>>>(Wfold, WfT, 3 * D, D);
    k_wt<<<dim3(24, 24), B256, 0, stream>>>(pW2, pW2T, D, D);
    k_zero<<<6, B256, 0, stream>>>(zb, TSTR);

    // 1) batched step MLPs + ctx + scaled sim weights (W1s tmp in R4)
    k_mvpart<<<dim3(12, 6, 3), B256, 0, stream>>>(q, 0, stW1, acc3, D, D, 6);
    k_biasact<<<dim3(3, 3), B256, 0, stream>>>(acc3, stb1, h3, D, 6, 1);
    k_mvpart<<<dim3(12, 6, 3), B256, 0, stream>>>(h3, D, stW2, acc3, D, D, 6);
    k_biasact<<<dim3(3, 3), B256, 0, stream>>>(acc3, stb2, cq3, D, 6, 0);
    k_ctx3<<<3, B256, 0, stream>>>(cq3, qwh, ctx3);
    for (int t = 0; t < NSTEP; ++t) {
        k_scalew<<<768, 256, 0, stream>>>(ctx3 + (size_t)t * D, simW1, W1s, D * 256);
        k_wt<<<dim3(24, 8), B256, 0, stream>>>(W1s, W1sT0 + t * 196608, D, 256);
    }

    // 2) fused token embeddings: TLR = PB16 @ [Wl|Wr]  (M=16384, N=1536)
    k_cvt<<<(NTOK * D / 4 + 255) / 256, B256, 0, stream>>>(para, PB16, NTOK * D / 4);
    gemm_m<0, 0, 1><<<3072, B256, 0, stream>>>(PB16, nullptr, nullptr, 0, 0, np, np,
        WlrT, zb, nullptr, TLR, NTOK, TSTR, D, 12);

    // 3) hiddens via gather-add-gelu
    k_entmean_t<<<NENT, 256, 0, stream>>>(TLR, mpos, mid, MMENT, mb1, enthid);
    k_addgelu<<<NPAIR, 256, 0, stream>>>(TLR, ppos, 1, 2, mb1, subhid);
    k_addgelu<<<NPAIR, 256, 0, stream>>>(TLR, ppos, 3, 4, mb1, objhid);

    // 4) ent_emb + step 0 sim -> probs[0]
    gemm_m<0, 0, 1><<<942, B256, 0, stream>>>(enthid, nullptr, nullptr, 0, 0, np, np,
        mW2T, mb2, nullptr, E, NENT, D, D, 6);
    gemm_m<0, 1, 0><<<314, B256, 0, stream>>>(E, nullptr, nullptr, 0, 0, np, np,
        W1sT0, simb1, H256a, nullptr, NENT, 256, D, 2);
    k_rowdot<0><<<NENT / 4, 256, 0, stream>>>(H256a, simW2, simb2, NENT, simb,
                                              nullptr, nullptr, nullptr);
    k_softmax<<<1, 256, 0, stream>>>(simb, probs, NENT);

    // 5) pair features + pair_emb
    gemm_m<0, 0, 1><<<1878, B256, 0, stream>>>(subhid, nullptr, nullptr, 0, 0, np, np,
        mW2T, mb2, nullptr, subf, NPAIR, D, D, 6);
    gemm_m<0, 0, 1><<<1878, B256, 0, stream>>>(objhid, nullptr, nullptr, 0, 0, np, np,
        mW2T, mb2, nullptr, objf, NPAIR, D, D, 6);
    gemm_m<2, 1, 1><<<1878, B256, 0, stream>>>(np, nullptr, nullptr, 0, 0, subf, objf,
        WfT, pb1, nullptr, pairh, NPAIR, D, 3 * D, 6);
    gemm_m<0, 0, 1><<<1878, B256, 0, stream>>>(pairh, nullptr, nullptr, 0, 0, np, np,
        pW2T, pb2, nullptr, pairE, NPAIR, D, D, 6);

    // 6) steps 1,2: sim on pairs + scatter-propagate
    for (int t = 1; t < NSTEP; ++t) {
        gemm_m<0, 1, 0><<<626, B256, 0, stream>>>(pairE, nullptr, nullptr, 0, 0, np, np,
            W1sT0 + t * 196608, simb1, H256b, nullptr, NPAIR, 256, D, 2);
        k_zero<<<40, 256, 0, stream>>>(newe, NENT);
        k_rowdot<1><<<NPAIR / 4, 256, 0, stream>>>(H256b, simW2, simb2, NPAIR, nullptr,
                                                   probs + (t - 1) * NENT, pso, newe);
        k_clampstore<<<40, 256, 0, stream>>>(newe, probs + t * NENT, NENT);
    }

    // 7) hop attention + final mix
    k_mvpart<<<dim3(4, 6, 1), B256, 0, stream>>>(q, 0, hW1, hacc, D, 256, 6);
    k_biasact<<<dim3(1, 1), B256, 0, stream>>>(hacc, hb1, hh, 256, 6, 1);
    k_dot3<<<1, B256, 0, stream>>>(hh, hW2, hb2, hlog);
    k_final<<<40, 256, 0, stream>>>(probs, hlog, (float*)d_out, NENT);
}

// Round 21
// 657.587 us; speedup vs baseline: 2.5587x; 1.0146x over previous
//
#include <hip/hip_runtime.h>
#include <math.h>

// ---------------------------------------------------------------------------
#define D 768
#define NPARA 32
#define LPARA 512
#define LQ 32
#define NENT 10000
#define MMENT 30000
#define NPAIR 20000
#define NSTEP 3
#define NTOK (NPARA * LPARA)   // 16384 unique tokens
#define TSTR 1536              // TLR row stride (Tl cols 0..767, Tr 768..1535)

using bf16x8 = __attribute__((ext_vector_type(8))) short;
using f32x4  = __attribute__((ext_vector_type(4))) float;

__device__ __forceinline__ float geluf(float x) {
    return 0.5f * x * (1.0f + erff(x * 0.70710678118654752f));
}
__device__ __forceinline__ float bf2f(ushort h) {
    union { unsigned u; float f; } v; v.u = ((unsigned)h) << 16; return v.f;
}
// round-to-nearest-even fp32 -> bf16
__device__ __forceinline__ ushort bfrne(float x) {
    union { float f; unsigned u; } v; v.f = x;
    unsigned r = (v.u + 0x7FFF + ((v.u >> 16) & 1)) >> 16;
    return (ushort)r;
}

// ---------------------------------------------------------------------------
// Single-plane bf16 MFMA GEMM. 64x128 tile, A+B LDS (XOR-swizzled), register
// prefetch of next A and B tiles, band-major XCD swizzle.
// R12 KNOWN-GOOD TEMPLATE (VGPR 60, no spill) — body must stay byte-identical.
// R13/R14 (MI=4) and R16 (merged prefetch) all perturbed regalloc -> spill.
// MODE 0: A = bf16 plane [M][K]
// MODE 1: A row r = concat(para[p,t1,:], para[p,t2,:]) fp32 gather (UNUSED now)
// MODE 2: A row r, sections {S, O, S*O} from bf16 feats, K=2304 (folded W1)
// B: pre-transposed bf16 weights WT[N][K]. OUTP 0: fp32 C; 1: bf16 C.
// ---------------------------------------------------------------------------
#define BM 64
#define BN 128

__device__ __forceinline__ int ldso(int row, int kb) {   // ushort index
    return row * 64 + (((kb) ^ ((row & 7) << 4)) >> 1);
}

template <int MODE, int ACT, int OUTP>
__global__ __launch_bounds__(256, 4) void gemm_m(
    const ushort* __restrict__ Ah,
    const float* __restrict__ para, const int* __restrict__ ppos, int c1, int c2,
    const ushort* __restrict__ Sh, const ushort* __restrict__ Oh,
    const ushort* __restrict__ Bh, const float* __restrict__ bias,
    float* __restrict__ Cf, ushort* __restrict__ Ch,
    int M, int N, int K, int nby)
{
    __shared__ ushort sA[BM * 64];   //  8 KB
    __shared__ ushort sB[BN * 64];   // 16 KB

    const int nwg = gridDim.x;
    const int q = nwg >> 3, r = nwg & 7;
    const int xcd = blockIdx.x & 7, idx = blockIdx.x >> 3;
    const int wgid = (xcd < r) ? xcd * (q + 1) + idx
                               : r * (q + 1) + (xcd - r) * q + idx;
    const int m0 = (wgid / nby) * BM;
    const int n0 = (wgid % nby) * BN;

    const int tid = threadIdx.x;
    const int lane = tid & 63;
    const int wv = tid >> 6;
    const int wr = (wv >> 1) * 32;
    const int wc = (wv & 1) * 64;
    const int ln = lane & 15;
    const int kg = lane >> 4;

    f32x4 acc[2][4];
#pragma unroll
    for (int i = 0; i < 2; ++i)
#pragma unroll
        for (int j = 0; j < 4; ++j)
#pragma unroll
            for (int e = 0; e < 4; ++e) acc[i][j][e] = 0.0f;

    const int arow = tid >> 2, aq = tid & 3;   // A: 4 thr/row, 16 ushort each
    const int brow = tid >> 1, bq = tid & 1;   // B: 2 thr/row, 32 ushort each
    const int gm = m0 + arow;
    const bool ok = gm < M;

    int baseL = 0, baseR = 0;
    if (MODE == 1 && ok) {
        int p = ppos[gm * 5];
        baseL = (p * LPARA + ppos[gm * 5 + c1]) * D;
        baseR = (p * LPARA + ppos[gm * 5 + c2]) * D;
    }

    bf16x8 pa[2];     // MODE 0 prefetch
    float4 pf[4];     // MODE 1 prefetch (16 fp32)
    ushort4 ps[8];    // MODE 2 prefetch (S and/or O quads)
    bf16x8 pb[4];     // B prefetch (32 ushorts)

    auto prefA = [&](int kt) {
        if (MODE == 0) {
            if (ok) {
                const ushort* g = Ah + (size_t)gm * K + kt + aq * 16;
                pa[0] = *(const bf16x8*)g;
                pa[1] = *(const bf16x8*)(g + 8);
            } else {
#pragma unroll
                for (int i = 0; i < 2; ++i)
#pragma unroll
                    for (int z = 0; z < 8; ++z) pa[i][z] = 0;
            }
        } else if (MODE == 1) {
            const int kb = kt + aq * 16;            // never crosses D boundary
            const int gb = (kb < D) ? (baseL + kb) : (baseR + kb - D);
#pragma unroll
            for (int j = 0; j < 4; ++j)
                pf[j] = ok ? *(const float4*)(para + gb + j * 4)
                           : make_float4(0.f, 0.f, 0.f, 0.f);
        } else {
            const int sec = kt / D;
            const size_t rb = (size_t)gm * D + (kt - sec * D) + aq * 16;
            if (ok) {
                if (sec == 0) {
#pragma unroll
                    for (int j = 0; j < 4; ++j)
                        ps[j] = *(const ushort4*)(Sh + rb + j * 4);
                } else if (sec == 1) {
#pragma unroll
                    for (int j = 0; j < 4; ++j)
                        ps[j] = *(const ushort4*)(Oh + rb + j * 4);
                } else {
#pragma unroll
                    for (int j = 0; j < 4; ++j) {
                        ps[j]     = *(const ushort4*)(Sh + rb + j * 4);
                        ps[4 + j] = *(const ushort4*)(Oh + rb + j * 4);
                    }
                }
            }
        }
    };

    auto prefB = [&](int kt) {
        const ushort* g = Bh + (size_t)(n0 + brow) * K + kt + bq * 32;
#pragma unroll
        for (int i = 0; i < 4; ++i)
            pb[i] = *(const bf16x8*)(g + i * 8);
    };

    auto storeAB = [&](int kt) {
        if (MODE == 0) {
            int o0 = ldso(arow, aq * 32), o1 = ldso(arow, aq * 32 + 16);
            *(bf16x8*)&sA[o0] = pa[0];
            *(bf16x8*)&sA[o1] = pa[1];
        } else if (MODE == 1) {
#pragma unroll
            for (int j = 0; j < 4; ++j) {
                ushort4 h;
                h.x = bfrne(pf[j].x); h.y = bfrne(pf[j].y);
                h.z = bfrne(pf[j].z); h.w = bfrne(pf[j].w);
                *(ushort4*)&sA[ldso(arow, aq * 32 + j * 8)] = h;
            }
        } else {
            const int sec = kt / D;
#pragma unroll
            for (int j = 0; j < 4; ++j) {
                ushort4 h;
                if (ok) {
                    if (sec < 2) {
                        h = ps[j];
                    } else {
                        h.x = bfrne(bf2f(ps[j].x) * bf2f(ps[4 + j].x));
                        h.y = bfrne(bf2f(ps[j].y) * bf2f(ps[4 + j].y));
                        h.z = bfrne(bf2f(ps[j].z) * bf2f(ps[4 + j].z));
                        h.w = bfrne(bf2f(ps[j].w) * bf2f(ps[4 + j].w));
                    }
                } else {
                    h.x = h.y = h.z = h.w = 0;
                }
                *(ushort4*)&sA[ldso(arow, aq * 32 + j * 8)] = h;
            }
        }
#pragma unroll
        for (int i = 0; i < 4; ++i)
            *(bf16x8*)&sB[ldso(brow, bq * 64 + i * 16)] = pb[i];
    };

    prefA(0);
    prefB(0);

    for (int kt = 0; kt < K; kt += 64) {
        if (kt > 0) __syncthreads();
        storeAB(kt);
        __syncthreads();

        const int ktn = kt + 64;
        if (ktn < K) { prefA(ktn); prefB(ktn); }

#pragma unroll
        for (int ks = 0; ks < 2; ++ks) {
            bf16x8 fb[4];
#pragma unroll
            for (int ni = 0; ni < 4; ++ni)
                fb[ni] = *(const bf16x8*)&sB[ldso(wc + ni * 16 + ln, ks * 64 + kg * 16)];
#pragma unroll
            for (int mi = 0; mi < 2; ++mi) {
                bf16x8 fa = *(const bf16x8*)&sA[ldso(wr + mi * 16 + ln, ks * 64 + kg * 16)];
#pragma unroll
                for (int ni = 0; ni < 4; ++ni)
                    acc[mi][ni] = __builtin_amdgcn_mfma_f32_16x16x32_bf16(
                        fa, fb[ni], acc[mi][ni], 0, 0, 0);
            }
        }
    }

    // epilogue: row = (lane>>4)*4+reg, col = lane&15
#pragma unroll
    for (int mi = 0; mi < 2; ++mi)
#pragma unroll
        for (int ni = 0; ni < 4; ++ni) {
            int col = n0 + wc + ni * 16 + ln;
            f32x4 a = acc[mi][ni];
#pragma unroll
            for (int j = 0; j < 4; ++j) {
                int row = m0 + wr + mi * 16 + kg * 4 + j;
                if (row < M) {
                    float v = a[j] + bias[col];
                    if (ACT == 1) v = geluf(v);
                    if (OUTP == 0) Cf[(size_t)row * N + col] = v;
                    else           Ch[(size_t)row * N + col] = bfrne(v);
                }
            }
        }
}

// ---------------------------------------------------------------------------
// Weight transpose: W[K][N] fp32 -> WT[N][K] bf16 (RNE)
__global__ __launch_bounds__(256) void k_wt(const float* __restrict__ W,
                                            ushort* __restrict__ WTh, int K, int N)
{
    __shared__ float t[32][33];
    const int k0 = blockIdx.x * 32, n0 = blockIdx.y * 32;
    const int c = threadIdx.x & 31, r8 = threadIdx.x >> 5;
#pragma unroll
    for (int i = 0; i < 4; ++i) {
        int r = r8 + i * 8;
        t[r][c] = W[(size_t)(k0 + r) * N + n0 + c];
    }
    __syncthreads();
#pragma unroll
    for (int i = 0; i < 4; ++i) {
        int r = r8 + i * 8;
        WTh[(size_t)(n0 + r) * K + k0 + c] = bfrne(t[c][r]);
    }
}

// folded pair W1: Wf[2304][768] from pW1[3072][768]
__global__ void k_fold(const float* __restrict__ pW1, float* __restrict__ Wf, int n)
{
    int i = blockIdx.x * blockDim.x + threadIdx.x;
    if (i >= n) return;
    int row = i / D;
    float v;
    if (row < D)            v = pW1[i] - pW1[i + 1536 * D];
    else if (row < 2 * D)   v = pW1[i] + pW1[i + 768 * D];
    else                    v = pW1[i + 768 * D];
    Wf[i] = v;
}

// para fp32 -> bf16 plane (vectorized x4)
__global__ void k_cvt(const float* __restrict__ src, ushort* __restrict__ dst, int n4)
{
    int i = blockIdx.x * blockDim.x + threadIdx.x;
    if (i >= n4) return;
    float4 v = ((const float4*)src)[i];
    ushort4 h;
    h.x = bfrne(v.x); h.y = bfrne(v.y); h.z = bfrne(v.z); h.w = bfrne(v.w);
    ((ushort4*)dst)[i] = h;
}

// dst[i] = src[i % period]
__global__ void k_dup(const float* __restrict__ src, float* __restrict__ dst,
                      int n, int period)
{
    int i = blockIdx.x * blockDim.x + threadIdx.x;
    if (i < n) dst[i] = src[i % period];
}

// hid[r,:] = gelu(TLR[tok(c1)][0:768] + TLR[tok(c2)][768:1536] + b)
__global__ __launch_bounds__(256) void k_addgelu(
    const ushort* __restrict__ T,
    const int* __restrict__ ppos, int c1, int c2,
    const float* __restrict__ b, ushort* __restrict__ out)
{
    const int rr = blockIdx.x;
    const int p = ppos[rr * 5];
    const size_t bl = (size_t)(p * LPARA + ppos[rr * 5 + c1]) * TSTR;
    const size_t br = (size_t)(p * LPARA + ppos[rr * 5 + c2]) * TSTR + D;
    const int tid = threadIdx.x;
#pragma unroll
    for (int i = 0; i < 3; ++i) {
        int d = tid + i * 256;
        float v = bf2f(T[bl + d]) + bf2f(T[br + d]) + b[d];
        out[(size_t)rr * D + d] = bfrne(geluf(v));
    }
}

// entity hidden via token embeddings: gelu(mean(Tl[tokL]+Tr[tokR]) + b)
__global__ __launch_bounds__(256) void k_entmean_t(
    const ushort* __restrict__ T,
    const int* __restrict__ mpos, const int* __restrict__ mid, int M,
    const float* __restrict__ b, ushort* __restrict__ oh)
{
    __shared__ int sb[2];
    const int e = blockIdx.x;
    if (threadIdx.x < 2) {
        int target = e + threadIdx.x;
        int lo = 0, hi = M;
        while (lo < hi) {
            int md = (lo + hi) >> 1;
            if (mid[md] < target) lo = md + 1; else hi = md;
        }
        sb[threadIdx.x] = lo;
    }
    __syncthreads();
    const int lo = sb[0], hi = sb[1];
    const int tid = threadIdx.x;
    float s0 = 0, s1 = 0, s2 = 0;
    for (int m = lo; m < hi; ++m) {
        int p = mpos[m * 3], t1 = mpos[m * 3 + 1], t2 = mpos[m * 3 + 2];
        const ushort* L = T + (size_t)(p * LPARA + t1) * TSTR;
        const ushort* R = T + (size_t)(p * LPARA + t2) * TSTR + D;
        s0 += bf2f(L[tid])       + bf2f(R[tid]);
        s1 += bf2f(L[tid + 256]) + bf2f(R[tid + 256]);
        s2 += bf2f(L[tid + 512]) + bf2f(R[tid + 512]);
    }
    const float inv = (hi > lo) ? 1.0f / (float)(hi - lo) : 0.0f;
    size_t base = (size_t)e * D;
    oh[base + tid]       = bfrne(geluf(s0 * inv + b[tid]));
    oh[base + tid + 256] = bfrne(geluf(s1 * inv + b[tid + 256]));
    oh[base + tid + 512] = bfrne(geluf(s2 * inv + b[tid + 512]));
}

// ---------------------------------------------------------------------------
// Batched split-K matvec (deterministic). grid (N/64, nks, T).
__global__ __launch_bounds__(256) void k_mvpart(
    const float* __restrict__ x, int xstride,
    const float* __restrict__ W, float* __restrict__ acc, int K, int N, int nks)
{
    const int t = blockIdx.z;
    const float* xt = x + (size_t)t * xstride;
    const float* Wt = W + (size_t)t * K * N;
    const int jj = threadIdx.x & 63;
    const int kq = threadIdx.x >> 6;
    const int j = blockIdx.x * 64 + jj;
    const int kchunk = K / (nks * 4);
    const int kbeg = (blockIdx.y * 4 + kq) * kchunk;
    float s = 0.0f;
    for (int k = kbeg; k < kbeg + kchunk; ++k)
        s = fmaf(xt[k], Wt[(size_t)k * N + j], s);
    __shared__ float red[256];
    red[threadIdx.x] = s;
    __syncthreads();
    if (kq == 0) {
        float v = red[jj] + red[64 + jj] + red[128 + jj] + red[192 + jj];
        acc[((size_t)(t * nks) + blockIdx.y) * N + j] = v;
    }
}

__global__ void k_biasact(const float* __restrict__ acc, const float* __restrict__ b,
                          float* __restrict__ out, int N, int nks, int act)
{
    const int t = blockIdx.y;
    const int j = blockIdx.x * 256 + threadIdx.x;
    if (j >= N) return;
    float s = 0.0f;
    for (int i = 0; i < nks; ++i) s += acc[((size_t)(t * nks) + i) * N + j];
    s += b[(size_t)t * N + j];
    if (act) s = geluf(s);
    out[(size_t)t * N + j] = s;
}

__global__ void k_dot3(const float* __restrict__ x, const float* __restrict__ W,
                       const float* __restrict__ b, float* __restrict__ out)
{
    int j = threadIdx.x >> 6, lane = threadIdx.x & 63;
    if (j >= 3) return;
    float s = 0.0f;
#pragma unroll
    for (int i = 0; i < 4; ++i) {
        int k = lane + i * 64;
        s += x[k] * W[k * 3 + j];
    }
    for (int off = 32; off > 0; off >>= 1) s += __shfl_down(s, off, 64);
    if (lane == 0) out[j] = s + b[j];
}

__global__ void k_ctx3(const float* __restrict__ cq3, const float* __restrict__ qwh,
                       float* __restrict__ ctx3)
{
    const float* cq = cq3 + (size_t)blockIdx.x * D;
    float* ctx = ctx3 + (size_t)blockIdx.x * D;
    __shared__ float red[256];
    __shared__ float dist[LQ];
    const int tid = threadIdx.x;
    const int l = tid >> 3, part = tid & 7;
    float s = 0.0f;
    for (int d = part; d < D; d += 8) s += cq[d] * qwh[l * D + d];
    red[tid] = s;
    __syncthreads();
    if (part == 0) {
        float v = 0;
        for (int i = 0; i < 8; ++i) v += red[l * 8 + i];
        dist[l] = v;
    }
    __syncthreads();
    if (tid == 0) {
        float mx = -1e30f;
        for (int i = 0; i < LQ; ++i) mx = fmaxf(mx, dist[i]);
        float sm = 0;
        for (int i = 0; i < LQ; ++i) { float e = expf(dist[i] - mx); dist[i] = e; sm += e; }
        float inv = 1.0f / sm;
        for (int i = 0; i < LQ; ++i) dist[i] *= inv;
    }
    __syncthreads();
    for (int d = tid; d < D; d += 256) {
        float v = 0;
#pragma unroll
        for (int l2 = 0; l2 < LQ; ++l2) v += dist[l2] * qwh[l2 * D + d];
        ctx[d] = v + cq[d];
    }
}

__global__ void k_scalew(const float* __restrict__ ctx, const float* __restrict__ w1,
                         float* __restrict__ o, int n)
{
    int i = blockIdx.x * 256 + threadIdx.x;
    if (i < n) o[i] = ctx[i >> 8] * w1[i];
}

// sim rowdot; hstr = row stride of H in floats
template <int PAIRMODE>
__global__ void k_rowdot(const float* __restrict__ H, int hstr,
                         const float* __restrict__ w2,
                         const float* __restrict__ sb2, int Nr,
                         float* __restrict__ simout,
                         const float* __restrict__ laste, const int* __restrict__ so,
                         float* __restrict__ newe)
{
    int r = blockIdx.x * 4 + (threadIdx.x >> 6);
    int lane = threadIdx.x & 63;
    if (r >= Nr) return;
    float s = 0.0f;
#pragma unroll
    for (int i = 0; i < 4; ++i)
        s += H[(size_t)r * hstr + lane + i * 64] * w2[lane + i * 64];
    for (int off = 32; off > 0; off >>= 1) s += __shfl_down(s, off, 64);
    if (lane == 0) {
        s += sb2[0];
        if (PAIRMODE == 0) {
            simout[r] = s;
        } else {
            float p = 1.0f / (1.0f + expf(-s));
            float v = laste[so[r * 2]] * p;
            atomicAdd(&newe[so[r * 2 + 1]], v);
        }
    }
}

__global__ void k_softmax(const float* __restrict__ sim, float* __restrict__ outp, int n)
{
    __shared__ float red[256];
    __shared__ float s_mx, s_sum;
    const int tid = threadIdx.x;
    float mx = -1e30f;
    for (int i = tid; i < n; i += 256) mx = fmaxf(mx, sim[i]);
    red[tid] = mx; __syncthreads();
    for (int off = 128; off > 0; off >>= 1) {
        if (tid < off) red[tid] = fmaxf(red[tid], red[tid + off]);
        __syncthreads();
    }
    if (tid == 0) s_mx = red[0];
    __syncthreads();
    const float mxv = s_mx;
    float sum = 0;
    for (int i = tid; i < n; i += 256) sum += expf(sim[i] - mxv);
    red[tid] = sum; __syncthreads();
    for (int off = 128; off > 0; off >>= 1) {
        if (tid < off) red[tid] += red[tid + off];
        __syncthreads();
    }
    if (tid == 0) s_sum = red[0];
    __syncthreads();
    const float inv = 1.0f / s_sum;
    for (int i = tid; i < n; i += 256) {
        float v = expf(sim[i] - mxv) * inv;
        outp[i] = v / fmaxf(v, 1.0f);
    }
}

__global__ void k_zero(float* p, int n)
{
    int i = blockIdx.x * blockDim.x + threadIdx.x;
    if (i < n) p[i] = 0.0f;
}

__global__ void k_clampstore(const float* __restrict__ ne, float* __restrict__ outp, int n)
{
    int i = blockIdx.x * blockDim.x + threadIdx.x;
    if (i < n) { float v = ne[i]; outp[i] = v / fmaxf(v, 1.0f); }
}

__global__ void k_final(const float* __restrict__ probs, const float* __restrict__ hlog,
                        float* __restrict__ out, int n)
{
    int i = blockIdx.x * blockDim.x + threadIdx.x;
    if (i >= n) return;
    float l0 = hlog[0], l1 = hlog[1], l2 = hlog[2];
    float m = fmaxf(l0, fmaxf(l1, l2));
    float e0 = expf(l0 - m), e1 = expf(l1 - m), e2 = expf(l2 - m);
    float inv = 1.0f / (e0 + e1 + e2);
    out[i] = (e0 * probs[i] + e1 * probs[n + i] + e2 * probs[2 * n + i]) * inv;
}

// ---------------------------------------------------------------------------
extern "C" void kernel_launch(void* const* d_in, const int* in_sizes, int n_in,
                              void* d_out, int out_size, void* d_ws, size_t ws_size,
                              hipStream_t stream)
{
    const size_t WS_NEED = 148015504;  // 141.2 MiB (proven capacity 148.8 MB)
    if (ws_size < WS_NEED) return;

    const float* para  = (const float*)d_in[0];
    const float* q     = (const float*)d_in[1];
    const float* qwh   = (const float*)d_in[2];
    const float* stW1  = (const float*)d_in[3];
    const float* stb1  = (const float*)d_in[4];
    const float* stW2  = (const float*)d_in[5];
    const float* stb2  = (const float*)d_in[6];
    const float* mW1   = (const float*)d_in[7];
    const float* mb1   = (const float*)d_in[8];
    const float* mW2   = (const float*)d_in[9];
    const float* mb2   = (const float*)d_in[10];
    const float* pW1   = (const float*)d_in[11];
    const float* pb1   = (const float*)d_in[12];
    const float* pW2   = (const float*)d_in[13];
    const float* pb2   = (const float*)d_in[14];
    const float* simW1 = (const float*)d_in[15];
    const float* simb1 = (const float*)d_in[16];
    const float* simW2 = (const float*)d_in[17];
    const float* simb2 = (const float*)d_in[18];
    const float* hW1   = (const float*)d_in[19];
    const float* hb1   = (const float*)d_in[20];
    const float* hW2   = (const float*)d_in[21];
    const float* hb2   = (const float*)d_in[22];
    const int*   mpos  = (const int*)d_in[23];
    const int*   mid   = (const int*)d_in[24];
    const int*   ppos  = (const int*)d_in[25];
    const int*   pso   = (const int*)d_in[26];

    // ---- workspace: regions + weights + fp32 tail ----
    ushort* ws16 = (ushort*)d_ws;
    ushort* R1 = ws16;                     // 15,360,000: PB16 -> subhid -> pairh
    ushort* R2 = R1 + 15360000;            // 15,360,000: Wfold -> objhid -> pairE
    ushort* R3 = R2 + 15360000;            // 15,360,000: TLR[0:15.36M) -> subf -> H256c lo
    ushort* R4 = R3 + 15360000;            // 15,360,000: TLR[tail] -> E+H256a -> objf -> H256c hi
    ushort* R5 = R4 + 15360000;            //  7,680,000: W1s tmp -> enthid
    ushort* WlrT  = R5 + 7680000;          //  1,179,648 ([1536][768]: Wl 0-767, Wr 768-1535)
    ushort* mW2T  = WlrT + 1179648;        //    589,824
    ushort* WfT   = mW2T + 589824;         //  1,769,472
    ushort* pW2T  = WfT + 1769472;         //    589,824
    ushort* W1sT0 = pW2T + 589824;         //    589,824 (3 x 196,608)
    float*  tail  = (float*)(W1sT0 + 589824);
    float*  simb  = tail;                  // 20,000
    float*  probs = simb + 20000;          // 30,000
    float*  newe  = probs + 30000;         // 10,000
    float*  acc3  = newe + 10000;          // 13,824
    float*  h3    = acc3 + 13824;          // 2,304
    float*  cq3   = h3   + 2304;           // 2,304
    float*  ctx3  = cq3  + 2304;           // 2,304
    float*  hacc  = ctx3 + 2304;           // 1,536
    float*  hh    = hacc + 1536;           // 256
    float*  hlog  = hh   + 256;            // 4
    float*  zb    = hlog + 4;              // 1,536 (zero bias)
    float*  sb1d  = zb   + 1536;           //   512 (duplicated simb1)

    // phase overlays (liveness audited):
    float*  Wfold  = (float*)R2;           // fp32 tmp, dead after k_wt(WfT)
    float*  W1s    = (float*)R5;           // fp32 tmp, dead before enthid written
    ushort* PB16   = R1;                   // [16384][768], dead after TLR GEMM
    ushort* TLR    = R3;                   // [16384][1536] = 25.17M, spans R3 + 9.81M of R4
    ushort* enthid = R5;                   // [10000][768] (after W1s dead)
    ushort* subhid = R1;                   // [20000][768] (after PB16 dead)
    ushort* objhid = R2;                   // [20000][768] (after Wfold dead) — contiguous w/ subhid
    ushort* E      = R4;                   // [10000][768] = 7.68M (TLR dead by then)
    float*  H256a  = (float*)(R4 + 7680000); // [10000][256] fp32 = 5.12M ushorts (in R4)
    ushort* subf   = R3;                   // [20000][768] (TLR + H256a/E dead)
    ushort* objf   = R4;                   // contiguous output of fused pair-feat GEMM
    ushort* pairh  = R1;                   // (subhid dead)
    ushort* pairE  = R2;                   // (objhid dead)
    float*  H256c  = (float*)R3;           // [20000][512] fp32 = 20.48M ushorts (subf/objf dead)

    dim3 B256(256);
    const ushort* np = nullptr;

    // 0) weight prep (Wfold in R2, consumed before objhid)
    k_fold<<<(2304 * D + 255) / 256, B256, 0, stream>>>(pW1, Wfold, 2304 * D);
    k_wt<<<dim3(24, 24), B256, 0, stream>>>(mW1, WlrT, D, D);                       // Wl
    k_wt<<<dim3(24, 24), B256, 0, stream>>>(mW1 + (size_t)D * D, WlrT + (size_t)D * D, D, D); // Wr
    k_wt<<<dim3(24, 24), B256, 0, stream>>>(mW2, mW2T, D, D);
    k_wt<<<dim3(72, 24), B256, 0, stream>>>(Wfold, WfT, 3 * D, D);
    k_wt<<<dim3(24, 24), B256, 0, stream>>>(pW2, pW2T, D, D);
    k_zero<<<6, B256, 0, stream>>>(zb, TSTR);
    k_dup<<<2, B256, 0, stream>>>(simb1, sb1d, 512, 256);

    // 1) batched step MLPs + ctx + scaled sim weights (W1s tmp in R5)
    k_mvpart<<<dim3(12, 6, 3), B256, 0, stream>>>(q, 0, stW1, acc3, D, D, 6);
    k_biasact<<<dim3(3, 3), B256, 0, stream>>>(acc3, stb1, h3, D, 6, 1);
    k_mvpart<<<dim3(12, 6, 3), B256, 0, stream>>>(h3, D, stW2, acc3, D, D, 6);
    k_biasact<<<dim3(3, 3), B256, 0, stream>>>(acc3, stb2, cq3, D, 6, 0);
    k_ctx3<<<3, B256, 0, stream>>>(cq3, qwh, ctx3);
    for (int t = 0; t < NSTEP; ++t) {
        k_scalew<<<768, 256, 0, stream>>>(ctx3 + (size_t)t * D, simW1, W1s, D * 256);
        k_wt<<<dim3(24, 8), B256, 0, stream>>>(W1s, W1sT0 + t * 196608, D, 256);
    }

    // 2) fused token embeddings: TLR = PB16 @ [Wl|Wr]  (M=16384, N=1536)
    k_cvt<<<(NTOK * D / 4 + 255) / 256, B256, 0, stream>>>(para, PB16, NTOK * D / 4);
    gemm_m<0, 0, 1><<<3072, B256, 0, stream>>>(PB16, nullptr, nullptr, 0, 0, np, np,
        WlrT, zb, nullptr, TLR, NTOK, TSTR, D, 12);

    // 3) hiddens via gather-add-gelu
    k_entmean_t<<<NENT, 256, 0, stream>>>(TLR, mpos, mid, MMENT, mb1, enthid);
    k_addgelu<<<NPAIR, 256, 0, stream>>>(TLR, ppos, 1, 2, mb1, subhid);
    k_addgelu<<<NPAIR, 256, 0, stream>>>(TLR, ppos, 3, 4, mb1, objhid);

    // 4) ent_emb + step 0 sim -> probs[0]
    gemm_m<0, 0, 1><<<942, B256, 0, stream>>>(enthid, nullptr, nullptr, 0, 0, np, np,
        mW2T, mb2, nullptr, E, NENT, D, D, 6);
    gemm_m<0, 1, 0><<<314, B256, 0, stream>>>(E, nullptr, nullptr, 0, 0, np, np,
        W1sT0, simb1, H256a, nullptr, NENT, 256, D, 2);
    k_rowdot<0><<<NENT / 4, 256, 0, stream>>>(H256a, 256, simW2, simb2, NENT, simb,
                                              nullptr, nullptr, nullptr);
    k_softmax<<<1, 256, 0, stream>>>(simb, probs, NENT);

    // 5) FUSED pair features: [subhid;objhid] (M=40000) @ mW2T -> [subf;objf]
    gemm_m<0, 0, 1><<<3750, B256, 0, stream>>>(subhid, nullptr, nullptr, 0, 0, np, np,
        mW2T, mb2, nullptr, subf, 2 * NPAIR, D, D, 6);
    gemm_m<2, 1, 1><<<1878, B256, 0, stream>>>(np, nullptr, nullptr, 0, 0, subf, objf,
        WfT, pb1, nullptr, pairh, NPAIR, D, 3 * D, 6);
    gemm_m<0, 0, 1><<<1878, B256, 0, stream>>>(pairh, nullptr, nullptr, 0, 0, np, np,
        pW2T, pb2, nullptr, pairE, NPAIR, D, D, 6);

    // 6) FUSED sims for steps 1,2: pairE @ [W1sT1|W1sT2] (N=512) -> H256c
    gemm_m<0, 1, 0><<<1252, B256, 0, stream>>>(pairE, nullptr, nullptr, 0, 0, np, np,
        W1sT0 + 196608, sb1d, H256c, nullptr, NPAIR, 512, D, 4);
    for (int t = 1; t < NSTEP; ++t) {
        k_zero<<<40, 256, 0, stream>>>(newe, NENT);
        k_rowdot<1><<<NPAIR / 4, 256, 0, stream>>>(H256c + (t - 1) * 256, 512,
                                                   simW2, simb2, NPAIR, nullptr,
                                                   probs + (t - 1) * NENT, pso, newe);
        k_clampstore<<<40, 256, 0, stream>>>(newe, probs + t * NENT, NENT);
    }

    // 7) hop attention + final mix
    k_mvpart<<<dim3(4, 6, 1), B256, 0, stream>>>(q, 0, hW1, hacc, D, 256, 6);
    k_biasact<<<dim3(1, 1), B256, 0, stream>>>(hacc, hb1, hh, 256, 6, 1);
    k_dot3<<<1, B256, 0, stream>>>(hh, hW2, hb2, hlog);
    k_final<<<40, 256, 0, stream>>>(probs, hlog, (float*)d_out, NENT);
}

// Round 22
// 628.648 us; speedup vs baseline: 2.6765x; 1.0460x over previous
//
#include <hip/hip_runtime.h>
#include <math.h>

// ---------------------------------------------------------------------------
#define D 768
#define NPARA 32
#define LPARA 512
#define LQ 32
#define NENT 10000
#define MMENT 30000
#define NPAIR 20000
#define NSTEP 3
#define NTOK (NPARA * LPARA)   // 16384 unique tokens
#define TSTR 1536              // TLR row stride (Tl cols 0..767, Tr 768..1535)

using bf16x8 = __attribute__((ext_vector_type(8))) short;
using f32x4  = __attribute__((ext_vector_type(4))) float;

__device__ __forceinline__ float geluf(float x) {
    return 0.5f * x * (1.0f + erff(x * 0.70710678118654752f));
}
__device__ __forceinline__ float bf2f(ushort h) {
    union { unsigned u; float f; } v; v.u = ((unsigned)h) << 16; return v.f;
}
// round-to-nearest-even fp32 -> bf16
__device__ __forceinline__ ushort bfrne(float x) {
    union { float f; unsigned u; } v; v.f = x;
    unsigned r = (v.u + 0x7FFF + ((v.u >> 16) & 1)) >> 16;
    return (ushort)r;
}

// ---------------------------------------------------------------------------
// Single-plane bf16 MFMA GEMM. 64x128 tile, A+B LDS (XOR-swizzled), register
// prefetch of next A and B tiles, band-major XCD swizzle.
// R12 KNOWN-GOOD TEMPLATE (VGPR 60, no spill) — body must stay byte-identical.
// R13/R14 (MI=4) and R16 (merged prefetch) all perturbed regalloc -> spill.
// MODE 0: A = bf16 plane [M][K]
// MODE 1: A row r = concat(para[p,t1,:], para[p,t2,:]) fp32 gather (UNUSED now)
// MODE 2: A row r, sections {S, O, S*O} from bf16 feats, K=2304 (folded W1)
// B: pre-transposed bf16 weights WT[N][K]. OUTP 0: fp32 C; 1: bf16 C.
// ---------------------------------------------------------------------------
#define BM 64
#define BN 128

__device__ __forceinline__ int ldso(int row, int kb) {   // ushort index
    return row * 64 + (((kb) ^ ((row & 7) << 4)) >> 1);
}

template <int MODE, int ACT, int OUTP>
__global__ __launch_bounds__(256, 4) void gemm_m(
    const ushort* __restrict__ Ah,
    const float* __restrict__ para, const int* __restrict__ ppos, int c1, int c2,
    const ushort* __restrict__ Sh, const ushort* __restrict__ Oh,
    const ushort* __restrict__ Bh, const float* __restrict__ bias,
    float* __restrict__ Cf, ushort* __restrict__ Ch,
    int M, int N, int K, int nby)
{
    __shared__ ushort sA[BM * 64];   //  8 KB
    __shared__ ushort sB[BN * 64];   // 16 KB

    const int nwg = gridDim.x;
    const int q = nwg >> 3, r = nwg & 7;
    const int xcd = blockIdx.x & 7, idx = blockIdx.x >> 3;
    const int wgid = (xcd < r) ? xcd * (q + 1) + idx
                               : r * (q + 1) + (xcd - r) * q + idx;
    const int m0 = (wgid / nby) * BM;
    const int n0 = (wgid % nby) * BN;

    const int tid = threadIdx.x;
    const int lane = tid & 63;
    const int wv = tid >> 6;
    const int wr = (wv >> 1) * 32;
    const int wc = (wv & 1) * 64;
    const int ln = lane & 15;
    const int kg = lane >> 4;

    f32x4 acc[2][4];
#pragma unroll
    for (int i = 0; i < 2; ++i)
#pragma unroll
        for (int j = 0; j < 4; ++j)
#pragma unroll
            for (int e = 0; e < 4; ++e) acc[i][j][e] = 0.0f;

    const int arow = tid >> 2, aq = tid & 3;   // A: 4 thr/row, 16 ushort each
    const int brow = tid >> 1, bq = tid & 1;   // B: 2 thr/row, 32 ushort each
    const int gm = m0 + arow;
    const bool ok = gm < M;

    int baseL = 0, baseR = 0;
    if (MODE == 1 && ok) {
        int p = ppos[gm * 5];
        baseL = (p * LPARA + ppos[gm * 5 + c1]) * D;
        baseR = (p * LPARA + ppos[gm * 5 + c2]) * D;
    }

    bf16x8 pa[2];     // MODE 0 prefetch
    float4 pf[4];     // MODE 1 prefetch (16 fp32)
    ushort4 ps[8];    // MODE 2 prefetch (S and/or O quads)
    bf16x8 pb[4];     // B prefetch (32 ushorts)

    auto prefA = [&](int kt) {
        if (MODE == 0) {
            if (ok) {
                const ushort* g = Ah + (size_t)gm * K + kt + aq * 16;
                pa[0] = *(const bf16x8*)g;
                pa[1] = *(const bf16x8*)(g + 8);
            } else {
#pragma unroll
                for (int i = 0; i < 2; ++i)
#pragma unroll
                    for (int z = 0; z < 8; ++z) pa[i][z] = 0;
            }
        } else if (MODE == 1) {
            const int kb = kt + aq * 16;            // never crosses D boundary
            const int gb = (kb < D) ? (baseL + kb) : (baseR + kb - D);
#pragma unroll
            for (int j = 0; j < 4; ++j)
                pf[j] = ok ? *(const float4*)(para + gb + j * 4)
                           : make_float4(0.f, 0.f, 0.f, 0.f);
        } else {
            const int sec = kt / D;
            const size_t rb = (size_t)gm * D + (kt - sec * D) + aq * 16;
            if (ok) {
                if (sec == 0) {
#pragma unroll
                    for (int j = 0; j < 4; ++j)
                        ps[j] = *(const ushort4*)(Sh + rb + j * 4);
                } else if (sec == 1) {
#pragma unroll
                    for (int j = 0; j < 4; ++j)
                        ps[j] = *(const ushort4*)(Oh + rb + j * 4);
                } else {
#pragma unroll
                    for (int j = 0; j < 4; ++j) {
                        ps[j]     = *(const ushort4*)(Sh + rb + j * 4);
                        ps[4 + j] = *(const ushort4*)(Oh + rb + j * 4);
                    }
                }
            }
        }
    };

    auto prefB = [&](int kt) {
        const ushort* g = Bh + (size_t)(n0 + brow) * K + kt + bq * 32;
#pragma unroll
        for (int i = 0; i < 4; ++i)
            pb[i] = *(const bf16x8*)(g + i * 8);
    };

    auto storeAB = [&](int kt) {
        if (MODE == 0) {
            int o0 = ldso(arow, aq * 32), o1 = ldso(arow, aq * 32 + 16);
            *(bf16x8*)&sA[o0] = pa[0];
            *(bf16x8*)&sA[o1] = pa[1];
        } else if (MODE == 1) {
#pragma unroll
            for (int j = 0; j < 4; ++j) {
                ushort4 h;
                h.x = bfrne(pf[j].x); h.y = bfrne(pf[j].y);
                h.z = bfrne(pf[j].z); h.w = bfrne(pf[j].w);
                *(ushort4*)&sA[ldso(arow, aq * 32 + j * 8)] = h;
            }
        } else {
            const int sec = kt / D;
#pragma unroll
            for (int j = 0; j < 4; ++j) {
                ushort4 h;
                if (ok) {
                    if (sec < 2) {
                        h = ps[j];
                    } else {
                        h.x = bfrne(bf2f(ps[j].x) * bf2f(ps[4 + j].x));
                        h.y = bfrne(bf2f(ps[j].y) * bf2f(ps[4 + j].y));
                        h.z = bfrne(bf2f(ps[j].z) * bf2f(ps[4 + j].z));
                        h.w = bfrne(bf2f(ps[j].w) * bf2f(ps[4 + j].w));
                    }
                } else {
                    h.x = h.y = h.z = h.w = 0;
                }
                *(ushort4*)&sA[ldso(arow, aq * 32 + j * 8)] = h;
            }
        }
#pragma unroll
        for (int i = 0; i < 4; ++i)
            *(bf16x8*)&sB[ldso(brow, bq * 64 + i * 16)] = pb[i];
    };

    prefA(0);
    prefB(0);

    for (int kt = 0; kt < K; kt += 64) {
        if (kt > 0) __syncthreads();
        storeAB(kt);
        __syncthreads();

        const int ktn = kt + 64;
        if (ktn < K) { prefA(ktn); prefB(ktn); }

#pragma unroll
        for (int ks = 0; ks < 2; ++ks) {
            bf16x8 fb[4];
#pragma unroll
            for (int ni = 0; ni < 4; ++ni)
                fb[ni] = *(const bf16x8*)&sB[ldso(wc + ni * 16 + ln, ks * 64 + kg * 16)];
#pragma unroll
            for (int mi = 0; mi < 2; ++mi) {
                bf16x8 fa = *(const bf16x8*)&sA[ldso(wr + mi * 16 + ln, ks * 64 + kg * 16)];
#pragma unroll
                for (int ni = 0; ni < 4; ++ni)
                    acc[mi][ni] = __builtin_amdgcn_mfma_f32_16x16x32_bf16(
                        fa, fb[ni], acc[mi][ni], 0, 0, 0);
            }
        }
    }

    // epilogue: row = (lane>>4)*4+reg, col = lane&15
#pragma unroll
    for (int mi = 0; mi < 2; ++mi)
#pragma unroll
        for (int ni = 0; ni < 4; ++ni) {
            int col = n0 + wc + ni * 16 + ln;
            f32x4 a = acc[mi][ni];
#pragma unroll
            for (int j = 0; j < 4; ++j) {
                int row = m0 + wr + mi * 16 + kg * 4 + j;
                if (row < M) {
                    float v = a[j] + bias[col];
                    if (ACT == 1) v = geluf(v);
                    if (OUTP == 0) Cf[(size_t)row * N + col] = v;
                    else           Ch[(size_t)row * N + col] = bfrne(v);
                }
            }
        }
}

// ---------------------------------------------------------------------------
// Weight transpose: W[K][N] fp32 -> WT[N][K] bf16 (RNE)
__global__ __launch_bounds__(256) void k_wt(const float* __restrict__ W,
                                            ushort* __restrict__ WTh, int K, int N)
{
    __shared__ float t[32][33];
    const int k0 = blockIdx.x * 32, n0 = blockIdx.y * 32;
    const int c = threadIdx.x & 31, r8 = threadIdx.x >> 5;
#pragma unroll
    for (int i = 0; i < 4; ++i) {
        int r = r8 + i * 8;
        t[r][c] = W[(size_t)(k0 + r) * N + n0 + c];
    }
    __syncthreads();
#pragma unroll
    for (int i = 0; i < 4; ++i) {
        int r = r8 + i * 8;
        WTh[(size_t)(n0 + r) * K + k0 + c] = bfrne(t[c][r]);
    }
}

// folded pair W1: Wf[2304][768] from pW1[3072][768]
__global__ void k_fold(const float* __restrict__ pW1, float* __restrict__ Wf, int n)
{
    int i = blockIdx.x * blockDim.x + threadIdx.x;
    if (i >= n) return;
    int row = i / D;
    float v;
    if (row < D)            v = pW1[i] - pW1[i + 1536 * D];
    else if (row < 2 * D)   v = pW1[i] + pW1[i + 768 * D];
    else                    v = pW1[i + 768 * D];
    Wf[i] = v;
}

// para fp32 -> bf16 plane (vectorized x4)
__global__ void k_cvt(const float* __restrict__ src, ushort* __restrict__ dst, int n4)
{
    int i = blockIdx.x * blockDim.x + threadIdx.x;
    if (i >= n4) return;
    float4 v = ((const float4*)src)[i];
    ushort4 h;
    h.x = bfrne(v.x); h.y = bfrne(v.y); h.z = bfrne(v.z); h.w = bfrne(v.w);
    ((ushort4*)dst)[i] = h;
}

// dst[i] = src[i % period]
__global__ void k_dup(const float* __restrict__ src, float* __restrict__ dst,
                      int n, int period)
{
    int i = blockIdx.x * blockDim.x + threadIdx.x;
    if (i < n) dst[i] = src[i % period];
}

// hid[r,:] = gelu(TLR[tok(c1)][0:768] + TLR[tok(c2)][768:1536] + b)
// 192 threads, ushort4-vectorized (G13: scalar bf16 loads are 2-2.5x slower)
__global__ __launch_bounds__(192) void k_addgelu(
    const ushort* __restrict__ T,
    const int* __restrict__ ppos, int c1, int c2,
    const float* __restrict__ b, ushort* __restrict__ out)
{
    const int rr = blockIdx.x;
    const int tid = threadIdx.x;
    const int p = ppos[rr * 5];
    const size_t bl = (size_t)(p * LPARA + ppos[rr * 5 + c1]) * TSTR + tid * 4;
    const size_t br = (size_t)(p * LPARA + ppos[rr * 5 + c2]) * TSTR + D + tid * 4;
    ushort4 L = *(const ushort4*)(T + bl);
    ushort4 R = *(const ushort4*)(T + br);
    float4 bb = *(const float4*)(b + tid * 4);
    ushort4 o;
    o.x = bfrne(geluf(bf2f(L.x) + bf2f(R.x) + bb.x));
    o.y = bfrne(geluf(bf2f(L.y) + bf2f(R.y) + bb.y));
    o.z = bfrne(geluf(bf2f(L.z) + bf2f(R.z) + bb.z));
    o.w = bfrne(geluf(bf2f(L.w) + bf2f(R.w) + bb.w));
    *(ushort4*)(out + (size_t)rr * D + tid * 4) = o;
}

// entity hidden via token embeddings: gelu(mean(Tl[tokL]+Tr[tokR]) + b)
// 192 threads, ushort4-vectorized
__global__ __launch_bounds__(192) void k_entmean_t(
    const ushort* __restrict__ T,
    const int* __restrict__ mpos, const int* __restrict__ mid, int M,
    const float* __restrict__ b, ushort* __restrict__ oh)
{
    __shared__ int sb[2];
    const int e = blockIdx.x;
    if (threadIdx.x < 2) {
        int target = e + threadIdx.x;
        int lo = 0, hi = M;
        while (lo < hi) {
            int md = (lo + hi) >> 1;
            if (mid[md] < target) lo = md + 1; else hi = md;
        }
        sb[threadIdx.x] = lo;
    }
    __syncthreads();
    const int lo = sb[0], hi = sb[1];
    const int tid = threadIdx.x;
    float s0 = 0, s1 = 0, s2 = 0, s3 = 0;
    for (int m = lo; m < hi; ++m) {
        int p = mpos[m * 3], t1 = mpos[m * 3 + 1], t2 = mpos[m * 3 + 2];
        ushort4 L = *(const ushort4*)(T + (size_t)(p * LPARA + t1) * TSTR + tid * 4);
        ushort4 R = *(const ushort4*)(T + (size_t)(p * LPARA + t2) * TSTR + D + tid * 4);
        s0 += bf2f(L.x) + bf2f(R.x);
        s1 += bf2f(L.y) + bf2f(R.y);
        s2 += bf2f(L.z) + bf2f(R.z);
        s3 += bf2f(L.w) + bf2f(R.w);
    }
    const float inv = (hi > lo) ? 1.0f / (float)(hi - lo) : 0.0f;
    float4 bb = *(const float4*)(b + tid * 4);
    ushort4 o;
    o.x = bfrne(geluf(s0 * inv + bb.x));
    o.y = bfrne(geluf(s1 * inv + bb.y));
    o.z = bfrne(geluf(s2 * inv + bb.z));
    o.w = bfrne(geluf(s3 * inv + bb.w));
    *(ushort4*)(oh + (size_t)e * D + tid * 4) = o;
}

// ---------------------------------------------------------------------------
// Batched split-K matvec (deterministic). grid (N/64, nks, T).
__global__ __launch_bounds__(256) void k_mvpart(
    const float* __restrict__ x, int xstride,
    const float* __restrict__ W, float* __restrict__ acc, int K, int N, int nks)
{
    const int t = blockIdx.z;
    const float* xt = x + (size_t)t * xstride;
    const float* Wt = W + (size_t)t * K * N;
    const int jj = threadIdx.x & 63;
    const int kq = threadIdx.x >> 6;
    const int j = blockIdx.x * 64 + jj;
    const int kchunk = K / (nks * 4);
    const int kbeg = (blockIdx.y * 4 + kq) * kchunk;
    float s = 0.0f;
    for (int k = kbeg; k < kbeg + kchunk; ++k)
        s = fmaf(xt[k], Wt[(size_t)k * N + j], s);
    __shared__ float red[256];
    red[threadIdx.x] = s;
    __syncthreads();
    if (kq == 0) {
        float v = red[jj] + red[64 + jj] + red[128 + jj] + red[192 + jj];
        acc[((size_t)(t * nks) + blockIdx.y) * N + j] = v;
    }
}

__global__ void k_biasact(const float* __restrict__ acc, const float* __restrict__ b,
                          float* __restrict__ out, int N, int nks, int act)
{
    const int t = blockIdx.y;
    const int j = blockIdx.x * 256 + threadIdx.x;
    if (j >= N) return;
    float s = 0.0f;
    for (int i = 0; i < nks; ++i) s += acc[((size_t)(t * nks) + i) * N + j];
    s += b[(size_t)t * N + j];
    if (act) s = geluf(s);
    out[(size_t)t * N + j] = s;
}

__global__ void k_dot3(const float* __restrict__ x, const float* __restrict__ W,
                       const float* __restrict__ b, float* __restrict__ out)
{
    int j = threadIdx.x >> 6, lane = threadIdx.x & 63;
    if (j >= 3) return;
    float s = 0.0f;
#pragma unroll
    for (int i = 0; i < 4; ++i) {
        int k = lane + i * 64;
        s += x[k] * W[k * 3 + j];
    }
    for (int off = 32; off > 0; off >>= 1) s += __shfl_down(s, off, 64);
    if (lane == 0) out[j] = s + b[j];
}

__global__ void k_ctx3(const float* __restrict__ cq3, const float* __restrict__ qwh,
                       float* __restrict__ ctx3)
{
    const float* cq = cq3 + (size_t)blockIdx.x * D;
    float* ctx = ctx3 + (size_t)blockIdx.x * D;
    __shared__ float red[256];
    __shared__ float dist[LQ];
    const int tid = threadIdx.x;
    const int l = tid >> 3, part = tid & 7;
    float s = 0.0f;
    for (int d = part; d < D; d += 8) s += cq[d] * qwh[l * D + d];
    red[tid] = s;
    __syncthreads();
    if (part == 0) {
        float v = 0;
        for (int i = 0; i < 8; ++i) v += red[l * 8 + i];
        dist[l] = v;
    }
    __syncthreads();
    if (tid == 0) {
        float mx = -1e30f;
        for (int i = 0; i < LQ; ++i) mx = fmaxf(mx, dist[i]);
        float sm = 0;
        for (int i = 0; i < LQ; ++i) { float e = expf(dist[i] - mx); dist[i] = e; sm += e; }
        float inv = 1.0f / sm;
        for (int i = 0; i < LQ; ++i) dist[i] *= inv;
    }
    __syncthreads();
    for (int d = tid; d < D; d += 256) {
        float v = 0;
#pragma unroll
        for (int l2 = 0; l2 < LQ; ++l2) v += dist[l2] * qwh[l2 * D + d];
        ctx[d] = v + cq[d];
    }
}

__global__ void k_scalew(const float* __restrict__ ctx, const float* __restrict__ w1,
                         float* __restrict__ o, int n)
{
    int i = blockIdx.x * 256 + threadIdx.x;
    if (i < n) o[i] = ctx[i >> 8] * w1[i];
}

// sim rowdot; hstr = row stride of H in floats
template <int PAIRMODE>
__global__ void k_rowdot(const float* __restrict__ H, int hstr,
                         const float* __restrict__ w2,
                         const float* __restrict__ sb2, int Nr,
                         float* __restrict__ simout,
                         const float* __restrict__ laste, const int* __restrict__ so,
                         float* __restrict__ newe)
{
    int r = blockIdx.x * 4 + (threadIdx.x >> 6);
    int lane = threadIdx.x & 63;
    if (r >= Nr) return;
    float s = 0.0f;
#pragma unroll
    for (int i = 0; i < 4; ++i)
        s += H[(size_t)r * hstr + lane + i * 64] * w2[lane + i * 64];
    for (int off = 32; off > 0; off >>= 1) s += __shfl_down(s, off, 64);
    if (lane == 0) {
        s += sb2[0];
        if (PAIRMODE == 0) {
            simout[r] = s;
        } else {
            float p = 1.0f / (1.0f + expf(-s));
            float v = laste[so[r * 2]] * p;
            atomicAdd(&newe[so[r * 2 + 1]], v);
        }
    }
}

__global__ void k_softmax(const float* __restrict__ sim, float* __restrict__ outp, int n)
{
    __shared__ float red[256];
    __shared__ float s_mx, s_sum;
    const int tid = threadIdx.x;
    float mx = -1e30f;
    for (int i = tid; i < n; i += 256) mx = fmaxf(mx, sim[i]);
    red[tid] = mx; __syncthreads();
    for (int off = 128; off > 0; off >>= 1) {
        if (tid < off) red[tid] = fmaxf(red[tid], red[tid + off]);
        __syncthreads();
    }
    if (tid == 0) s_mx = red[0];
    __syncthreads();
    const float mxv = s_mx;
    float sum = 0;
    for (int i = tid; i < n; i += 256) sum += expf(sim[i] - mxv);
    red[tid] = sum; __syncthreads();
    for (int off = 128; off > 0; off >>= 1) {
        if (tid < off) red[tid] += red[tid + off];
        __syncthreads();
    }
    if (tid == 0) s_sum = red[0];
    __syncthreads();
    const float inv = 1.0f / s_sum;
    for (int i = tid; i < n; i += 256) {
        float v = expf(sim[i] - mxv) * inv;
        outp[i] = v / fmaxf(v, 1.0f);
    }
}

__global__ void k_zero(float* p, int n)
{
    int i = blockIdx.x * blockDim.x + threadIdx.x;
    if (i < n) p[i] = 0.0f;
}

__global__ void k_clampstore(const float* __restrict__ ne, float* __restrict__ outp, int n)
{
    int i = blockIdx.x * blockDim.x + threadIdx.x;
    if (i < n) { float v = ne[i]; outp[i] = v / fmaxf(v, 1.0f); }
}

__global__ void k_final(const float* __restrict__ probs, const float* __restrict__ hlog,
                        float* __restrict__ out, int n)
{
    int i = blockIdx.x * blockDim.x + threadIdx.x;
    if (i >= n) return;
    float l0 = hlog[0], l1 = hlog[1], l2 = hlog[2];
    float m = fmaxf(l0, fmaxf(l1, l2));
    float e0 = expf(l0 - m), e1 = expf(l1 - m), e2 = expf(l2 - m);
    float inv = 1.0f / (e0 + e1 + e2);
    out[i] = (e0 * probs[i] + e1 * probs[n + i] + e2 * probs[2 * n + i]) * inv;
}

// ---------------------------------------------------------------------------
extern "C" void kernel_launch(void* const* d_in, const int* in_sizes, int n_in,
                              void* d_out, int out_size, void* d_ws, size_t ws_size,
                              hipStream_t stream)
{
    const size_t WS_NEED = 148015504;  // 141.2 MiB (proven capacity 148.8 MB)
    if (ws_size < WS_NEED) return;

    const float* para  = (const float*)d_in[0];
    const float* q     = (const float*)d_in[1];
    const float* qwh   = (const float*)d_in[2];
    const float* stW1  = (const float*)d_in[3];
    const float* stb1  = (const float*)d_in[4];
    const float* stW2  = (const float*)d_in[5];
    const float* stb2  = (const float*)d_in[6];
    const float* mW1   = (const float*)d_in[7];
    const float* mb1   = (const float*)d_in[8];
    const float* mW2   = (const float*)d_in[9];
    const float* mb2   = (const float*)d_in[10];
    const float* pW1   = (const float*)d_in[11];
    const float* pb1   = (const float*)d_in[12];
    const float* pW2   = (const float*)d_in[13];
    const float* pb2   = (const float*)d_in[14];
    const float* simW1 = (const float*)d_in[15];
    const float* simb1 = (const float*)d_in[16];
    const float* simW2 = (const float*)d_in[17];
    const float* simb2 = (const float*)d_in[18];
    const float* hW1   = (const float*)d_in[19];
    const float* hb1   = (const float*)d_in[20];
    const float* hW2   = (const float*)d_in[21];
    const float* hb2   = (const float*)d_in[22];
    const int*   mpos  = (const int*)d_in[23];
    const int*   mid   = (const int*)d_in[24];
    const int*   ppos  = (const int*)d_in[25];
    const int*   pso   = (const int*)d_in[26];

    // ---- workspace: regions + weights + fp32 tail ----
    ushort* ws16 = (ushort*)d_ws;
    ushort* R1 = ws16;                     // 15,360,000: PB16 -> subhid -> pairh
    ushort* R2 = R1 + 15360000;            // 15,360,000: Wfold -> objhid -> pairE
    ushort* R3 = R2 + 15360000;            // 15,360,000: TLR[0:15.36M) -> subf -> H256c lo
    ushort* R4 = R3 + 15360000;            // 15,360,000: TLR[tail] -> E+H256a -> objf -> H256c hi
    ushort* R5 = R4 + 15360000;            //  7,680,000: W1s tmp -> enthid
    ushort* WlrT  = R5 + 7680000;          //  1,179,648 ([1536][768]: Wl 0-767, Wr 768-1535)
    ushort* mW2T  = WlrT + 1179648;        //    589,824
    ushort* WfT   = mW2T + 589824;         //  1,769,472
    ushort* pW2T  = WfT + 1769472;         //    589,824
    ushort* W1sT0 = pW2T + 589824;         //    589,824 (3 x 196,608)
    float*  tail  = (float*)(W1sT0 + 589824);
    float*  simb  = tail;                  // 20,000
    float*  probs = simb + 20000;          // 30,000
    float*  newe  = probs + 30000;         // 10,000
    float*  acc3  = newe + 10000;          // 13,824
    float*  h3    = acc3 + 13824;          // 2,304
    float*  cq3   = h3   + 2304;           // 2,304
    float*  ctx3  = cq3  + 2304;           // 2,304
    float*  hacc  = ctx3 + 2304;           // 1,536
    float*  hh    = hacc + 1536;           // 256
    float*  hlog  = hh   + 256;            // 4
    float*  zb    = hlog + 4;              // 1,536 (zero bias)
    float*  sb1d  = zb   + 1536;           //   512 (duplicated simb1)

    // phase overlays (liveness audited):
    float*  Wfold  = (float*)R2;           // fp32 tmp, dead after k_wt(WfT)
    float*  W1s    = (float*)R5;           // fp32 tmp, dead before enthid written
    ushort* PB16   = R1;                   // [16384][768], dead after TLR GEMM
    ushort* TLR    = R3;                   // [16384][1536] = 25.17M, spans R3 + 9.81M of R4
    ushort* enthid = R5;                   // [10000][768] (after W1s dead)
    ushort* subhid = R1;                   // [20000][768] (after PB16 dead)
    ushort* objhid = R2;                   // [20000][768] (after Wfold dead) — contiguous w/ subhid
    ushort* E      = R4;                   // [10000][768] = 7.68M (TLR dead by then)
    float*  H256a  = (float*)(R4 + 7680000); // [10000][256] fp32 = 5.12M ushorts (in R4)
    ushort* subf   = R3;                   // [20000][768] (TLR + H256a/E dead)
    ushort* objf   = R4;                   // contiguous output of fused pair-feat GEMM
    ushort* pairh  = R1;                   // (subhid dead)
    ushort* pairE  = R2;                   // (objhid dead)
    float*  H256c  = (float*)R3;           // [20000][512] fp32 = 20.48M ushorts (subf/objf dead)

    dim3 B256(256);
    dim3 B192(192);
    const ushort* np = nullptr;

    // 0) weight prep (Wfold in R2, consumed before objhid)
    k_fold<<<(2304 * D + 255) / 256, B256, 0, stream>>>(pW1, Wfold, 2304 * D);
    k_wt<<<dim3(24, 24), B256, 0, stream>>>(mW1, WlrT, D, D);                       // Wl
    k_wt<<<dim3(24, 24), B256, 0, stream>>>(mW1 + (size_t)D * D, WlrT + (size_t)D * D, D, D); // Wr
    k_wt<<<dim3(24, 24), B256, 0, stream>>>(mW2, mW2T, D, D);
    k_wt<<<dim3(72, 24), B256, 0, stream>>>(Wfold, WfT, 3 * D, D);
    k_wt<<<dim3(24, 24), B256, 0, stream>>>(pW2, pW2T, D, D);
    k_zero<<<6, B256, 0, stream>>>(zb, TSTR);
    k_dup<<<2, B256, 0, stream>>>(simb1, sb1d, 512, 256);

    // 1) batched step MLPs + ctx + scaled sim weights (W1s tmp in R5)
    k_mvpart<<<dim3(12, 6, 3), B256, 0, stream>>>(q, 0, stW1, acc3, D, D, 6);
    k_biasact<<<dim3(3, 3), B256, 0, stream>>>(acc3, stb1, h3, D, 6, 1);
    k_mvpart<<<dim3(12, 6, 3), B256, 0, stream>>>(h3, D, stW2, acc3, D, D, 6);
    k_biasact<<<dim3(3, 3), B256, 0, stream>>>(acc3, stb2, cq3, D, 6, 0);
    k_ctx3<<<3, B256, 0, stream>>>(cq3, qwh, ctx3);
    for (int t = 0; t < NSTEP; ++t) {
        k_scalew<<<768, 256, 0, stream>>>(ctx3 + (size_t)t * D, simW1, W1s, D * 256);
        k_wt<<<dim3(24, 8), B256, 0, stream>>>(W1s, W1sT0 + t * 196608, D, 256);
    }

    // 2) fused token embeddings: TLR = PB16 @ [Wl|Wr]  (M=16384, N=1536)
    k_cvt<<<(NTOK * D / 4 + 255) / 256, B256, 0, stream>>>(para, PB16, NTOK * D / 4);
    gemm_m<0, 0, 1><<<3072, B256, 0, stream>>>(PB16, nullptr, nullptr, 0, 0, np, np,
        WlrT, zb, nullptr, TLR, NTOK, TSTR, D, 12);

    // 3) hiddens via gather-add-gelu (ushort4-vectorized)
    k_entmean_t<<<NENT, B192, 0, stream>>>(TLR, mpos, mid, MMENT, mb1, enthid);
    k_addgelu<<<NPAIR, B192, 0, stream>>>(TLR, ppos, 1, 2, mb1, subhid);
    k_addgelu<<<NPAIR, B192, 0, stream>>>(TLR, ppos, 3, 4, mb1, objhid);

    // 4) ent_emb + step 0 sim -> probs[0]
    gemm_m<0, 0, 1><<<942, B256, 0, stream>>>(enthid, nullptr, nullptr, 0, 0, np, np,
        mW2T, mb2, nullptr, E, NENT, D, D, 6);
    gemm_m<0, 1, 0><<<314, B256, 0, stream>>>(E, nullptr, nullptr, 0, 0, np, np,
        W1sT0, simb1, H256a, nullptr, NENT, 256, D, 2);
    k_rowdot<0><<<NENT / 4, 256, 0, stream>>>(H256a, 256, simW2, simb2, NENT, simb,
                                              nullptr, nullptr, nullptr);
    k_softmax<<<1, 256, 0, stream>>>(simb, probs, NENT);

    // 5) FUSED pair features: [subhid;objhid] (M=40000) @ mW2T -> [subf;objf]
    gemm_m<0, 0, 1><<<3750, B256, 0, stream>>>(subhid, nullptr, nullptr, 0, 0, np, np,
        mW2T, mb2, nullptr, subf, 2 * NPAIR, D, D, 6);
    gemm_m<2, 1, 1><<<1878, B256, 0, stream>>>(np, nullptr, nullptr, 0, 0, subf, objf,
        WfT, pb1, nullptr, pairh, NPAIR, D, 3 * D, 6);
    gemm_m<0, 0, 1><<<1878, B256, 0, stream>>>(pairh, nullptr, nullptr, 0, 0, np, np,
        pW2T, pb2, nullptr, pairE, NPAIR, D, D, 6);

    // 6) FUSED sims for steps 1,2: pairE @ [W1sT1|W1sT2] (N=512) -> H256c
    gemm_m<0, 1, 0><<<1252, B256, 0, stream>>>(pairE, nullptr, nullptr, 0, 0, np, np,
        W1sT0 + 196608, sb1d, H256c, nullptr, NPAIR, 512, D, 4);
    for (int t = 1; t < NSTEP; ++t) {
        k_zero<<<40, 256, 0, stream>>>(newe, NENT);
        k_rowdot<1><<<NPAIR / 4, 256, 0, stream>>>(H256c + (t - 1) * 256, 512,
                                                   simW2, simb2, NPAIR, nullptr,
                                                   probs + (t - 1) * NENT, pso, newe);
        k_clampstore<<<40, 256, 0, stream>>>(newe, probs + t * NENT, NENT);
    }

    // 7) hop attention + final mix
    k_mvpart<<<dim3(4, 6, 1), B256, 0, stream>>>(q, 0, hW1, hacc, D, 256, 6);
    k_biasact<<<dim3(1, 1), B256, 0, stream>>>(hacc, hb1, hh, 256, 6, 1);
    k_dot3<<<1, B256, 0, stream>>>(hh, hW2, hb2, hlog);
    k_final<<<40, 256, 0, stream>>>(probs, hlog, (float*)d_out, NENT);
}

// Round 23
// 615.697 us; speedup vs baseline: 2.7328x; 1.0210x over previous
//
#include <hip/hip_runtime.h>
#include <math.h>

// ---------------------------------------------------------------------------
#define D 768
#define NPARA 32
#define LPARA 512
#define LQ 32
#define NENT 10000
#define MMENT 30000
#define NPAIR 20000
#define NSTEP 3
#define NTOK (NPARA * LPARA)   // 16384 unique tokens
#define TSTR 1536              // TLR row stride (Tl cols 0..767, Tr 768..1535)

using bf16x8 = __attribute__((ext_vector_type(8))) short;
using f32x4  = __attribute__((ext_vector_type(4))) float;

__device__ __forceinline__ float geluf(float x) {
    return 0.5f * x * (1.0f + erff(x * 0.70710678118654752f));
}
__device__ __forceinline__ float bf2f(ushort h) {
    union { unsigned u; float f; } v; v.u = ((unsigned)h) << 16; return v.f;
}
// round-to-nearest-even fp32 -> bf16
__device__ __forceinline__ ushort bfrne(float x) {
    union { float f; unsigned u; } v; v.f = x;
    unsigned r = (v.u + 0x7FFF + ((v.u >> 16) & 1)) >> 16;
    return (ushort)r;
}

// ---------------------------------------------------------------------------
// Single-plane bf16 MFMA GEMM. 64x128 tile, A+B LDS (XOR-swizzled), register
// prefetch of next A and B tiles, band-major XCD swizzle.
// R12 KNOWN-GOOD TEMPLATE (VGPR 60, no spill) — body must stay byte-identical.
// R13/R14 (MI=4) and R16 (merged prefetch) all perturbed regalloc -> spill.
// MODE 0: A = bf16 plane [M][K]
// MODE 1: A row r = concat(para[p,t1,:], para[p,t2,:]) fp32 gather (UNUSED now)
// MODE 2: A row r, sections {S, O, S*O} from bf16 feats, K=2304 (folded W1)
// B: pre-transposed bf16 weights WT[N][K]. OUTP 0: fp32 C; 1: bf16 C.
// ---------------------------------------------------------------------------
#define BM 64
#define BN 128

__device__ __forceinline__ int ldso(int row, int kb) {   // ushort index
    return row * 64 + (((kb) ^ ((row & 7) << 4)) >> 1);
}

template <int MODE, int ACT, int OUTP>
__global__ __launch_bounds__(256, 4) void gemm_m(
    const ushort* __restrict__ Ah,
    const float* __restrict__ para, const int* __restrict__ ppos, int c1, int c2,
    const ushort* __restrict__ Sh, const ushort* __restrict__ Oh,
    const ushort* __restrict__ Bh, const float* __restrict__ bias,
    float* __restrict__ Cf, ushort* __restrict__ Ch,
    int M, int N, int K, int nby)
{
    __shared__ ushort sA[BM * 64];   //  8 KB
    __shared__ ushort sB[BN * 64];   // 16 KB

    const int nwg = gridDim.x;
    const int q = nwg >> 3, r = nwg & 7;
    const int xcd = blockIdx.x & 7, idx = blockIdx.x >> 3;
    const int wgid = (xcd < r) ? xcd * (q + 1) + idx
                               : r * (q + 1) + (xcd - r) * q + idx;
    const int m0 = (wgid / nby) * BM;
    const int n0 = (wgid % nby) * BN;

    const int tid = threadIdx.x;
    const int lane = tid & 63;
    const int wv = tid >> 6;
    const int wr = (wv >> 1) * 32;
    const int wc = (wv & 1) * 64;
    const int ln = lane & 15;
    const int kg = lane >> 4;

    f32x4 acc[2][4];
#pragma unroll
    for (int i = 0; i < 2; ++i)
#pragma unroll
        for (int j = 0; j < 4; ++j)
#pragma unroll
            for (int e = 0; e < 4; ++e) acc[i][j][e] = 0.0f;

    const int arow = tid >> 2, aq = tid & 3;   // A: 4 thr/row, 16 ushort each
    const int brow = tid >> 1, bq = tid & 1;   // B: 2 thr/row, 32 ushort each
    const int gm = m0 + arow;
    const bool ok = gm < M;

    int baseL = 0, baseR = 0;
    if (MODE == 1 && ok) {
        int p = ppos[gm * 5];
        baseL = (p * LPARA + ppos[gm * 5 + c1]) * D;
        baseR = (p * LPARA + ppos[gm * 5 + c2]) * D;
    }

    bf16x8 pa[2];     // MODE 0 prefetch
    float4 pf[4];     // MODE 1 prefetch (16 fp32)
    ushort4 ps[8];    // MODE 2 prefetch (S and/or O quads)
    bf16x8 pb[4];     // B prefetch (32 ushorts)

    auto prefA = [&](int kt) {
        if (MODE == 0) {
            if (ok) {
                const ushort* g = Ah + (size_t)gm * K + kt + aq * 16;
                pa[0] = *(const bf16x8*)g;
                pa[1] = *(const bf16x8*)(g + 8);
            } else {
#pragma unroll
                for (int i = 0; i < 2; ++i)
#pragma unroll
                    for (int z = 0; z < 8; ++z) pa[i][z] = 0;
            }
        } else if (MODE == 1) {
            const int kb = kt + aq * 16;            // never crosses D boundary
            const int gb = (kb < D) ? (baseL + kb) : (baseR + kb - D);
#pragma unroll
            for (int j = 0; j < 4; ++j)
                pf[j] = ok ? *(const float4*)(para + gb + j * 4)
                           : make_float4(0.f, 0.f, 0.f, 0.f);
        } else {
            const int sec = kt / D;
            const size_t rb = (size_t)gm * D + (kt - sec * D) + aq * 16;
            if (ok) {
                if (sec == 0) {
#pragma unroll
                    for (int j = 0; j < 4; ++j)
                        ps[j] = *(const ushort4*)(Sh + rb + j * 4);
                } else if (sec == 1) {
#pragma unroll
                    for (int j = 0; j < 4; ++j)
                        ps[j] = *(const ushort4*)(Oh + rb + j * 4);
                } else {
#pragma unroll
                    for (int j = 0; j < 4; ++j) {
                        ps[j]     = *(const ushort4*)(Sh + rb + j * 4);
                        ps[4 + j] = *(const ushort4*)(Oh + rb + j * 4);
                    }
                }
            }
        }
    };

    auto prefB = [&](int kt) {
        const ushort* g = Bh + (size_t)(n0 + brow) * K + kt + bq * 32;
#pragma unroll
        for (int i = 0; i < 4; ++i)
            pb[i] = *(const bf16x8*)(g + i * 8);
    };

    auto storeAB = [&](int kt) {
        if (MODE == 0) {
            int o0 = ldso(arow, aq * 32), o1 = ldso(arow, aq * 32 + 16);
            *(bf16x8*)&sA[o0] = pa[0];
            *(bf16x8*)&sA[o1] = pa[1];
        } else if (MODE == 1) {
#pragma unroll
            for (int j = 0; j < 4; ++j) {
                ushort4 h;
                h.x = bfrne(pf[j].x); h.y = bfrne(pf[j].y);
                h.z = bfrne(pf[j].z); h.w = bfrne(pf[j].w);
                *(ushort4*)&sA[ldso(arow, aq * 32 + j * 8)] = h;
            }
        } else {
            const int sec = kt / D;
#pragma unroll
            for (int j = 0; j < 4; ++j) {
                ushort4 h;
                if (ok) {
                    if (sec < 2) {
                        h = ps[j];
                    } else {
                        h.x = bfrne(bf2f(ps[j].x) * bf2f(ps[4 + j].x));
                        h.y = bfrne(bf2f(ps[j].y) * bf2f(ps[4 + j].y));
                        h.z = bfrne(bf2f(ps[j].z) * bf2f(ps[4 + j].z));
                        h.w = bfrne(bf2f(ps[j].w) * bf2f(ps[4 + j].w));
                    }
                } else {
                    h.x = h.y = h.z = h.w = 0;
                }
                *(ushort4*)&sA[ldso(arow, aq * 32 + j * 8)] = h;
            }
        }
#pragma unroll
        for (int i = 0; i < 4; ++i)
            *(bf16x8*)&sB[ldso(brow, bq * 64 + i * 16)] = pb[i];
    };

    prefA(0);
    prefB(0);

    for (int kt = 0; kt < K; kt += 64) {
        if (kt > 0) __syncthreads();
        storeAB(kt);
        __syncthreads();

        const int ktn = kt + 64;
        if (ktn < K) { prefA(ktn); prefB(ktn); }

#pragma unroll
        for (int ks = 0; ks < 2; ++ks) {
            bf16x8 fb[4];
#pragma unroll
            for (int ni = 0; ni < 4; ++ni)
                fb[ni] = *(const bf16x8*)&sB[ldso(wc + ni * 16 + ln, ks * 64 + kg * 16)];
#pragma unroll
            for (int mi = 0; mi < 2; ++mi) {
                bf16x8 fa = *(const bf16x8*)&sA[ldso(wr + mi * 16 + ln, ks * 64 + kg * 16)];
#pragma unroll
                for (int ni = 0; ni < 4; ++ni)
                    acc[mi][ni] = __builtin_amdgcn_mfma_f32_16x16x32_bf16(
                        fa, fb[ni], acc[mi][ni], 0, 0, 0);
            }
        }
    }

    // epilogue: row = (lane>>4)*4+reg, col = lane&15
#pragma unroll
    for (int mi = 0; mi < 2; ++mi)
#pragma unroll
        for (int ni = 0; ni < 4; ++ni) {
            int col = n0 + wc + ni * 16 + ln;
            f32x4 a = acc[mi][ni];
#pragma unroll
            for (int j = 0; j < 4; ++j) {
                int row = m0 + wr + mi * 16 + kg * 4 + j;
                if (row < M) {
                    float v = a[j] + bias[col];
                    if (ACT == 1) v = geluf(v);
                    if (OUTP == 0) Cf[(size_t)row * N + col] = v;
                    else           Ch[(size_t)row * N + col] = bfrne(v);
                }
            }
        }
}

// ---------------------------------------------------------------------------
// Weight transpose: W[K][N] fp32 -> WT[N][K] bf16 (RNE)
__global__ __launch_bounds__(256) void k_wt(const float* __restrict__ W,
                                            ushort* __restrict__ WTh, int K, int N)
{
    __shared__ float t[32][33];
    const int k0 = blockIdx.x * 32, n0 = blockIdx.y * 32;
    const int c = threadIdx.x & 31, r8 = threadIdx.x >> 5;
#pragma unroll
    for (int i = 0; i < 4; ++i) {
        int r = r8 + i * 8;
        t[r][c] = W[(size_t)(k0 + r) * N + n0 + c];
    }
    __syncthreads();
#pragma unroll
    for (int i = 0; i < 4; ++i) {
        int r = r8 + i * 8;
        WTh[(size_t)(n0 + r) * K + k0 + c] = bfrne(t[c][r]);
    }
}

// fused scale+transpose for sim weights: WT[t][n][k] = ctx3[t][k]*simW1[k][n]
// grid (24, 8, 3): K=768 k-tiles x N=256 n-tiles x 3 steps
__global__ __launch_bounds__(256) void k_scalewt(
    const float* __restrict__ ctx3, const float* __restrict__ W,
    ushort* __restrict__ WT)
{
    __shared__ float t[32][33];
    const int ts = blockIdx.z;
    const int k0 = blockIdx.x * 32, n0 = blockIdx.y * 32;
    const int c = threadIdx.x & 31, r8 = threadIdx.x >> 5;
    const float* ctx = ctx3 + (size_t)ts * D;
    ushort* WTt = WT + (size_t)ts * 196608;
#pragma unroll
    for (int i = 0; i < 4; ++i) {
        int r = r8 + i * 8;
        t[r][c] = ctx[k0 + r] * W[(size_t)(k0 + r) * 256 + n0 + c];
    }
    __syncthreads();
#pragma unroll
    for (int i = 0; i < 4; ++i) {
        int r = r8 + i * 8;
        WTt[(size_t)(n0 + r) * D + k0 + c] = bfrne(t[c][r]);
    }
}

// folded pair W1: Wf[2304][768] from pW1[3072][768]
__global__ void k_fold(const float* __restrict__ pW1, float* __restrict__ Wf, int n)
{
    int i = blockIdx.x * blockDim.x + threadIdx.x;
    if (i >= n) return;
    int row = i / D;
    float v;
    if (row < D)            v = pW1[i] - pW1[i + 1536 * D];
    else if (row < 2 * D)   v = pW1[i] + pW1[i + 768 * D];
    else                    v = pW1[i + 768 * D];
    Wf[i] = v;
}

// para fp32 -> bf16 plane (vectorized x4)
__global__ void k_cvt(const float* __restrict__ src, ushort* __restrict__ dst, int n4)
{
    int i = blockIdx.x * blockDim.x + threadIdx.x;
    if (i >= n4) return;
    float4 v = ((const float4*)src)[i];
    ushort4 h;
    h.x = bfrne(v.x); h.y = bfrne(v.y); h.z = bfrne(v.z); h.w = bfrne(v.w);
    ((ushort4*)dst)[i] = h;
}

// dst[i] = src[i % period]
__global__ void k_dup(const float* __restrict__ src, float* __restrict__ dst,
                      int n, int period)
{
    int i = blockIdx.x * blockDim.x + threadIdx.x;
    if (i < n) dst[i] = src[i % period];
}

// fused sub+obj gather-add-gelu; out base = subhid, objhid = subhid + NPAIR*D
// (R1 and R2 are contiguous). 192 threads, ushort4-vectorized.
__global__ __launch_bounds__(192) void k_addgelu2(
    const ushort* __restrict__ T,
    const int* __restrict__ ppos,
    const float* __restrict__ b, ushort* __restrict__ out)
{
    const int half = blockIdx.x / NPAIR;        // 0: sub (cols 1,2)  1: obj (3,4)
    const int rr = blockIdx.x - half * NPAIR;
    const int c1 = 1 + half * 2, c2 = 2 + half * 2;
    const int tid = threadIdx.x;
    const int p = ppos[rr * 5];
    const size_t bl = (size_t)(p * LPARA + ppos[rr * 5 + c1]) * TSTR + tid * 4;
    const size_t br = (size_t)(p * LPARA + ppos[rr * 5 + c2]) * TSTR + D + tid * 4;
    ushort4 L = *(const ushort4*)(T + bl);
    ushort4 R = *(const ushort4*)(T + br);
    float4 bb = *(const float4*)(b + tid * 4);
    ushort4 o;
    o.x = bfrne(geluf(bf2f(L.x) + bf2f(R.x) + bb.x));
    o.y = bfrne(geluf(bf2f(L.y) + bf2f(R.y) + bb.y));
    o.z = bfrne(geluf(bf2f(L.z) + bf2f(R.z) + bb.z));
    o.w = bfrne(geluf(bf2f(L.w) + bf2f(R.w) + bb.w));
    *(ushort4*)(out + (size_t)half * NPAIR * D + (size_t)rr * D + tid * 4) = o;
}

// entity hidden via token embeddings: gelu(mean(Tl[tokL]+Tr[tokR]) + b)
// 192 threads, ushort4-vectorized
__global__ __launch_bounds__(192) void k_entmean_t(
    const ushort* __restrict__ T,
    const int* __restrict__ mpos, const int* __restrict__ mid, int M,
    const float* __restrict__ b, ushort* __restrict__ oh)
{
    __shared__ int sb[2];
    const int e = blockIdx.x;
    if (threadIdx.x < 2) {
        int target = e + threadIdx.x;
        int lo = 0, hi = M;
        while (lo < hi) {
            int md = (lo + hi) >> 1;
            if (mid[md] < target) lo = md + 1; else hi = md;
        }
        sb[threadIdx.x] = lo;
    }
    __syncthreads();
    const int lo = sb[0], hi = sb[1];
    const int tid = threadIdx.x;
    float s0 = 0, s1 = 0, s2 = 0, s3 = 0;
    for (int m = lo; m < hi; ++m) {
        int p = mpos[m * 3], t1 = mpos[m * 3 + 1], t2 = mpos[m * 3 + 2];
        ushort4 L = *(const ushort4*)(T + (size_t)(p * LPARA + t1) * TSTR + tid * 4);
        ushort4 R = *(const ushort4*)(T + (size_t)(p * LPARA + t2) * TSTR + D + tid * 4);
        s0 += bf2f(L.x) + bf2f(R.x);
        s1 += bf2f(L.y) + bf2f(R.y);
        s2 += bf2f(L.z) + bf2f(R.z);
        s3 += bf2f(L.w) + bf2f(R.w);
    }
    const float inv = (hi > lo) ? 1.0f / (float)(hi - lo) : 0.0f;
    float4 bb = *(const float4*)(b + tid * 4);
    ushort4 o;
    o.x = bfrne(geluf(s0 * inv + bb.x));
    o.y = bfrne(geluf(s1 * inv + bb.y));
    o.z = bfrne(geluf(s2 * inv + bb.z));
    o.w = bfrne(geluf(s3 * inv + bb.w));
    *(ushort4*)(oh + (size_t)e * D + tid * 4) = o;
}

// ---------------------------------------------------------------------------
// Batched split-K matvec (deterministic). grid (N/64, nks, T).
__global__ __launch_bounds__(256) void k_mvpart(
    const float* __restrict__ x, int xstride,
    const float* __restrict__ W, float* __restrict__ acc, int K, int N, int nks)
{
    const int t = blockIdx.z;
    const float* xt = x + (size_t)t * xstride;
    const float* Wt = W + (size_t)t * K * N;
    const int jj = threadIdx.x & 63;
    const int kq = threadIdx.x >> 6;
    const int j = blockIdx.x * 64 + jj;
    const int kchunk = K / (nks * 4);
    const int kbeg = (blockIdx.y * 4 + kq) * kchunk;
    float s = 0.0f;
    for (int k = kbeg; k < kbeg + kchunk; ++k)
        s = fmaf(xt[k], Wt[(size_t)k * N + j], s);
    __shared__ float red[256];
    red[threadIdx.x] = s;
    __syncthreads();
    if (kq == 0) {
        float v = red[jj] + red[64 + jj] + red[128 + jj] + red[192 + jj];
        acc[((size_t)(t * nks) + blockIdx.y) * N + j] = v;
    }
}

__global__ void k_biasact(const float* __restrict__ acc, const float* __restrict__ b,
                          float* __restrict__ out, int N, int nks, int act)
{
    const int t = blockIdx.y;
    const int j = blockIdx.x * 256 + threadIdx.x;
    if (j >= N) return;
    float s = 0.0f;
    for (int i = 0; i < nks; ++i) s += acc[((size_t)(t * nks) + i) * N + j];
    s += b[(size_t)t * N + j];
    if (act) s = geluf(s);
    out[(size_t)t * N + j] = s;
}

__global__ void k_dot3(const float* __restrict__ x, const float* __restrict__ W,
                       const float* __restrict__ b, float* __restrict__ out)
{
    int j = threadIdx.x >> 6, lane = threadIdx.x & 63;
    if (j >= 3) return;
    float s = 0.0f;
#pragma unroll
    for (int i = 0; i < 4; ++i) {
        int k = lane + i * 64;
        s += x[k] * W[k * 3 + j];
    }
    for (int off = 32; off > 0; off >>= 1) s += __shfl_down(s, off, 64);
    if (lane == 0) out[j] = s + b[j];
}

__global__ void k_ctx3(const float* __restrict__ cq3, const float* __restrict__ qwh,
                       float* __restrict__ ctx3)
{
    const float* cq = cq3 + (size_t)blockIdx.x * D;
    float* ctx = ctx3 + (size_t)blockIdx.x * D;
    __shared__ float red[256];
    __shared__ float dist[LQ];
    const int tid = threadIdx.x;
    const int l = tid >> 3, part = tid & 7;
    float s = 0.0f;
    for (int d = part; d < D; d += 8) s += cq[d] * qwh[l * D + d];
    red[tid] = s;
    __syncthreads();
    if (part == 0) {
        float v = 0;
        for (int i = 0; i < 8; ++i) v += red[l * 8 + i];
        dist[l] = v;
    }
    __syncthreads();
    if (tid == 0) {
        float mx = -1e30f;
        for (int i = 0; i < LQ; ++i) mx = fmaxf(mx, dist[i]);
        float sm = 0;
        for (int i = 0; i < LQ; ++i) { float e = expf(dist[i] - mx); dist[i] = e; sm += e; }
        float inv = 1.0f / sm;
        for (int i = 0; i < LQ; ++i) dist[i] *= inv;
    }
    __syncthreads();
    for (int d = tid; d < D; d += 256) {
        float v = 0;
#pragma unroll
        for (int l2 = 0; l2 < LQ; ++l2) v += dist[l2] * qwh[l2 * D + d];
        ctx[d] = v + cq[d];
    }
}

// sim rowdot; hstr = row stride of H in floats
template <int PAIRMODE>
__global__ void k_rowdot(const float* __restrict__ H, int hstr,
                         const float* __restrict__ w2,
                         const float* __restrict__ sb2, int Nr,
                         float* __restrict__ simout,
                         const float* __restrict__ laste, const int* __restrict__ so,
                         float* __restrict__ newe)
{
    int r = blockIdx.x * 4 + (threadIdx.x >> 6);
    int lane = threadIdx.x & 63;
    if (r >= Nr) return;
    float s = 0.0f;
#pragma unroll
    for (int i = 0; i < 4; ++i)
        s += H[(size_t)r * hstr + lane + i * 64] * w2[lane + i * 64];
    for (int off = 32; off > 0; off >>= 1) s += __shfl_down(s, off, 64);
    if (lane == 0) {
        s += sb2[0];
        if (PAIRMODE == 0) {
            simout[r] = s;
        } else {
            float p = 1.0f / (1.0f + expf(-s));
            float v = laste[so[r * 2]] * p;
            atomicAdd(&newe[so[r * 2 + 1]], v);
        }
    }
}

__global__ void k_softmax(const float* __restrict__ sim, float* __restrict__ outp, int n)
{
    __shared__ float red[256];
    __shared__ float s_mx, s_sum;
    const int tid = threadIdx.x;
    float mx = -1e30f;
    for (int i = tid; i < n; i += 256) mx = fmaxf(mx, sim[i]);
    red[tid] = mx; __syncthreads();
    for (int off = 128; off > 0; off >>= 1) {
        if (tid < off) red[tid] = fmaxf(red[tid], red[tid + off]);
        __syncthreads();
    }
    if (tid == 0) s_mx = red[0];
    __syncthreads();
    const float mxv = s_mx;
    float sum = 0;
    for (int i = tid; i < n; i += 256) sum += expf(sim[i] - mxv);
    red[tid] = sum; __syncthreads();
    for (int off = 128; off > 0; off >>= 1) {
        if (tid < off) red[tid] += red[tid + off];
        __syncthreads();
    }
    if (tid == 0) s_sum = red[0];
    __syncthreads();
    const float inv = 1.0f / s_sum;
    for (int i = tid; i < n; i += 256) {
        float v = expf(sim[i] - mxv) * inv;
        outp[i] = v / fmaxf(v, 1.0f);
    }
}

__global__ void k_zero(float* p, int n)
{
    int i = blockIdx.x * blockDim.x + threadIdx.x;
    if (i < n) p[i] = 0.0f;
}

__global__ void k_clampstore(const float* __restrict__ ne, float* __restrict__ outp, int n)
{
    int i = blockIdx.x * blockDim.x + threadIdx.x;
    if (i < n) { float v = ne[i]; outp[i] = v / fmaxf(v, 1.0f); }
}

__global__ void k_final(const float* __restrict__ probs, const float* __restrict__ hlog,
                        float* __restrict__ out, int n)
{
    int i = blockIdx.x * blockDim.x + threadIdx.x;
    if (i >= n) return;
    float l0 = hlog[0], l1 = hlog[1], l2 = hlog[2];
    float m = fmaxf(l0, fmaxf(l1, l2));
    float e0 = expf(l0 - m), e1 = expf(l1 - m), e2 = expf(l2 - m);
    float inv = 1.0f / (e0 + e1 + e2);
    out[i] = (e0 * probs[i] + e1 * probs[n + i] + e2 * probs[2 * n + i]) * inv;
}

// ---------------------------------------------------------------------------
extern "C" void kernel_launch(void* const* d_in, const int* in_sizes, int n_in,
                              void* d_out, int out_size, void* d_ws, size_t ws_size,
                              hipStream_t stream)
{
    const size_t WS_NEED = 148015504;  // 141.2 MiB (proven capacity 148.8 MB)
    if (ws_size < WS_NEED) return;

    const float* para  = (const float*)d_in[0];
    const float* q     = (const float*)d_in[1];
    const float* qwh   = (const float*)d_in[2];
    const float* stW1  = (const float*)d_in[3];
    const float* stb1  = (const float*)d_in[4];
    const float* stW2  = (const float*)d_in[5];
    const float* stb2  = (const float*)d_in[6];
    const float* mW1   = (const float*)d_in[7];
    const float* mb1   = (const float*)d_in[8];
    const float* mW2   = (const float*)d_in[9];
    const float* mb2   = (const float*)d_in[10];
    const float* pW1   = (const float*)d_in[11];
    const float* pb1   = (const float*)d_in[12];
    const float* pW2   = (const float*)d_in[13];
    const float* pb2   = (const float*)d_in[14];
    const float* simW1 = (const float*)d_in[15];
    const float* simb1 = (const float*)d_in[16];
    const float* simW2 = (const float*)d_in[17];
    const float* simb2 = (const float*)d_in[18];
    const float* hW1   = (const float*)d_in[19];
    const float* hb1   = (const float*)d_in[20];
    const float* hW2   = (const float*)d_in[21];
    const float* hb2   = (const float*)d_in[22];
    const int*   mpos  = (const int*)d_in[23];
    const int*   mid   = (const int*)d_in[24];
    const int*   ppos  = (const int*)d_in[25];
    const int*   pso   = (const int*)d_in[26];

    // ---- workspace: regions + weights + fp32 tail ----
    ushort* ws16 = (ushort*)d_ws;
    ushort* R1 = ws16;                     // 15,360,000: PB16 -> subhid -> pairh
    ushort* R2 = R1 + 15360000;            // 15,360,000: Wfold -> objhid -> pairE
    ushort* R3 = R2 + 15360000;            // 15,360,000: TLR[0:15.36M) -> subf -> H256c lo
    ushort* R4 = R3 + 15360000;            // 15,360,000: TLR[tail] -> E+H256a -> objf -> H256c hi
    ushort* R5 = R4 + 15360000;            //  7,680,000: enthid
    ushort* WlrT  = R5 + 7680000;          //  1,179,648 ([1536][768]: Wl 0-767, Wr 768-1535)
    ushort* mW2T  = WlrT + 1179648;        //    589,824
    ushort* WfT   = mW2T + 589824;         //  1,769,472
    ushort* pW2T  = WfT + 1769472;         //    589,824
    ushort* W1sT0 = pW2T + 589824;         //    589,824 (3 x 196,608)
    float*  tail  = (float*)(W1sT0 + 589824);
    float*  simb  = tail;                  // 20,000
    float*  probs = simb + 20000;          // 30,000
    float*  newe  = probs + 30000;         // 10,000
    float*  acc3  = newe + 10000;          // 13,824
    float*  h3    = acc3 + 13824;          // 2,304
    float*  cq3   = h3   + 2304;           // 2,304
    float*  ctx3  = cq3  + 2304;           // 2,304
    float*  hacc  = ctx3 + 2304;           // 1,536
    float*  hh    = hacc + 1536;           // 256
    float*  hlog  = hh   + 256;            // 4
    float*  zb    = hlog + 4;              // 1,536 (zero bias)
    float*  sb1d  = zb   + 1536;           //   512 (duplicated simb1)

    // phase overlays (liveness audited):
    float*  Wfold  = (float*)R2;           // fp32 tmp, dead after k_wt(WfT)
    ushort* PB16   = R1;                   // [16384][768], dead after TLR GEMM
    ushort* TLR    = R3;                   // [16384][1536] = 25.17M, spans R3 + 9.81M of R4
    ushort* enthid = R5;                   // [10000][768]
    ushort* subhid = R1;                   // [20000][768] (after PB16 dead)
    ushort* objhid = R2;                   // [20000][768] (after Wfold dead) — contiguous w/ subhid
    ushort* E      = R4;                   // [10000][768] = 7.68M (TLR dead by then)
    float*  H256a  = (float*)(R4 + 7680000); // [10000][256] fp32 = 5.12M ushorts (in R4)
    ushort* subf   = R3;                   // [20000][768] (TLR + H256a/E dead)
    ushort* objf   = R4;                   // contiguous output of fused pair-feat GEMM
    ushort* pairh  = R1;                   // (subhid dead)
    ushort* pairE  = R2;                   // (objhid dead)
    float*  H256c  = (float*)R3;           // [20000][512] fp32 = 20.48M ushorts (subf/objf dead)

    dim3 B256(256);
    dim3 B192(192);
    const ushort* np = nullptr;

    // 0) weight prep (Wfold in R2, consumed before objhid)
    k_fold<<<(2304 * D + 255) / 256, B256, 0, stream>>>(pW1, Wfold, 2304 * D);
    k_wt<<<dim3(24, 24), B256, 0, stream>>>(mW1, WlrT, D, D);                       // Wl
    k_wt<<<dim3(24, 24), B256, 0, stream>>>(mW1 + (size_t)D * D, WlrT + (size_t)D * D, D, D); // Wr
    k_wt<<<dim3(24, 24), B256, 0, stream>>>(mW2, mW2T, D, D);
    k_wt<<<dim3(72, 24), B256, 0, stream>>>(Wfold, WfT, 3 * D, D);
    k_wt<<<dim3(24, 24), B256, 0, stream>>>(pW2, pW2T, D, D);
    k_zero<<<6, B256, 0, stream>>>(zb, TSTR);
    k_dup<<<2, B256, 0, stream>>>(simb1, sb1d, 512, 256);

    // 1) batched step MLPs + ctx + fused scale+transpose of sim weights
    k_mvpart<<<dim3(12, 6, 3), B256, 0, stream>>>(q, 0, stW1, acc3, D, D, 6);
    k_biasact<<<dim3(3, 3), B256, 0, stream>>>(acc3, stb1, h3, D, 6, 1);
    k_mvpart<<<dim3(12, 6, 3), B256, 0, stream>>>(h3, D, stW2, acc3, D, D, 6);
    k_biasact<<<dim3(3, 3), B256, 0, stream>>>(acc3, stb2, cq3, D, 6, 0);
    k_ctx3<<<3, B256, 0, stream>>>(cq3, qwh, ctx3);
    k_scalewt<<<dim3(24, 8, 3), B256, 0, stream>>>(ctx3, simW1, W1sT0);

    // 2) fused token embeddings: TLR = PB16 @ [Wl|Wr]  (M=16384, N=1536)
    k_cvt<<<(NTOK * D / 4 + 255) / 256, B256, 0, stream>>>(para, PB16, NTOK * D / 4);
    gemm_m<0, 0, 1><<<3072, B256, 0, stream>>>(PB16, nullptr, nullptr, 0, 0, np, np,
        WlrT, zb, nullptr, TLR, NTOK, TSTR, D, 12);

    // 3) hiddens via gather-add-gelu (fused sub+obj launch; vectorized)
    k_entmean_t<<<NENT, B192, 0, stream>>>(TLR, mpos, mid, MMENT, mb1, enthid);
    k_addgelu2<<<2 * NPAIR, B192, 0, stream>>>(TLR, ppos, mb1, subhid);

    // 4) ent_emb + step 0 sim -> probs[0]
    gemm_m<0, 0, 1><<<942, B256, 0, stream>>>(enthid, nullptr, nullptr, 0, 0, np, np,
        mW2T, mb2, nullptr, E, NENT, D, D, 6);
    gemm_m<0, 1, 0><<<314, B256, 0, stream>>>(E, nullptr, nullptr, 0, 0, np, np,
        W1sT0, simb1, H256a, nullptr, NENT, 256, D, 2);
    k_rowdot<0><<<NENT / 4, 256, 0, stream>>>(H256a, 256, simW2, simb2, NENT, simb,
                                              nullptr, nullptr, nullptr);
    k_softmax<<<1, 256, 0, stream>>>(simb, probs, NENT);

    // 5) FUSED pair features: [subhid;objhid] (M=40000) @ mW2T -> [subf;objf]
    gemm_m<0, 0, 1><<<3750, B256, 0, stream>>>(subhid, nullptr, nullptr, 0, 0, np, np,
        mW2T, mb2, nullptr, subf, 2 * NPAIR, D, D, 6);
    gemm_m<2, 1, 1><<<1878, B256, 0, stream>>>(np, nullptr, nullptr, 0, 0, subf, objf,
        WfT, pb1, nullptr, pairh, NPAIR, D, 3 * D, 6);
    gemm_m<0, 0, 1><<<1878, B256, 0, stream>>>(pairh, nullptr, nullptr, 0, 0, np, np,
        pW2T, pb2, nullptr, pairE, NPAIR, D, D, 6);

    // 6) FUSED sims for steps 1,2: pairE @ [W1sT1|W1sT2] (N=512) -> H256c
    gemm_m<0, 1, 0><<<1252, B256, 0, stream>>>(pairE, nullptr, nullptr, 0, 0, np, np,
        W1sT0 + 196608, sb1d, H256c, nullptr, NPAIR, 512, D, 4);
    for (int t = 1; t < NSTEP; ++t) {
        k_zero<<<40, 256, 0, stream>>>(newe, NENT);
        k_rowdot<1><<<NPAIR / 4, 256, 0, stream>>>(H256c + (t - 1) * 256, 512,
                                                   simW2, simb2, NPAIR, nullptr,
                                                   probs + (t - 1) * NENT, pso, newe);
        k_clampstore<<<40, 256, 0, stream>>>(newe, probs + t * NENT, NENT);
    }

    // 7) hop attention + final mix
    k_mvpart<<<dim3(4, 6, 1), B256, 0, stream>>>(q, 0, hW1, hacc, D, 256, 6);
    k_biasact<<<dim3(1, 1), B256, 0, stream>>>(hacc, hb1, hh, 256, 6, 1);
    k_dot3<<<1, B256, 0, stream>>>(hh, hW2, hb2, hlog);
    k_final<<<40, 256, 0, stream>>>(probs, hlog, (float*)d_out, NENT);
}